// Round 1
// baseline (2442.975 us; speedup 1.0000x reference)
//
#include <hip/hip_runtime.h>
#include <hip/hip_bf16.h>
#include <stdint.h>

// SRALayer: x->(Q,K,V,gamma) projections, gated linear-attention scan, output proj.
// B=8, S=2048, D=512. Round-1 strategy: correctness-first fp32 pipeline.
//   - gemm_nt: fp32 tiled GEMM (NT: C[m][n] = sum_k A[m][k] W[n][k] + b[n]),
//     optional sigmoid, optional bf16 output. Used for all 5 matmuls.
//   - scan_kernel: recurrence S_t = g_t (x) S_{t-1} + k_t v_t^T ; out = q_t . S_t
//     parallel over (batch, dk-group, dv); state register-resident; fp32 atomics into O.
// ws layout: Qb(bf16 16MB) Kb(16MB) Vb(16MB) Gf(fp32 64MB) O(fp32 64MB) = 176MB.

#define B_ 8
#define S_ 2048
#define D_ 512
#define M_ (B_ * S_)

__device__ __forceinline__ float bflo(uint32_t u) { return __uint_as_float(u << 16); }
__device__ __forceinline__ float bfhi(uint32_t u) { return __uint_as_float(u & 0xffff0000u); }
__device__ __forceinline__ uint16_t f2bf(float f) {
    uint32_t u = __float_as_uint(f);
    uint32_t r = (u + 0x7fffu + ((u >> 16) & 1u)) >> 16;   // RNE
    return (uint16_t)r;
}

// ---------------- fp32 tiled GEMM (NT), 128x128 tile, BK=16, 256 thr, 8x8 micro ----
__global__ __launch_bounds__(256) void gemm_nt(const float* __restrict__ A,
                                               const float* __restrict__ W,
                                               const float* __restrict__ bias,
                                               void* __restrict__ out,
                                               int out_bf16, int do_sig)
{
    __shared__ float As[16][132];   // [k][m], +4 pad to soften write conflicts
    __shared__ float Bs[16][132];   // [k][n]

    const int tid = threadIdx.x;
    const int tx = tid & 15;        // n-group
    const int ty = tid >> 4;        // m-group
    const int m0 = blockIdx.x * 128;
    const int n0 = blockIdx.y * 128;

    const int ar = tid >> 2;          // 0..63
    const int ac = (tid & 3) << 2;    // 0,4,8,12

    float acc[8][8];
#pragma unroll
    for (int i = 0; i < 8; ++i)
#pragma unroll
        for (int j = 0; j < 8; ++j) acc[i][j] = 0.f;

    for (int k0 = 0; k0 < D_; k0 += 16) {
        float4 a0 = *(const float4*)&A[(size_t)(m0 + ar) * D_ + k0 + ac];
        float4 a1 = *(const float4*)&A[(size_t)(m0 + ar + 64) * D_ + k0 + ac];
        float4 w0 = *(const float4*)&W[(size_t)(n0 + ar) * D_ + k0 + ac];
        float4 w1 = *(const float4*)&W[(size_t)(n0 + ar + 64) * D_ + k0 + ac];
        __syncthreads();
        As[ac + 0][ar] = a0.x; As[ac + 1][ar] = a0.y; As[ac + 2][ar] = a0.z; As[ac + 3][ar] = a0.w;
        As[ac + 0][ar + 64] = a1.x; As[ac + 1][ar + 64] = a1.y; As[ac + 2][ar + 64] = a1.z; As[ac + 3][ar + 64] = a1.w;
        Bs[ac + 0][ar] = w0.x; Bs[ac + 1][ar] = w0.y; Bs[ac + 2][ar] = w0.z; Bs[ac + 3][ar] = w0.w;
        Bs[ac + 0][ar + 64] = w1.x; Bs[ac + 1][ar + 64] = w1.y; Bs[ac + 2][ar + 64] = w1.z; Bs[ac + 3][ar + 64] = w1.w;
        __syncthreads();
#pragma unroll
        for (int kk = 0; kk < 16; ++kk) {
            float av[8], bv[8];
            *(float4*)&av[0] = *(const float4*)&As[kk][ty * 8];
            *(float4*)&av[4] = *(const float4*)&As[kk][ty * 8 + 4];
            *(float4*)&bv[0] = *(const float4*)&Bs[kk][tx * 8];
            *(float4*)&bv[4] = *(const float4*)&Bs[kk][tx * 8 + 4];
#pragma unroll
            for (int i = 0; i < 8; ++i)
#pragma unroll
                for (int j = 0; j < 8; ++j)
                    acc[i][j] = fmaf(av[i], bv[j], acc[i][j]);
        }
    }

#pragma unroll
    for (int i = 0; i < 8; ++i) {
        const int m = m0 + ty * 8 + i;
#pragma unroll
        for (int j = 0; j < 8; ++j) {
            const int n = n0 + tx * 8 + j;
            float c = acc[i][j] + bias[n];
            if (do_sig) c = 1.f / (1.f + expf(-c));
            if (out_bf16) ((uint16_t*)out)[(size_t)m * D_ + n] = f2bf(c);
            else          ((float*)out)[(size_t)m * D_ + n] = c;
        }
    }
}

// ---------------- recurrence scan -------------------------------------------------
// grid (4 dk-groups of 128, 8 dv-groups of 64, B). block 512.
// thread: dkc = tid&15 -> 8 dk elems; dvc = tid>>4 -> 2 dv elems. state s[8][2] fp32.
// per t: s = g*s + k*v ; partial = q.s ; butterfly-reduce over 16 lanes; atomicAdd O.
__global__ __launch_bounds__(512) void scan_kernel(const uint16_t* __restrict__ Qb,
                                                   const uint16_t* __restrict__ Kb,
                                                   const uint16_t* __restrict__ Vb,
                                                   const float* __restrict__ Gf,
                                                   float* __restrict__ O)
{
    const int b   = blockIdx.z;
    const int tid = threadIdx.x;
    const int dkc = tid & 15;
    const int dvc = tid >> 4;
    const int dk  = blockIdx.x * 128 + dkc * 8;
    const int dv  = blockIdx.y * 64 + dvc * 2;

    const size_t base = (size_t)b * S_ * D_;
    const uint16_t* kp = Kb + base + dk;
    const uint16_t* qp = Qb + base + dk;
    const float*    gp = Gf + base + dk;
    const uint16_t* vp = Vb + base + dv;
    float*          op = O  + base + dv;

    float s[8][2];
#pragma unroll
    for (int i = 0; i < 8; ++i) { s[i][0] = 0.f; s[i][1] = 0.f; }

    for (int t = 0; t < S_; ++t) {
        const uint4  ku = *(const uint4*)kp;
        const uint4  qu = *(const uint4*)qp;
        const float4 g0 = *(const float4*)gp;
        const float4 g1 = *(const float4*)(gp + 4);
        const uint32_t vu = *(const uint32_t*)vp;
        const float v0 = bflo(vu), v1 = bfhi(vu);

        float a0 = 0.f, a1 = 0.f;
        const uint32_t kw[4] = {ku.x, ku.y, ku.z, ku.w};
        const uint32_t qw[4] = {qu.x, qu.y, qu.z, qu.w};
        const float    gw[8] = {g0.x, g0.y, g0.z, g0.w, g1.x, g1.y, g1.z, g1.w};
#pragma unroll
        for (int p = 0; p < 4; ++p) {
            const float ke = bflo(kw[p]), ko = bfhi(kw[p]);
            const float qe = bflo(qw[p]), qo = bfhi(qw[p]);
            const float ge = gw[2 * p], go = gw[2 * p + 1];
            s[2 * p][0]     = fmaf(ge, s[2 * p][0],     ke * v0);
            s[2 * p][1]     = fmaf(ge, s[2 * p][1],     ke * v1);
            s[2 * p + 1][0] = fmaf(go, s[2 * p + 1][0], ko * v0);
            s[2 * p + 1][1] = fmaf(go, s[2 * p + 1][1], ko * v1);
            a0 = fmaf(qe, s[2 * p][0], a0);
            a0 = fmaf(qo, s[2 * p + 1][0], a0);
            a1 = fmaf(qe, s[2 * p][1], a1);
            a1 = fmaf(qo, s[2 * p + 1][1], a1);
        }
#pragma unroll
        for (int off = 1; off < 16; off <<= 1) {
            a0 += __shfl_xor(a0, off);
            a1 += __shfl_xor(a1, off);
        }
        if (dkc == 0) {
            atomicAdd(op, a0);
            atomicAdd(op + 1, a1);
        }
        kp += D_; qp += D_; gp += D_; vp += D_; op += D_;
    }
}

// ---------------- launch ----------------------------------------------------------
extern "C" void kernel_launch(void* const* d_in, const int* in_sizes, int n_in,
                              void* d_out, int out_size, void* d_ws, size_t ws_size,
                              hipStream_t stream)
{
    (void)in_sizes; (void)n_in; (void)out_size; (void)ws_size;

    const float* x  = (const float*)d_in[0];
    const float* Wq = (const float*)d_in[1];  const float* bq = (const float*)d_in[2];
    const float* Wk = (const float*)d_in[3];  const float* bk = (const float*)d_in[4];
    const float* Wv = (const float*)d_in[5];  const float* bv = (const float*)d_in[6];
    const float* Wg = (const float*)d_in[7];  const float* bg = (const float*)d_in[8];
    const float* Wo = (const float*)d_in[9];  const float* bo = (const float*)d_in[10];

    const size_t MD = (size_t)M_ * D_;
    uint16_t* Qb = (uint16_t*)d_ws;
    uint16_t* Kb = Qb + MD;
    uint16_t* Vb = Kb + MD;
    float*    Gf = (float*)(Vb + MD);
    float*    O  = Gf + MD;

    hipMemsetAsync(O, 0, MD * sizeof(float), stream);

    dim3 gg(M_ / 128, D_ / 128), bb(256);
    gemm_nt<<<gg, bb, 0, stream>>>(x, Wq, bq, (void*)Qb, 1, 0);
    gemm_nt<<<gg, bb, 0, stream>>>(x, Wk, bk, (void*)Kb, 1, 0);
    gemm_nt<<<gg, bb, 0, stream>>>(x, Wv, bv, (void*)Vb, 1, 0);
    gemm_nt<<<gg, bb, 0, stream>>>(x, Wg, bg, (void*)Gf, 0, 1);

    scan_kernel<<<dim3(4, 8, B_), 512, 0, stream>>>(Qb, Kb, Vb, Gf, O);

    gemm_nt<<<gg, bb, 0, stream>>>(O, Wo, bo, d_out, 0, 0);
}

// Round 2
// 919.638 us; speedup vs baseline: 2.6565x; 2.6565x over previous
//
#include <hip/hip_runtime.h>
#include <hip/hip_bf16.h>
#include <stdint.h>

// SRALayer R2: bf16 MFMA projections + restructured latency-tolerant scan.
//  conv_x / conv_w : fp32 -> bf16 (vectorized)
//  mfma_gemm       : C = A(bf16, MxK) @ W^T(bf16, NxK) + bias; modes: f32 / bf16 / sigmoid->bf16
//  scan2           : S_t = g ⊙ S_{t-1} + k v^T ; out = q·S.  Block = (batch, 16-dv slice),
//                    thread owns 8dk x 2dv state; deferred 8-step batched 64-lane reduce; no atomics.
// ws: [xb|Ob 32MB][Wb 2.5MB][Qb 32][Kb 32][Vb 32][Gb 32] = 162.5MB

#define B_ 8
#define S_ 2048
#define D_ 512
#define M_ (B_ * S_)

typedef __bf16 bf16x8 __attribute__((ext_vector_type(8)));
typedef float f32x4 __attribute__((ext_vector_type(4)));

__device__ __forceinline__ float bflo(uint32_t u) { return __uint_as_float(u << 16); }
__device__ __forceinline__ float bfhi(uint32_t u) { return __uint_as_float(u & 0xffff0000u); }
__device__ __forceinline__ uint16_t f2bf(float f) {
    uint32_t u = __float_as_uint(f);
    return (uint16_t)((u + 0x7fffu + ((u >> 16) & 1u)) >> 16);   // RNE
}
__device__ __forceinline__ uint32_t pack2bf(float a, float b) {
    return (uint32_t)f2bf(a) | ((uint32_t)f2bf(b) << 16);
}
__device__ __forceinline__ void unpack8(uint4 u, float* f) {
    f[0] = bflo(u.x); f[1] = bfhi(u.x);
    f[2] = bflo(u.y); f[3] = bfhi(u.y);
    f[4] = bflo(u.z); f[5] = bfhi(u.z);
    f[6] = bflo(u.w); f[7] = bfhi(u.w);
}

// ---------------- fp32 -> bf16 converters -----------------------------------------
__global__ __launch_bounds__(256) void conv_x(const float* __restrict__ in,
                                              uint16_t* __restrict__ out) {
    const size_t i = ((size_t)blockIdx.x * 256 + threadIdx.x) * 8;
    float4 a = *(const float4*)&in[i];
    float4 b = *(const float4*)&in[i + 4];
    uint4 o;
    o.x = pack2bf(a.x, a.y); o.y = pack2bf(a.z, a.w);
    o.z = pack2bf(b.x, b.y); o.w = pack2bf(b.z, b.w);
    *(uint4*)&out[i] = o;
}

__global__ __launch_bounds__(256) void conv_w(const float* __restrict__ w0, const float* __restrict__ w1,
                                              const float* __restrict__ w2, const float* __restrict__ w3,
                                              const float* __restrict__ w4, uint16_t* __restrict__ out) {
    const float* ws[5] = {w0, w1, w2, w3, w4};
    const float* in = ws[blockIdx.y];
    uint16_t* o = out + (size_t)blockIdx.y * D_ * D_;
    const size_t i = ((size_t)blockIdx.x * 256 + threadIdx.x) * 8;
    float4 a = *(const float4*)&in[i];
    float4 b = *(const float4*)&in[i + 4];
    uint4 u;
    u.x = pack2bf(a.x, a.y); u.y = pack2bf(a.z, a.w);
    u.z = pack2bf(b.x, b.y); u.w = pack2bf(b.z, b.w);
    *(uint4*)&o[i] = u;
}

// ---------------- bf16 MFMA GEMM (NT), 128x128 tile, BK=64, 4 waves ---------------
__device__ __forceinline__ void gload_lds16(const uint16_t* g, uint16_t* l) {
    __builtin_amdgcn_global_load_lds(
        (const __attribute__((address_space(1))) uint32_t*)g,
        (__attribute__((address_space(3))) uint32_t*)l, 16, 0, 0);
}

// mode: 0 = fp32 out, 1 = bf16 out, 2 = sigmoid -> bf16 out
__global__ __launch_bounds__(256) void mfma_gemm(const uint16_t* __restrict__ A,
                                                 const uint16_t* __restrict__ Wt,
                                                 const float* __restrict__ bias,
                                                 void* __restrict__ out, const int mode)
{
    __shared__ __attribute__((aligned(16))) uint16_t As[128 * 64];
    __shared__ __attribute__((aligned(16))) uint16_t Bs[128 * 64];

    const int tid  = threadIdx.x;
    const int wave = tid >> 6;
    const int lane = tid & 63;
    const int m0 = blockIdx.x * 128;
    const int n0 = blockIdx.y * 128;

    const int wr = (wave >> 1) * 64;
    const int wc = (wave & 1) * 64;
    const int fr = lane & 15;          // A-row / B-col / D-col within 16
    const int fq = lane >> 4;          // k-octet; D-row quad

    f32x4 acc[4][4] = {};

    for (int k0 = 0; k0 < D_; k0 += 64) {
        __syncthreads();
#pragma unroll
        for (int i = 0; i < 4; ++i) {
            const int c = i * 256 + tid;                // chunk 0..1023 (16B each)
            const int row = c >> 3, kc = (c & 7) * 8;
            const int ldsb = (i * 256 + wave * 64) * 8; // wave-uniform base, +lane*16B by HW
            gload_lds16(&A [(size_t)(m0 + row) * D_ + k0 + kc], &As[ldsb]);
            gload_lds16(&Wt[(size_t)(n0 + row) * D_ + k0 + kc], &Bs[ldsb]);
        }
        __syncthreads();
#pragma unroll
        for (int kk = 0; kk < 64; kk += 32) {
            bf16x8 af[4], bf[4];
#pragma unroll
            for (int m = 0; m < 4; ++m)
                af[m] = *(const bf16x8*)&As[(wr + m * 16 + fr) * 64 + kk + fq * 8];
#pragma unroll
            for (int n = 0; n < 4; ++n)
                bf[n] = *(const bf16x8*)&Bs[(wc + n * 16 + fr) * 64 + kk + fq * 8];
#pragma unroll
            for (int m = 0; m < 4; ++m)
#pragma unroll
                for (int n = 0; n < 4; ++n)
                    acc[m][n] = __builtin_amdgcn_mfma_f32_16x16x32_bf16(af[m], bf[n], acc[m][n], 0, 0, 0);
        }
    }

#pragma unroll
    for (int n = 0; n < 4; ++n) {
        const int col = n0 + wc + n * 16 + fr;
        const float bv = bias[col];
#pragma unroll
        for (int m = 0; m < 4; ++m) {
#pragma unroll
            for (int q = 0; q < 4; ++q) {
                const int row = m0 + wr + m * 16 + fq * 4 + q;
                float c = acc[m][n][q] + bv;
                if (mode == 2) c = 1.f / (1.f + __expf(-c));
                if (mode == 0) ((float*)out)[(size_t)row * D_ + col] = c;
                else           ((uint16_t*)out)[(size_t)row * D_ + col] = f2bf(c);
            }
        }
    }
}

// ---------------- recurrence scan (v2) --------------------------------------------
// grid (32 dv-slices of 16, B). block 512 = 8 waves; wave = dvc (2 dv), lane = dkc (8 dk).
__global__ __launch_bounds__(512) void scan2(const uint16_t* __restrict__ Qb,
                                             const uint16_t* __restrict__ Kb,
                                             const uint16_t* __restrict__ Vb,
                                             const uint16_t* __restrict__ Gb,
                                             uint16_t* __restrict__ Ob)
{
    const int b   = blockIdx.y;
    const int dv0 = blockIdx.x * 16;
    const int tid = threadIdx.x;
    const int dkc = tid & 63;
    const int dvc = tid >> 6;          // 0..7 (one per wave)
    const int dk0 = dkc * 8;
    const int dv  = dv0 + dvc * 2;

    const size_t base = (size_t)b * S_ * D_;
    const uint16_t* kp = Kb + base + dk0;
    const uint16_t* qp = Qb + base + dk0;
    const uint16_t* gp = Gb + base + dk0;
    const uint16_t* vp = Vb + base + dv;
    uint16_t*       op = Ob + base + dv;

    float s[8][2];
#pragma unroll
    for (int i = 0; i < 8; ++i) { s[i][0] = 0.f; s[i][1] = 0.f; }

    uint4 kc = *(const uint4*)kp;
    uint4 qc = *(const uint4*)qp;
    uint4 gc = *(const uint4*)gp;
    uint32_t vc = *(const uint32_t*)vp;

    for (int t0 = 0; t0 < S_; t0 += 8) {
        float acc[8][2];
#pragma unroll
        for (int tb = 0; tb < 8; ++tb) {
            const int adv = (t0 + tb + 1 < S_) ? D_ : 0;   // depth-1 prefetch
            uint4 kn = *(const uint4*)(kp + adv);
            uint4 qn = *(const uint4*)(qp + adv);
            uint4 gn = *(const uint4*)(gp + adv);
            uint32_t vn = *(const uint32_t*)(vp + adv);
            kp += adv; qp += adv; gp += adv; vp += adv;

            float k[8], q[8], g[8];
            unpack8(kc, k); unpack8(qc, q); unpack8(gc, g);
            const float v0 = bflo(vc), v1 = bfhi(vc);
            float a0 = 0.f, a1 = 0.f;
#pragma unroll
            for (int i = 0; i < 8; ++i) {
                s[i][0] = fmaf(g[i], s[i][0], k[i] * v0);
                s[i][1] = fmaf(g[i], s[i][1], k[i] * v1);
                a0 = fmaf(q[i], s[i][0], a0);
                a1 = fmaf(q[i], s[i][1], a1);
            }
            acc[tb][0] = a0; acc[tb][1] = a1;
            kc = kn; qc = qn; gc = gn; vc = vn;
        }
        // 16 independent 64-lane reductions (pipelined shuffle chains)
#pragma unroll
        for (int off = 1; off < 64; off <<= 1) {
#pragma unroll
            for (int tb = 0; tb < 8; ++tb) {
                acc[tb][0] += __shfl_xor(acc[tb][0], off);
                acc[tb][1] += __shfl_xor(acc[tb][1], off);
            }
        }
        if (dkc == 0) {
#pragma unroll
            for (int tb = 0; tb < 8; ++tb)
                *(uint32_t*)&op[(size_t)(t0 + tb) * D_] = pack2bf(acc[tb][0], acc[tb][1]);
        }
    }
}

// ---------------- launch ----------------------------------------------------------
extern "C" void kernel_launch(void* const* d_in, const int* in_sizes, int n_in,
                              void* d_out, int out_size, void* d_ws, size_t ws_size,
                              hipStream_t stream)
{
    (void)in_sizes; (void)n_in; (void)out_size; (void)ws_size;

    const float* x  = (const float*)d_in[0];
    const float* Wq = (const float*)d_in[1];  const float* bq = (const float*)d_in[2];
    const float* Wk = (const float*)d_in[3];  const float* bk = (const float*)d_in[4];
    const float* Wv = (const float*)d_in[5];  const float* bv = (const float*)d_in[6];
    const float* Wg = (const float*)d_in[7];  const float* bg = (const float*)d_in[8];
    const float* Wo = (const float*)d_in[9];  const float* bo = (const float*)d_in[10];

    char* w = (char*)d_ws;
    const size_t MD = (size_t)M_ * D_;            // 16M elems
    uint16_t* xb = (uint16_t*)w;                  // 32MB (reused as Ob)
    uint16_t* Wb = (uint16_t*)(w + MD * 2);       // 2.5MB
    uint16_t* Qb = (uint16_t*)(w + MD * 2 + 5 * D_ * D_ * 2);
    uint16_t* Kb = Qb + MD;
    uint16_t* Vb = Kb + MD;
    uint16_t* Gb = Vb + MD;
    uint16_t* Ob = xb;

    conv_x<<<dim3(M_ * D_ / (256 * 8)), 256, 0, stream>>>(x, xb);
    conv_w<<<dim3(D_ * D_ / (256 * 8), 5), 256, 0, stream>>>(Wq, Wk, Wv, Wg, Wo, Wb);

    dim3 gg(M_ / 128, D_ / 128), bb(256);
    mfma_gemm<<<gg, bb, 0, stream>>>(xb, Wb + 0 * D_ * D_, bq, (void*)Qb, 1);
    mfma_gemm<<<gg, bb, 0, stream>>>(xb, Wb + 1 * D_ * D_, bk, (void*)Kb, 1);
    mfma_gemm<<<gg, bb, 0, stream>>>(xb, Wb + 2 * D_ * D_, bv, (void*)Vb, 1);
    mfma_gemm<<<gg, bb, 0, stream>>>(xb, Wb + 3 * D_ * D_, bg, (void*)Gb, 2);

    scan2<<<dim3(32, B_), 512, 0, stream>>>(Qb, Kb, Vb, Gb, Ob);

    mfma_gemm<<<gg, bb, 0, stream>>>(Ob, Wb + 4 * D_ * D_, bo, d_out, 0);
}

// Round 3
// 394.998 us; speedup vs baseline: 6.1848x; 2.3282x over previous
//
#include <hip/hip_runtime.h>
#include <hip/hip_bf16.h>
#include <stdint.h>

// SRALayer R3: fully-MFMA chunked gated linear attention.
//   sub-chunk = 32 steps (local cumprod mu, fp32, bounded), super-chunk = 256 steps.
//   q~ = q*mu ; k~ = k/mu ; all cross/inter/state decays are products<=1 folded on LDS-stage.
//   S boundary states stored per super-chunk (7 per batch), bf16 [dv][dk].
// Pipeline: convs -> 4 proj GEMMs (Q,K bf16; V transposed bf16; G fp32 sigmoid)
//   -> prep (mu cumprod; Q~ in-place; K~T transposed; T table)
//   -> tables (Pre/Suf/Lam) -> dsgemm (dS per super -> S) -> scanfix (7-step state scan)
//   -> pass3 (inter + crosses + masked self, all MFMA) -> output proj.

#define B_ 8
#define S_ 2048
#define D_ 512
#define M_ (B_ * S_)
#define NSUB 64
#define SUBL 32
#define NSUP 8
#define SUPL 256

typedef __bf16 bf16x8 __attribute__((ext_vector_type(8)));
typedef float f32x4 __attribute__((ext_vector_type(4)));

__device__ __forceinline__ float bflo(uint32_t u){ return __uint_as_float(u<<16); }
__device__ __forceinline__ float bfhi(uint32_t u){ return __uint_as_float(u&0xffff0000u); }
__device__ __forceinline__ uint16_t f2bf(float f){
    uint32_t u = __float_as_uint(f);
    return (uint16_t)((u + 0x7fffu + ((u>>16)&1u)) >> 16);
}
__device__ __forceinline__ uint32_t pack2bf(float a, float b){
    return (uint32_t)f2bf(a) | ((uint32_t)f2bf(b)<<16);
}
__device__ __forceinline__ void gload16(const void* g, void* l){
    __builtin_amdgcn_global_load_lds(
        (const __attribute__((address_space(1))) uint32_t*)g,
        (__attribute__((address_space(3))) uint32_t*)l, 16, 0, 0);
}

// ---------------- fp32 -> bf16 converters -----------------------------------------
__global__ __launch_bounds__(256) void conv_x(const float* __restrict__ in,
                                              uint16_t* __restrict__ out){
    const size_t i = ((size_t)blockIdx.x*256 + threadIdx.x)*8;
    float4 a = *(const float4*)&in[i];
    float4 b = *(const float4*)&in[i+4];
    uint4 o; o.x=pack2bf(a.x,a.y); o.y=pack2bf(a.z,a.w); o.z=pack2bf(b.x,b.y); o.w=pack2bf(b.z,b.w);
    *(uint4*)&out[i] = o;
}
__global__ __launch_bounds__(256) void conv_w(const float* w0, const float* w1, const float* w2,
                                              const float* w3, const float* w4,
                                              uint16_t* __restrict__ out){
    const float* ws[5] = {w0,w1,w2,w3,w4};
    const float* in = ws[blockIdx.y];
    uint16_t* o = out + (size_t)blockIdx.y*D_*D_;
    const size_t i = ((size_t)blockIdx.x*256 + threadIdx.x)*8;
    float4 a = *(const float4*)&in[i];
    float4 b = *(const float4*)&in[i+4];
    uint4 u; u.x=pack2bf(a.x,a.y); u.y=pack2bf(a.z,a.w); u.z=pack2bf(b.x,b.y); u.w=pack2bf(b.z,b.w);
    *(uint4*)&o[i] = u;
}

// ---------------- bf16 MFMA GEMM (NT), 128x128 tile, BK=64 ------------------------
// mode 0: fp32 out (+bias)   1: bf16 out   2: sigmoid -> fp32 out   3: bf16 out transposed VT[b][dv][t]
__global__ __launch_bounds__(256) void mfma_gemm(const uint16_t* __restrict__ A,
                                                 const uint16_t* __restrict__ Wt,
                                                 const float* __restrict__ bias,
                                                 void* __restrict__ out, const int mode)
{
    __shared__ __attribute__((aligned(16))) uint16_t As[128*64];
    __shared__ __attribute__((aligned(16))) uint16_t Bs[128*64];
    const int tid = threadIdx.x, wave = tid>>6, lane = tid&63;
    const int m0 = blockIdx.x*128, n0 = blockIdx.y*128;
    const int wr = (wave>>1)*64, wc = (wave&1)*64;
    const int fr = lane&15, fq = lane>>4;
    f32x4 acc[4][4] = {};

    for (int k0 = 0; k0 < D_; k0 += 64) {
        __syncthreads();
#pragma unroll
        for (int i = 0; i < 4; ++i) {
            const int c = i*256 + tid;
            const int row = c>>3, kc = (c&7)*8;
            const int ldsb = (i*256 + wave*64)*8;
            gload16(&A [(size_t)(m0+row)*D_ + k0 + kc], &As[ldsb]);
            gload16(&Wt[(size_t)(n0+row)*D_ + k0 + kc], &Bs[ldsb]);
        }
        __syncthreads();
#pragma unroll
        for (int kk = 0; kk < 64; kk += 32) {
            bf16x8 af[4], bf[4];
#pragma unroll
            for (int m = 0; m < 4; ++m) af[m] = *(const bf16x8*)&As[(wr+m*16+fr)*64 + kk + fq*8];
#pragma unroll
            for (int n = 0; n < 4; ++n) bf[n] = *(const bf16x8*)&Bs[(wc+n*16+fr)*64 + kk + fq*8];
#pragma unroll
            for (int m = 0; m < 4; ++m)
#pragma unroll
                for (int n = 0; n < 4; ++n)
                    acc[m][n] = __builtin_amdgcn_mfma_f32_16x16x32_bf16(af[m], bf[n], acc[m][n], 0,0,0);
        }
    }
#pragma unroll
    for (int n = 0; n < 4; ++n) {
        const int col = n0 + wc + n*16 + fr;
        const float bv = bias[col];
        if (mode == 3) {
#pragma unroll
            for (int m = 0; m < 4; ++m) {
                const int rg = m0 + wr + m*16 + fq*4;
                const int bb = rg >> 11, t = rg & 2047;
                uint2 pk;
                pk.x = pack2bf(acc[m][n][0]+bv, acc[m][n][1]+bv);
                pk.y = pack2bf(acc[m][n][2]+bv, acc[m][n][3]+bv);
                *(uint2*)&((uint16_t*)out)[((size_t)bb*D_ + col)*S_ + t] = pk;
            }
        } else {
#pragma unroll
            for (int m = 0; m < 4; ++m)
#pragma unroll
                for (int q = 0; q < 4; ++q) {
                    const int row = m0 + wr + m*16 + fq*4 + q;
                    float c = acc[m][n][q] + bv;
                    if (mode == 2) c = 1.f/(1.f+expf(-c));
                    if (mode == 1) ((uint16_t*)out)[(size_t)row*D_ + col] = f2bf(c);
                    else           ((float*)out)[(size_t)row*D_ + col] = c;
                }
        }
    }
}

// ---------------- prep: mu cumprod, Q~ in-place, K~T transposed, T ------------------
__global__ __launch_bounds__(256) void prep(const float* __restrict__ Gf,
                                            uint16_t* __restrict__ Qb,
                                            const uint16_t* __restrict__ Kb,
                                            uint16_t* __restrict__ KT,
                                            float* __restrict__ T)
{
    __shared__ __attribute__((aligned(16))) float    gt[SUBL][D_];
    __shared__ __attribute__((aligned(16))) uint16_t qt[SUBL][D_];
    __shared__ __attribute__((aligned(16))) uint16_t kt[SUBL][D_];
    const int sub = blockIdx.x, b = blockIdx.y;
    const int tid = threadIdx.x, wave = tid>>6, lane = tid&63;
    const size_t rowbase = ((size_t)b*S_ + sub*SUBL)*D_;

#pragma unroll
    for (int r = 0; r < 16; ++r) {   // gt: 4096 x 16B
        int c = r*256 + wave*64;
        gload16((const char*)Gf + rowbase*4 + (size_t)(c+lane)*16, (char*)&gt[0][0] + (size_t)c*16);
    }
#pragma unroll
    for (int r = 0; r < 8; ++r) {    // qt/kt: 2048 x 16B each
        int c = r*256 + wave*64;
        gload16((const char*)Qb + rowbase*2 + (size_t)(c+lane)*16, (char*)&qt[0][0] + (size_t)c*16);
        gload16((const char*)Kb + rowbase*2 + (size_t)(c+lane)*16, (char*)&kt[0][0] + (size_t)c*16);
    }
    __syncthreads();

    const int dk0 = tid*2;
    float mu0 = 1.f, mu1 = 1.f;
    for (int t = 0; t < SUBL; ++t) {
        mu0 *= gt[t][dk0];   mu0 = fmaxf(mu0, 1e-30f);
        mu1 *= gt[t][dk0+1]; mu1 = fmaxf(mu1, 1e-30f);
        qt[t][dk0]   = f2bf(bflo((uint32_t)qt[t][dk0])   * mu0);
        qt[t][dk0+1] = f2bf(bflo((uint32_t)qt[t][dk0+1]) * mu1);
        kt[t][dk0]   = f2bf(bflo((uint32_t)kt[t][dk0])   / mu0);
        kt[t][dk0+1] = f2bf(bflo((uint32_t)kt[t][dk0+1]) / mu1);
    }
    T[((size_t)b*NSUB + sub)*D_ + dk0]     = mu0;
    T[((size_t)b*NSUB + sub)*D_ + dk0 + 1] = mu1;
    __syncthreads();

    {   // write back Q~ rows, coalesced
        const int r = tid>>3, c0 = (tid&7)*64;
#pragma unroll
        for (int e = 0; e < 64; e += 8)
            *(uint4*)&Qb[rowbase + (size_t)r*D_ + c0 + e] = *(uint4*)&qt[r][c0+e];
    }
#pragma unroll
    for (int rr = 0; rr < 2; ++rr) {  // write K~T columns: [dk][32 t] 64B rows
        const int dk = tid*2 + rr;
        uint16_t* dst = &KT[((size_t)b*D_ + dk)*S_ + sub*SUBL];
#pragma unroll
        for (int q4 = 0; q4 < 4; ++q4) {
            uint4 o;
            o.x = (uint32_t)kt[q4*8+0][dk] | ((uint32_t)kt[q4*8+1][dk]<<16);
            o.y = (uint32_t)kt[q4*8+2][dk] | ((uint32_t)kt[q4*8+3][dk]<<16);
            o.z = (uint32_t)kt[q4*8+4][dk] | ((uint32_t)kt[q4*8+5][dk]<<16);
            o.w = (uint32_t)kt[q4*8+6][dk] | ((uint32_t)kt[q4*8+7][dk]<<16);
            *(uint4*)&dst[q4*8] = o;
        }
    }
}

// ---------------- tables: Pre / Suf / Lam from T -----------------------------------
__global__ __launch_bounds__(512) void tables(const float* __restrict__ T,
                                              float* __restrict__ Pre,
                                              float* __restrict__ Suf,
                                              float* __restrict__ Lam)
{
    const int b = blockIdx.x, dk = threadIdx.x;
    for (int sp = 0; sp < NSUP; ++sp) {
        float run = 1.f;
#pragma unroll
        for (int m = 0; m < 8; ++m) {
            Pre[((size_t)b*NSUB + sp*8+m)*D_ + dk] = run;
            run *= T[((size_t)b*NSUB + sp*8+m)*D_ + dk];
        }
        Lam[((size_t)b*NSUP + sp)*D_ + dk] = run;
        float rs = 1.f;
#pragma unroll
        for (int m = 7; m >= 0; --m) {
            rs *= T[((size_t)b*NSUB + sp*8+m)*D_ + dk];
            Suf[((size_t)b*NSUB + sp*8+m)*D_ + dk] = rs;
        }
    }
}

// ---------------- dsgemm: S[c] = dS_c = sum_u khat_u v_u^T  (stored [dv][dk]) ------
__global__ __launch_bounds__(256) void dsgemm(const uint16_t* __restrict__ VT,
                                              const uint16_t* __restrict__ KT,
                                              const float* __restrict__ Suf,
                                              uint16_t* __restrict__ Sst)
{
    __shared__ __attribute__((aligned(16))) uint16_t As[128][40];  // [dv][t32]
    __shared__ __attribute__((aligned(16))) uint16_t Bs[128][40];  // [dk][t32] suffix-scaled
    const int tile = blockIdx.x, c = blockIdx.y, b = blockIdx.z;
    const int m0 = (tile&3)*128, n0 = (tile>>2)*128;
    const int tid = threadIdx.x, wave = tid>>6, lane = tid&63;
    const int wr = (wave>>1)*64, wc = (wave&1)*64;
    const int fr = lane&15, fq = lane>>4;
    f32x4 acc[4][4] = {};

    for (int j = 0; j < 8; ++j) {
        const int t0 = c*SUPL + j*SUBL;
        __syncthreads();
#pragma unroll
        for (int ch = tid; ch < 512; ch += 256) {
            int row = ch>>2, tc = (ch&3)*8;
            *(uint4*)&As[row][tc] = *(const uint4*)&VT[((size_t)b*D_ + m0+row)*S_ + t0 + tc];
        }
#pragma unroll
        for (int ch = tid; ch < 512; ch += 256) {
            int row = ch>>2, tc = (ch&3)*8;
            uint4 u = *(const uint4*)&KT[((size_t)b*D_ + n0+row)*S_ + t0 + tc];
            float sf = Suf[((size_t)b*NSUB + c*8 + j)*D_ + n0 + row];
            uint4 o;
            o.x = pack2bf(bflo(u.x)*sf, bfhi(u.x)*sf);
            o.y = pack2bf(bflo(u.y)*sf, bfhi(u.y)*sf);
            o.z = pack2bf(bflo(u.z)*sf, bfhi(u.z)*sf);
            o.w = pack2bf(bflo(u.w)*sf, bfhi(u.w)*sf);
            *(uint4*)&Bs[row][tc] = o;
        }
        __syncthreads();
        bf16x8 af[4], bf[4];
#pragma unroll
        for (int m = 0; m < 4; ++m) af[m] = *(const bf16x8*)&As[wr+m*16+fr][fq*8];
#pragma unroll
        for (int n = 0; n < 4; ++n) bf[n] = *(const bf16x8*)&Bs[wc+n*16+fr][fq*8];
#pragma unroll
        for (int m = 0; m < 4; ++m)
#pragma unroll
            for (int n = 0; n < 4; ++n)
                acc[m][n] = __builtin_amdgcn_mfma_f32_16x16x32_bf16(af[m], bf[n], acc[m][n], 0,0,0);
    }
#pragma unroll
    for (int n = 0; n < 4; ++n) {
        const int dk = n0 + wc + n*16 + fr;
#pragma unroll
        for (int m = 0; m < 4; ++m)
#pragma unroll
            for (int q = 0; q < 4; ++q) {
                const int dv = m0 + wr + m*16 + fq*4 + q;
                Sst[(((size_t)c*B_ + b)*D_ + dv)*D_ + dk] = f2bf(acc[m][n][q]);
            }
    }
}

// ---------------- scanfix: S_c = Lam_c (x) S_{c-1} + dS_c, c = 1..6 ----------------
__global__ __launch_bounds__(256) void scanfix(uint16_t* __restrict__ Sst,
                                               const float* __restrict__ Lam)
{
    const int id = blockIdx.x*256 + threadIdx.x;      // 0..262143
    const int g = id & 63, dv = (id>>6) & 511, b = id >> 15;
    const int dk = g*8;
    float s[8];
    {
        uint4 u = *(const uint4*)&Sst[(((size_t)0*B_ + b)*D_ + dv)*D_ + dk];
        s[0]=bflo(u.x); s[1]=bfhi(u.x); s[2]=bflo(u.y); s[3]=bfhi(u.y);
        s[4]=bflo(u.z); s[5]=bfhi(u.z); s[6]=bflo(u.w); s[7]=bfhi(u.w);
    }
    for (int c = 1; c < 7; ++c) {
        const size_t bs = (((size_t)c*B_ + b)*D_ + dv)*D_ + dk;
        uint4 d = *(const uint4*)&Sst[bs];
        float4 l0 = *(const float4*)&Lam[((size_t)b*NSUP + c)*D_ + dk];
        float4 l1 = *(const float4*)&Lam[((size_t)b*NSUP + c)*D_ + dk + 4];
        s[0] = l0.x*s[0] + bflo(d.x); s[1] = l0.y*s[1] + bfhi(d.x);
        s[2] = l0.z*s[2] + bflo(d.y); s[3] = l0.w*s[3] + bfhi(d.y);
        s[4] = l1.x*s[4] + bflo(d.z); s[5] = l1.y*s[5] + bfhi(d.z);
        s[6] = l1.z*s[6] + bflo(d.w); s[7] = l1.w*s[7] + bfhi(d.w);
        uint4 o;
        o.x = pack2bf(s[0],s[1]); o.y = pack2bf(s[2],s[3]);
        o.z = pack2bf(s[4],s[5]); o.w = pack2bf(s[6],s[7]);
        *(uint4*)&Sst[bs] = o;
    }
}

// ---------------- pass3: out = q~ @ S_eff + crosses + masked self ------------------
__global__ __launch_bounds__(256, 2) void pass3(const uint16_t* __restrict__ Qt,
                                                const uint16_t* __restrict__ KT,
                                                const uint16_t* __restrict__ VT,
                                                const uint16_t* __restrict__ Sst,
                                                const float* __restrict__ T,
                                                const float* __restrict__ Pre,
                                                uint16_t* __restrict__ O)
{
    __shared__ __attribute__((aligned(16))) uint16_t qs[SUBL][520];
    __shared__ __attribute__((aligned(16))) uint16_t scr[512*40];
    __shared__ __attribute__((aligned(16))) float    abf32[SUBL][33];
    __shared__ __attribute__((aligned(16))) uint16_t abf16[SUBL][40];

    const int sg = blockIdx.x, b = blockIdx.y;
    const int sp = sg>>3, i = sg&7;
    const int tid = threadIdx.x, wave = tid>>6, lane = tid&63;
    const int fr = lane&15, fq = lane>>4;
    const int t0g = sg*SUBL;
    const int wdv = wave*128;

    f32x4 acc[2][8] = {};

    // P0: stage Q~ tile
    for (int ch = tid; ch < 2048; ch += 256) {
        int r = ch>>6, c8 = (ch&63)*8;
        *(uint4*)&qs[r][c8] = *(const uint4*)&Qt[((size_t)b*S_ + t0g + r)*D_ + c8];
    }
    __syncthreads();

    // P1: inter-chunk term (S_prev row-scaled by Pre_i)
    if (sp > 0) {
        uint16_t (*interB)[40] = (uint16_t(*)[40])scr;
        const size_t sbase = ((size_t)(sp-1)*B_ + b)*D_*D_;
        const float* pre = &Pre[((size_t)b*NSUB + sg)*D_];
        for (int kt = 0; kt < 16; ++kt) {
            __syncthreads();
            for (int ch = tid; ch < 2048; ch += 256) {
                int row = ch>>2, c8 = (ch&3)*8;
                int dk = kt*32 + c8;
                uint4 u = *(const uint4*)&Sst[sbase + (size_t)row*D_ + dk];
                uint4 o;
                o.x = pack2bf(bflo(u.x)*pre[dk+0], bfhi(u.x)*pre[dk+1]);
                o.y = pack2bf(bflo(u.y)*pre[dk+2], bfhi(u.y)*pre[dk+3]);
                o.z = pack2bf(bflo(u.z)*pre[dk+4], bfhi(u.z)*pre[dk+5]);
                o.w = pack2bf(bflo(u.w)*pre[dk+6], bfhi(u.w)*pre[dk+7]);
                *(uint4*)&interB[row][c8] = o;
            }
            __syncthreads();
            bf16x8 af[2], bf[8];
#pragma unroll
            for (int m = 0; m < 2; ++m) af[m] = *(const bf16x8*)&qs[m*16+fr][kt*32 + fq*8];
#pragma unroll
            for (int n = 0; n < 8; ++n) bf[n] = *(const bf16x8*)&interB[wdv + n*16 + fr][fq*8];
#pragma unroll
            for (int m = 0; m < 2; ++m)
#pragma unroll
                for (int n = 0; n < 8; ++n)
                    acc[m][n] = __builtin_amdgcn_mfma_f32_16x16x32_bf16(af[m], bf[n], acc[m][n], 0,0,0);
        }
    }

    // P2/P3: crosses (j = i-1 .. 0) then masked self (j = i)
    float C0 = 1.f, C1 = 1.f;
    const int dkA = tid*2, dkB = tid*2+1;
    for (int jj = 0; jj <= i; ++jj) {
        int j; float cs0, cs1; bool self;
        if (jj < i) {
            j = i-1-jj;
            C0 *= T[((size_t)b*NSUB + sp*8 + j)*D_ + dkA];
            C1 *= T[((size_t)b*NSUB + sp*8 + j)*D_ + dkB];
            cs0 = C0; cs1 = C1; self = false;
        } else { j = i; cs0 = 1.f; cs1 = 1.f; self = true; }
        const int tj = sp*SUPL + j*SUBL;

        __syncthreads();
        // stage k~ transposed [u][dk], scaled by cs
        uint16_t (*kts)[520] = (uint16_t(*)[520])scr;
#pragma unroll
        for (int rr = 0; rr < 2; ++rr) {
            const int dk = tid*2 + rr;
            const float cs = rr ? cs1 : cs0;
            const uint16_t* src = &KT[((size_t)b*D_ + dk)*S_ + tj];
#pragma unroll
            for (int q4 = 0; q4 < 4; ++q4) {
                uint4 u = *(const uint4*)&src[q4*8];
                kts[q4*8+0][dk] = f2bf(bflo(u.x)*cs); kts[q4*8+1][dk] = f2bf(bfhi(u.x)*cs);
                kts[q4*8+2][dk] = f2bf(bflo(u.y)*cs); kts[q4*8+3][dk] = f2bf(bfhi(u.y)*cs);
                kts[q4*8+4][dk] = f2bf(bflo(u.z)*cs); kts[q4*8+5][dk] = f2bf(bfhi(u.z)*cs);
                kts[q4*8+6][dk] = f2bf(bflo(u.w)*cs); kts[q4*8+7][dk] = f2bf(bfhi(u.w)*cs);
            }
        }
#pragma unroll
        for (int z = 0; z < 4; ++z) {
            int idx = tid*4 + z;
            abf32[idx>>5][idx&31] = 0.f;
        }
        __syncthreads();
        // A-GEMM, K-split across waves
        {
            f32x4 pa[2][2] = {};
#pragma unroll
            for (int kk = 0; kk < 4; ++kk) {
                bf16x8 af[2], bfv[2];
#pragma unroll
                for (int m = 0; m < 2; ++m) af[m]  = *(const bf16x8*)&qs [m*16+fr][wave*128 + kk*32 + fq*8];
#pragma unroll
                for (int n = 0; n < 2; ++n) bfv[n] = *(const bf16x8*)&kts[n*16+fr][wave*128 + kk*32 + fq*8];
#pragma unroll
                for (int m = 0; m < 2; ++m)
#pragma unroll
                    for (int n = 0; n < 2; ++n)
                        pa[m][n] = __builtin_amdgcn_mfma_f32_16x16x32_bf16(af[m], bfv[n], pa[m][n], 0,0,0);
            }
#pragma unroll
            for (int m = 0; m < 2; ++m)
#pragma unroll
                for (int n = 0; n < 2; ++n)
#pragma unroll
                    for (int q = 0; q < 4; ++q)
                        atomicAdd(&abf32[m*16 + fq*4 + q][n*16 + fr], pa[m][n][q]);
        }
        __syncthreads();
#pragma unroll
        for (int z = 0; z < 4; ++z) {
            int idx = tid*4 + z, r = idx>>5, cu = idx&31;
            float v = abf32[r][cu];
            abf16[r][cu] = (self && cu > r) ? (uint16_t)0 : f2bf(v);
        }
        __syncthreads();
        // stage V^T tile [dv][u]
        uint16_t (*vts)[40] = (uint16_t(*)[40])scr;
        for (int ch = tid; ch < 2048; ch += 256) {
            int row = ch>>2, tc = (ch&3)*8;
            *(uint4*)&vts[row][tc] = *(const uint4*)&VT[((size_t)b*D_ + row)*S_ + tj + tc];
        }
        __syncthreads();
        // AV
        {
            bf16x8 af[2], bfv[8];
#pragma unroll
            for (int m = 0; m < 2; ++m) af[m] = *(const bf16x8*)&abf16[m*16+fr][fq*8];
#pragma unroll
            for (int n = 0; n < 8; ++n) bfv[n] = *(const bf16x8*)&vts[wdv + n*16 + fr][fq*8];
#pragma unroll
            for (int m = 0; m < 2; ++m)
#pragma unroll
                for (int n = 0; n < 8; ++n)
                    acc[m][n] = __builtin_amdgcn_mfma_f32_16x16x32_bf16(af[m], bfv[n], acc[m][n], 0,0,0);
        }
    }
    // epilogue
#pragma unroll
    for (int n = 0; n < 8; ++n) {
        const int dv = wdv + n*16 + fr;
#pragma unroll
        for (int m = 0; m < 2; ++m)
#pragma unroll
            for (int q = 0; q < 4; ++q) {
                const int t = t0g + m*16 + fq*4 + q;
                O[((size_t)b*S_ + t)*D_ + dv] = f2bf(acc[m][n][q]);
            }
    }
}

// ---------------- launch ----------------------------------------------------------
extern "C" void kernel_launch(void* const* d_in, const int* in_sizes, int n_in,
                              void* d_out, int out_size, void* d_ws, size_t ws_size,
                              hipStream_t stream)
{
    (void)in_sizes; (void)n_in; (void)out_size; (void)ws_size;
    const float* x  = (const float*)d_in[0];
    const float* Wq = (const float*)d_in[1];  const float* bq = (const float*)d_in[2];
    const float* Wk = (const float*)d_in[3];  const float* bk = (const float*)d_in[4];
    const float* Wv = (const float*)d_in[5];  const float* bv = (const float*)d_in[6];
    const float* Wg = (const float*)d_in[7];  const float* bg = (const float*)d_in[8];
    const float* Wo = (const float*)d_in[9];  const float* bo = (const float*)d_in[10];

    char* w = (char*)d_ws;
    const size_t MD2 = (size_t)M_*D_*2;       // 16.78 MB
    uint16_t* Wb = (uint16_t*)w;                       w += 5*(size_t)D_*D_*2;   // 2.62MB
    uint16_t* xb = (uint16_t*)w;                       w += MD2;                 // x, later O
    uint16_t* Qb = (uint16_t*)w;                       w += MD2;                 // Q -> Q~
    uint16_t* Kb = (uint16_t*)w;                       w += MD2;                 // K raw
    uint16_t* KT = (uint16_t*)w;                       w += MD2;                 // K~T [b][dk][t]
    uint16_t* VT = (uint16_t*)w;                       w += MD2;                 // V^T [b][dv][t]
    float*    Gf = (float*)w;                          w += (size_t)M_*D_*4;     // 33.5MB
    uint16_t* Sst = (uint16_t*)w;                      w += (size_t)7*B_*D_*D_*2;// 29.4MB
    float*    T   = (float*)w;                         w += (size_t)B_*NSUB*D_*4;
    float*    Pre = (float*)w;                         w += (size_t)B_*NSUB*D_*4;
    float*    Suf = (float*)w;                         w += (size_t)B_*NSUB*D_*4;
    float*    Lam = (float*)w;                         w += (size_t)B_*NSUP*D_*4;

    conv_x<<<dim3(M_*D_/2048), 256, 0, stream>>>(x, xb);
    conv_w<<<dim3(D_*D_/2048, 5), 256, 0, stream>>>(Wq, Wk, Wv, Wg, Wo, Wb);

    dim3 gg(M_/128, D_/128), bb(256);
    mfma_gemm<<<gg, bb, 0, stream>>>(xb, Wb + 0*(size_t)D_*D_, bq, (void*)Qb, 1);
    mfma_gemm<<<gg, bb, 0, stream>>>(xb, Wb + 1*(size_t)D_*D_, bk, (void*)Kb, 1);
    mfma_gemm<<<gg, bb, 0, stream>>>(xb, Wb + 2*(size_t)D_*D_, bv, (void*)VT, 3);
    mfma_gemm<<<gg, bb, 0, stream>>>(xb, Wb + 3*(size_t)D_*D_, bg, (void*)Gf, 2);

    prep<<<dim3(NSUB, B_), 256, 0, stream>>>(Gf, Qb, Kb, KT, T);
    tables<<<dim3(B_), 512, 0, stream>>>(T, Pre, Suf, Lam);
    dsgemm<<<dim3(16, 7, B_), 256, 0, stream>>>(VT, KT, Suf, Sst);
    scanfix<<<dim3(1024), 256, 0, stream>>>(Sst, Lam);
    pass3<<<dim3(NSUB, B_), 256, 0, stream>>>(Qb, KT, VT, Sst, T, Pre, xb);

    mfma_gemm<<<gg, bb, 0, stream>>>(xb, Wb + 4*(size_t)D_*D_, bo, d_out, 0);
}

// Round 4
// 275.652 us; speedup vs baseline: 8.8625x; 1.4330x over previous
//
#include <hip/hip_runtime.h>
#include <hip/hip_bf16.h>
#include <stdint.h>

// SRALayer R4: chunked GLA, pass3 replaced by pairsA (P-block materialization)
// + bigout (single balanced NT GEMM: O = [Q~*Pre | P] @ [S_prev ; V]).
// sub-chunk 32 (mu fp32 local cumprod), super-chunk 256, 7 stored states/batch.

#define B_ 8
#define S_ 2048
#define D_ 512
#define M_ (B_ * S_)
#define NSUB 64
#define SUBL 32
#define NSUP 8
#define SUPL 256

typedef __bf16 bf16x8 __attribute__((ext_vector_type(8)));
typedef float f32x4 __attribute__((ext_vector_type(4)));

__device__ __forceinline__ float bflo(uint32_t u){ return __uint_as_float(u<<16); }
__device__ __forceinline__ float bfhi(uint32_t u){ return __uint_as_float(u&0xffff0000u); }
__device__ __forceinline__ uint16_t f2bf(float f){
    uint32_t u = __float_as_uint(f);
    return (uint16_t)((u + 0x7fffu + ((u>>16)&1u)) >> 16);
}
__device__ __forceinline__ uint32_t pack2bf(float a, float b){
    return (uint32_t)f2bf(a) | ((uint32_t)f2bf(b)<<16);
}
__device__ __forceinline__ void gload16(const void* g, void* l){
    __builtin_amdgcn_global_load_lds(
        (const __attribute__((address_space(1))) uint32_t*)g,
        (__attribute__((address_space(3))) uint32_t*)l, 16, 0, 0);
}

// ---------------- fp32 -> bf16 converters -----------------------------------------
__global__ __launch_bounds__(256) void conv_x(const float* __restrict__ in,
                                              uint16_t* __restrict__ out){
    const size_t i = ((size_t)blockIdx.x*256 + threadIdx.x)*8;
    float4 a = *(const float4*)&in[i];
    float4 b = *(const float4*)&in[i+4];
    uint4 o; o.x=pack2bf(a.x,a.y); o.y=pack2bf(a.z,a.w); o.z=pack2bf(b.x,b.y); o.w=pack2bf(b.z,b.w);
    *(uint4*)&out[i] = o;
}
__global__ __launch_bounds__(256) void conv_w(const float* w0, const float* w1, const float* w2,
                                              const float* w3, const float* w4,
                                              uint16_t* __restrict__ out){
    const float* ws[5] = {w0,w1,w2,w3,w4};
    const float* in = ws[blockIdx.y];
    uint16_t* o = out + (size_t)blockIdx.y*D_*D_;
    const size_t i = ((size_t)blockIdx.x*256 + threadIdx.x)*8;
    float4 a = *(const float4*)&in[i];
    float4 b = *(const float4*)&in[i+4];
    uint4 u; u.x=pack2bf(a.x,a.y); u.y=pack2bf(a.z,a.w); u.z=pack2bf(b.x,b.y); u.w=pack2bf(b.z,b.w);
    *(uint4*)&o[i] = u;
}

// ---------------- bf16 MFMA GEMM (NT), 128x128 tile, BK=64 ------------------------
// mode 0: fp32 out (+bias)   1: bf16 out   2: sigmoid -> fp32 out   3: bf16 transposed VT
__global__ __launch_bounds__(256) void mfma_gemm(const uint16_t* __restrict__ A,
                                                 const uint16_t* __restrict__ Wt,
                                                 const float* __restrict__ bias,
                                                 void* __restrict__ out, const int mode)
{
    __shared__ __attribute__((aligned(16))) uint16_t As[128*64];
    __shared__ __attribute__((aligned(16))) uint16_t Bs[128*64];
    const int tid = threadIdx.x, wave = tid>>6, lane = tid&63;
    const int m0 = blockIdx.x*128, n0 = blockIdx.y*128;
    const int wr = (wave>>1)*64, wc = (wave&1)*64;
    const int fr = lane&15, fq = lane>>4;
    f32x4 acc[4][4] = {};

    for (int k0 = 0; k0 < D_; k0 += 64) {
        __syncthreads();
#pragma unroll
        for (int i = 0; i < 4; ++i) {
            const int c = i*256 + tid;
            const int row = c>>3, kc = (c&7)*8;
            const int ldsb = (i*256 + wave*64)*8;
            gload16(&A [(size_t)(m0+row)*D_ + k0 + kc], &As[ldsb]);
            gload16(&Wt[(size_t)(n0+row)*D_ + k0 + kc], &Bs[ldsb]);
        }
        __syncthreads();
#pragma unroll
        for (int kk = 0; kk < 64; kk += 32) {
            bf16x8 af[4], bf[4];
#pragma unroll
            for (int m = 0; m < 4; ++m) af[m] = *(const bf16x8*)&As[(wr+m*16+fr)*64 + kk + fq*8];
#pragma unroll
            for (int n = 0; n < 4; ++n) bf[n] = *(const bf16x8*)&Bs[(wc+n*16+fr)*64 + kk + fq*8];
#pragma unroll
            for (int m = 0; m < 4; ++m)
#pragma unroll
                for (int n = 0; n < 4; ++n)
                    acc[m][n] = __builtin_amdgcn_mfma_f32_16x16x32_bf16(af[m], bf[n], acc[m][n], 0,0,0);
        }
    }
#pragma unroll
    for (int n = 0; n < 4; ++n) {
        const int col = n0 + wc + n*16 + fr;
        const float bv = bias[col];
        if (mode == 3) {
#pragma unroll
            for (int m = 0; m < 4; ++m) {
                const int rg = m0 + wr + m*16 + fq*4;
                const int bb = rg >> 11, t = rg & 2047;
                uint2 pk;
                pk.x = pack2bf(acc[m][n][0]+bv, acc[m][n][1]+bv);
                pk.y = pack2bf(acc[m][n][2]+bv, acc[m][n][3]+bv);
                *(uint2*)&((uint16_t*)out)[((size_t)bb*D_ + col)*S_ + t] = pk;
            }
        } else {
#pragma unroll
            for (int m = 0; m < 4; ++m)
#pragma unroll
                for (int q = 0; q < 4; ++q) {
                    const int row = m0 + wr + m*16 + fq*4 + q;
                    float c = acc[m][n][q] + bv;
                    if (mode == 2) c = 1.f/(1.f+expf(-c));
                    if (mode == 1) ((uint16_t*)out)[(size_t)row*D_ + col] = f2bf(c);
                    else           ((float*)out)[(size_t)row*D_ + col] = c;
                }
        }
    }
}

// ---------------- prep: mu cumprod, Q~ & K^ rows in-place, K^T, T ------------------
__global__ __launch_bounds__(256) void prep(const float* __restrict__ Gf,
                                            uint16_t* __restrict__ Qb,
                                            uint16_t* __restrict__ Kb,
                                            uint16_t* __restrict__ KT,
                                            float* __restrict__ T)
{
    __shared__ __attribute__((aligned(16))) float    gt[SUBL][D_];
    __shared__ __attribute__((aligned(16))) uint16_t qt[SUBL][D_];
    __shared__ __attribute__((aligned(16))) uint16_t kt[SUBL][D_];
    const int sub = blockIdx.x, b = blockIdx.y;
    const int tid = threadIdx.x, wave = tid>>6, lane = tid&63;
    const size_t rowbase = ((size_t)b*S_ + sub*SUBL)*D_;

#pragma unroll
    for (int r = 0; r < 16; ++r) {
        int c = r*256 + wave*64;
        gload16((const char*)Gf + rowbase*4 + (size_t)(c+lane)*16, (char*)&gt[0][0] + (size_t)c*16);
    }
#pragma unroll
    for (int r = 0; r < 8; ++r) {
        int c = r*256 + wave*64;
        gload16((const char*)Qb + rowbase*2 + (size_t)(c+lane)*16, (char*)&qt[0][0] + (size_t)c*16);
        gload16((const char*)Kb + rowbase*2 + (size_t)(c+lane)*16, (char*)&kt[0][0] + (size_t)c*16);
    }
    __syncthreads();

    const int dk0 = tid*2;
    float mu0 = 1.f, mu1 = 1.f;
    for (int t = 0; t < SUBL; ++t) {
        mu0 *= gt[t][dk0];   mu0 = fmaxf(mu0, 1e-30f);
        mu1 *= gt[t][dk0+1]; mu1 = fmaxf(mu1, 1e-30f);
        qt[t][dk0]   = f2bf(bflo((uint32_t)qt[t][dk0])   * mu0);
        qt[t][dk0+1] = f2bf(bflo((uint32_t)qt[t][dk0+1]) * mu1);
        kt[t][dk0]   = f2bf(bflo((uint32_t)kt[t][dk0])   / mu0);
        kt[t][dk0+1] = f2bf(bflo((uint32_t)kt[t][dk0+1]) / mu1);
    }
    T[((size_t)b*NSUB + sub)*D_ + dk0]     = mu0;
    T[((size_t)b*NSUB + sub)*D_ + dk0 + 1] = mu1;
    __syncthreads();

    {   // write back Q~ and K^ rows, coalesced
        const int r = tid>>3, c0 = (tid&7)*64;
#pragma unroll
        for (int e = 0; e < 64; e += 8) {
            *(uint4*)&Qb[rowbase + (size_t)r*D_ + c0 + e] = *(uint4*)&qt[r][c0+e];
            *(uint4*)&Kb[rowbase + (size_t)r*D_ + c0 + e] = *(uint4*)&kt[r][c0+e];
        }
    }
#pragma unroll
    for (int rr = 0; rr < 2; ++rr) {  // K^T columns
        const int dk = tid*2 + rr;
        uint16_t* dst = &KT[((size_t)b*D_ + dk)*S_ + sub*SUBL];
#pragma unroll
        for (int q4 = 0; q4 < 4; ++q4) {
            uint4 o;
            o.x = (uint32_t)kt[q4*8+0][dk] | ((uint32_t)kt[q4*8+1][dk]<<16);
            o.y = (uint32_t)kt[q4*8+2][dk] | ((uint32_t)kt[q4*8+3][dk]<<16);
            o.z = (uint32_t)kt[q4*8+4][dk] | ((uint32_t)kt[q4*8+5][dk]<<16);
            o.w = (uint32_t)kt[q4*8+6][dk] | ((uint32_t)kt[q4*8+7][dk]<<16);
            *(uint4*)&dst[q4*8] = o;
        }
    }
}

// ---------------- tables: Pre / Suf / Lam from T -----------------------------------
__global__ __launch_bounds__(512) void tables(const float* __restrict__ T,
                                              float* __restrict__ Pre,
                                              float* __restrict__ Suf,
                                              float* __restrict__ Lam)
{
    const int b = blockIdx.x, dk = threadIdx.x;
    for (int sp = 0; sp < NSUP; ++sp) {
        float run = 1.f;
#pragma unroll
        for (int m = 0; m < 8; ++m) {
            Pre[((size_t)b*NSUB + sp*8+m)*D_ + dk] = run;
            run *= T[((size_t)b*NSUB + sp*8+m)*D_ + dk];
        }
        Lam[((size_t)b*NSUP + sp)*D_ + dk] = run;
        float rs = 1.f;
#pragma unroll
        for (int m = 7; m >= 0; --m) {
            rs *= T[((size_t)b*NSUB + sp*8+m)*D_ + dk];
            Suf[((size_t)b*NSUB + sp*8+m)*D_ + dk] = rs;
        }
    }
}

// ---------------- pairsA: P_ij = Q~_i @ (D_ij * K^_j)^T, self-masked ---------------
// grid (i:8, sp:8, b:8), 256 thr. XOR-swizzled LDS tiles; 1 16x16 quadrant per wave.
__device__ __forceinline__ int swz(int r, int c){ return r*D_ + (c ^ ((r&7)<<3)); }

__global__ __launch_bounds__(256) void pairsA(const uint16_t* __restrict__ Qt,
                                              const uint16_t* __restrict__ Kh,
                                              const float* __restrict__ T,
                                              uint16_t* __restrict__ P)
{
    __shared__ __attribute__((aligned(16))) uint16_t qs[SUBL*D_];
    __shared__ __attribute__((aligned(16))) uint16_t ks[SUBL*D_];
    __shared__ float D_lds[D_];
    const int i = blockIdx.x, sp = blockIdx.y, b = blockIdx.z;
    const int tid = threadIdx.x, wave = tid>>6, lane = tid&63;
    const int fr = lane&15, fq = lane>>4;
    const int mq = wave>>1, nq = wave&1;
    const size_t qrow = (size_t)b*S_ + sp*SUPL + i*SUBL;
    const size_t prow = ((size_t)(b*NSUP + sp)*SUPL + i*SUBL);

    // stage Q~_i and raw K^_i (self), swizzled
#pragma unroll
    for (int z = 0; z < 8; ++z) {
        int ch = z*256 + tid, r = ch>>6, c = (ch&63)*8;
        *(uint4*)&qs[swz(r,c)] = *(const uint4*)&Qt[(qrow + r)*D_ + c];
        *(uint4*)&ks[swz(r,c)] = *(const uint4*)&Kh[(qrow + r)*D_ + c];
    }
    float d0 = 1.f, d1 = 1.f;
    const int dkA = tid*2, dkB = tid*2+1;

    for (int j = i; j >= 0; --j) {
        if (j < i) {
            d0 *= T[((size_t)b*NSUB + sp*8 + j)*D_ + dkA];
            d1 *= T[((size_t)b*NSUB + sp*8 + j)*D_ + dkB];
            D_lds[dkA] = d0; D_lds[dkB] = d1;
            __syncthreads();     // D visible; prev iter's LDS frag reads done
#pragma unroll
            for (int z = 0; z < 8; ++z) {
                int ch = z*256 + tid, r = ch>>6, c = (ch&63)*8;
                uint4 u = *(const uint4*)&Kh[((size_t)b*S_ + sp*SUPL + j*SUBL + r)*D_ + c];
                uint4 o;
                o.x = pack2bf(bflo(u.x)*D_lds[c+0], bfhi(u.x)*D_lds[c+1]);
                o.y = pack2bf(bflo(u.y)*D_lds[c+2], bfhi(u.y)*D_lds[c+3]);
                o.z = pack2bf(bflo(u.z)*D_lds[c+4], bfhi(u.z)*D_lds[c+5]);
                o.w = pack2bf(bflo(u.w)*D_lds[c+6], bfhi(u.w)*D_lds[c+7]);
                *(uint4*)&ks[swz(r,c)] = o;
            }
        }
        __syncthreads();
        f32x4 a0 = {}, a1 = {}, a2 = {}, a3 = {};
#pragma unroll
        for (int kk = 0; kk < 512; kk += 128) {
            bf16x8 q0 = *(const bf16x8*)&qs[swz(mq*16+fr, kk      + fq*8)];
            bf16x8 k0 = *(const bf16x8*)&ks[swz(nq*16+fr, kk      + fq*8)];
            bf16x8 q1 = *(const bf16x8*)&qs[swz(mq*16+fr, kk + 32 + fq*8)];
            bf16x8 k1 = *(const bf16x8*)&ks[swz(nq*16+fr, kk + 32 + fq*8)];
            bf16x8 q2 = *(const bf16x8*)&qs[swz(mq*16+fr, kk + 64 + fq*8)];
            bf16x8 k2 = *(const bf16x8*)&ks[swz(nq*16+fr, kk + 64 + fq*8)];
            bf16x8 q3 = *(const bf16x8*)&qs[swz(mq*16+fr, kk + 96 + fq*8)];
            bf16x8 k3 = *(const bf16x8*)&ks[swz(nq*16+fr, kk + 96 + fq*8)];
            a0 = __builtin_amdgcn_mfma_f32_16x16x32_bf16(q0, k0, a0, 0,0,0);
            a1 = __builtin_amdgcn_mfma_f32_16x16x32_bf16(q1, k1, a1, 0,0,0);
            a2 = __builtin_amdgcn_mfma_f32_16x16x32_bf16(q2, k2, a2, 0,0,0);
            a3 = __builtin_amdgcn_mfma_f32_16x16x32_bf16(q3, k3, a3, 0,0,0);
        }
        const int ul = nq*16 + fr;
#pragma unroll
        for (int q_ = 0; q_ < 4; ++q_) {
            const int tl = mq*16 + fq*4 + q_;
            float v = a0[q_] + a1[q_] + a2[q_] + a3[q_];
            if (j == i && ul > tl) v = 0.f;
            P[(prow + tl)*SUPL + j*SUBL + ul] = f2bf(v);
        }
        __syncthreads();        // P-frag LDS reads done before next stage overwrites
    }
}

// ---------------- dsgemm: dS_c = sum_u (Suf*k^_u) v_u^T  (stored [dv][dk]) ---------
__global__ __launch_bounds__(256) void dsgemm(const uint16_t* __restrict__ VT,
                                              const uint16_t* __restrict__ KT,
                                              const float* __restrict__ Suf,
                                              uint16_t* __restrict__ Sst)
{
    __shared__ __attribute__((aligned(16))) uint16_t As[128][40];
    __shared__ __attribute__((aligned(16))) uint16_t Bs[128][40];
    const int tile = blockIdx.x, c = blockIdx.y, b = blockIdx.z;
    const int m0 = (tile&3)*128, n0 = (tile>>2)*128;
    const int tid = threadIdx.x, wave = tid>>6, lane = tid&63;
    const int wr = (wave>>1)*64, wc = (wave&1)*64;
    const int fr = lane&15, fq = lane>>4;
    f32x4 acc[4][4] = {};

    for (int j = 0; j < 8; ++j) {
        const int t0 = c*SUPL + j*SUBL;
        __syncthreads();
#pragma unroll
        for (int ch = tid; ch < 512; ch += 256) {
            int row = ch>>2, tc = (ch&3)*8;
            *(uint4*)&As[row][tc] = *(const uint4*)&VT[((size_t)b*D_ + m0+row)*S_ + t0 + tc];
        }
#pragma unroll
        for (int ch = tid; ch < 512; ch += 256) {
            int row = ch>>2, tc = (ch&3)*8;
            uint4 u = *(const uint4*)&KT[((size_t)b*D_ + n0+row)*S_ + t0 + tc];
            float sf = Suf[((size_t)b*NSUB + c*8 + j)*D_ + n0 + row];
            uint4 o;
            o.x = pack2bf(bflo(u.x)*sf, bfhi(u.x)*sf);
            o.y = pack2bf(bflo(u.y)*sf, bfhi(u.y)*sf);
            o.z = pack2bf(bflo(u.z)*sf, bfhi(u.z)*sf);
            o.w = pack2bf(bflo(u.w)*sf, bfhi(u.w)*sf);
            *(uint4*)&Bs[row][tc] = o;
        }
        __syncthreads();
        bf16x8 af[4], bf[4];
#pragma unroll
        for (int m = 0; m < 4; ++m) af[m] = *(const bf16x8*)&As[wr+m*16+fr][fq*8];
#pragma unroll
        for (int n = 0; n < 4; ++n) bf[n] = *(const bf16x8*)&Bs[wc+n*16+fr][fq*8];
#pragma unroll
        for (int m = 0; m < 4; ++m)
#pragma unroll
            for (int n = 0; n < 4; ++n)
                acc[m][n] = __builtin_amdgcn_mfma_f32_16x16x32_bf16(af[m], bf[n], acc[m][n], 0,0,0);
    }
#pragma unroll
    for (int n = 0; n < 4; ++n) {
        const int dk = n0 + wc + n*16 + fr;
#pragma unroll
        for (int m = 0; m < 4; ++m)
#pragma unroll
            for (int q = 0; q < 4; ++q) {
                const int dv = m0 + wr + m*16 + fq*4 + q;
                Sst[(((size_t)c*B_ + b)*D_ + dv)*D_ + dk] = f2bf(acc[m][n][q]);
            }
    }
}

// ---------------- scanfix: S_c = Lam_c (x) S_{c-1} + dS_c, c = 1..6 ----------------
__global__ __launch_bounds__(256) void scanfix(uint16_t* __restrict__ Sst,
                                               const float* __restrict__ Lam)
{
    const int id = blockIdx.x*256 + threadIdx.x;
    const int g = id & 63, dv = (id>>6) & 511, b = id >> 15;
    const int dk = g*8;
    float s[8];
    {
        uint4 u = *(const uint4*)&Sst[(((size_t)0*B_ + b)*D_ + dv)*D_ + dk];
        s[0]=bflo(u.x); s[1]=bfhi(u.x); s[2]=bflo(u.y); s[3]=bfhi(u.y);
        s[4]=bflo(u.z); s[5]=bfhi(u.z); s[6]=bflo(u.w); s[7]=bfhi(u.w);
    }
    for (int c = 1; c < 7; ++c) {
        const size_t bs = (((size_t)c*B_ + b)*D_ + dv)*D_ + dk;
        uint4 d = *(const uint4*)&Sst[bs];
        float4 l0 = *(const float4*)&Lam[((size_t)b*NSUP + c)*D_ + dk];
        float4 l1 = *(const float4*)&Lam[((size_t)b*NSUP + c)*D_ + dk + 4];
        s[0] = l0.x*s[0] + bflo(d.x); s[1] = l0.y*s[1] + bfhi(d.x);
        s[2] = l0.z*s[2] + bflo(d.y); s[3] = l0.w*s[3] + bfhi(d.y);
        s[4] = l1.x*s[4] + bflo(d.z); s[5] = l1.y*s[5] + bfhi(d.z);
        s[6] = l1.z*s[6] + bflo(d.w); s[7] = l1.w*s[7] + bfhi(d.w);
        uint4 o;
        o.x = pack2bf(s[0],s[1]); o.y = pack2bf(s[2],s[3]);
        o.z = pack2bf(s[4],s[5]); o.w = pack2bf(s[6],s[7]);
        *(uint4*)&Sst[bs] = o;
    }
}

// ---------------- bigout: O = [Q~*Pre | P] @ [S_prev ; V], K=768, 128x128 ----------
__global__ __launch_bounds__(256) void bigout(const uint16_t* __restrict__ Qt,
                                              const float* __restrict__ Pre,
                                              const uint16_t* __restrict__ Sst,
                                              const uint16_t* __restrict__ Pb,
                                              const uint16_t* __restrict__ VT,
                                              uint16_t* __restrict__ O)
{
    __shared__ __attribute__((aligned(16))) uint16_t As[128*64];
    __shared__ __attribute__((aligned(16))) uint16_t Bs[128*64];
    __shared__ float PreL[4*512];
    const int m0 = blockIdx.x*128, n0 = blockIdx.y*128;
    const int b = blockIdx.z>>3, sp = blockIdx.z&7;
    const int tid = threadIdx.x, wave = tid>>6, lane = tid&63;
    const int wr = (wave>>1)*64, wc = (wave&1)*64;
    const int fr = lane&15, fq = lane>>4;
    const int i0 = m0>>5;

#pragma unroll
    for (int z = 0; z < 8; ++z) {
        int idx = z*256 + tid;
        PreL[idx] = Pre[((size_t)b*NSUB + sp*8 + i0 + (idx>>9))*D_ + (idx&511)];
    }
    f32x4 acc[4][4] = {};
    const int kt0 = (sp == 0) ? 8 : 0;
    for (int kt = kt0; kt < 12; ++kt) {
        __syncthreads();
        if (kt < 8) {
            const int k0 = kt*64;
#pragma unroll
            for (int z = 0; z < 4; ++z) {       // A: reg-staged Q~ * Pre
                int ch = z*256 + tid, r = ch>>3, cc = (ch&7)*8;
                uint4 u = *(const uint4*)&Qt[((size_t)b*S_ + sp*SUPL + m0 + r)*D_ + k0 + cc];
                const float* pr = &PreL[((r>>5)<<9) + k0 + cc];
                uint4 o;
                o.x = pack2bf(bflo(u.x)*pr[0], bfhi(u.x)*pr[1]);
                o.y = pack2bf(bflo(u.y)*pr[2], bfhi(u.y)*pr[3]);
                o.z = pack2bf(bflo(u.z)*pr[4], bfhi(u.z)*pr[5]);
                o.w = pack2bf(bflo(u.w)*pr[6], bfhi(u.w)*pr[7]);
                *(uint4*)&As[r*64 + cc] = o;
            }
#pragma unroll
            for (int z = 0; z < 4; ++z) {       // B: S_prev rows (dv), unscaled
                int ch = z*256 + tid, row = ch>>3, cc = (ch&7)*8;
                int ldsb = (z*256 + wave*64)*8;
                gload16(&Sst[(((size_t)(sp-1)*B_ + b)*D_ + n0 + row)*D_ + k0 + cc], &Bs[ldsb]);
            }
        } else {
            const int u0 = (kt-8)*64;
#pragma unroll
            for (int z = 0; z < 4; ++z) {
                int ch = z*256 + tid, row = ch>>3, cc = (ch&7)*8;
                int ldsb = (z*256 + wave*64)*8;
                gload16(&Pb[((size_t)(b*NSUP + sp)*SUPL + m0 + row)*SUPL + u0 + cc], &As[ldsb]);
                gload16(&VT[((size_t)b*D_ + n0 + row)*S_ + sp*SUPL + u0 + cc], &Bs[ldsb]);
            }
        }
        __syncthreads();
#pragma unroll
        for (int kk = 0; kk < 64; kk += 32) {
            bf16x8 af[4], bf[4];
#pragma unroll
            for (int m = 0; m < 4; ++m) af[m] = *(const bf16x8*)&As[(wr+m*16+fr)*64 + kk + fq*8];
#pragma unroll
            for (int n = 0; n < 4; ++n) bf[n] = *(const bf16x8*)&Bs[(wc+n*16+fr)*64 + kk + fq*8];
#pragma unroll
            for (int m = 0; m < 4; ++m)
#pragma unroll
                for (int n = 0; n < 4; ++n)
                    acc[m][n] = __builtin_amdgcn_mfma_f32_16x16x32_bf16(af[m], bf[n], acc[m][n], 0,0,0);
        }
    }
#pragma unroll
    for (int n = 0; n < 4; ++n) {
        const int dv = n0 + wc + n*16 + fr;
#pragma unroll
        for (int m = 0; m < 4; ++m)
#pragma unroll
            for (int q = 0; q < 4; ++q) {
                const int t = sp*SUPL + m0 + wr + m*16 + fq*4 + q;
                O[((size_t)b*S_ + t)*D_ + dv] = f2bf(acc[m][n][q]);
            }
    }
}

// ---------------- launch ----------------------------------------------------------
extern "C" void kernel_launch(void* const* d_in, const int* in_sizes, int n_in,
                              void* d_out, int out_size, void* d_ws, size_t ws_size,
                              hipStream_t stream)
{
    (void)in_sizes; (void)n_in; (void)out_size; (void)ws_size;
    const float* x  = (const float*)d_in[0];
    const float* Wq = (const float*)d_in[1];  const float* bq = (const float*)d_in[2];
    const float* Wk = (const float*)d_in[3];  const float* bk = (const float*)d_in[4];
    const float* Wv = (const float*)d_in[5];  const float* bv = (const float*)d_in[6];
    const float* Wg = (const float*)d_in[7];  const float* bg = (const float*)d_in[8];
    const float* Wo = (const float*)d_in[9];  const float* bo = (const float*)d_in[10];

    char* w = (char*)d_ws;
    const size_t MD2 = (size_t)M_*D_*2;
    uint16_t* Wb = (uint16_t*)w;                       w += 5*(size_t)D_*D_*2;
    uint16_t* xb = (uint16_t*)w;                       w += MD2;                  // x, later O
    uint16_t* Qb = (uint16_t*)w;                       w += MD2;                  // Q -> Q~
    uint16_t* Kb = (uint16_t*)w;                       w += MD2;                  // K -> K^ rows
    uint16_t* KT = (uint16_t*)w;                       w += MD2;                  // K^T [b][dk][t]
    uint16_t* VT = (uint16_t*)w;                       w += MD2;                  // V^T [b][dv][t]
    float*    Gf = (float*)w;                          w += (size_t)M_*D_*4;
    uint16_t* Sst = (uint16_t*)w;                      w += (size_t)7*B_*D_*D_*2;
    uint16_t* Pb  = (uint16_t*)w;                      w += (size_t)B_*NSUP*SUPL*SUPL*2;  // 8.39MB
    float*    T   = (float*)w;                         w += (size_t)B_*NSUB*D_*4;
    float*    Pre = (float*)w;                         w += (size_t)B_*NSUB*D_*4;
    float*    Suf = (float*)w;                         w += (size_t)B_*NSUB*D_*4;
    float*    Lam = (float*)w;                         w += (size_t)B_*NSUP*D_*4;

    hipMemsetAsync(Pb, 0, (size_t)B_*NSUP*SUPL*SUPL*2, stream);

    conv_x<<<dim3(M_*D_/2048), 256, 0, stream>>>(x, xb);
    conv_w<<<dim3(D_*D_/2048, 5), 256, 0, stream>>>(Wq, Wk, Wv, Wg, Wo, Wb);

    dim3 gg(M_/128, D_/128), bb(256);
    mfma_gemm<<<gg, bb, 0, stream>>>(xb, Wb + 0*(size_t)D_*D_, bq, (void*)Qb, 1);
    mfma_gemm<<<gg, bb, 0, stream>>>(xb, Wb + 1*(size_t)D_*D_, bk, (void*)Kb, 1);
    mfma_gemm<<<gg, bb, 0, stream>>>(xb, Wb + 2*(size_t)D_*D_, bv, (void*)VT, 3);
    mfma_gemm<<<gg, bb, 0, stream>>>(xb, Wb + 3*(size_t)D_*D_, bg, (void*)Gf, 2);

    prep<<<dim3(NSUB, B_), 256, 0, stream>>>(Gf, Qb, Kb, KT, T);
    tables<<<dim3(B_), 512, 0, stream>>>(T, Pre, Suf, Lam);

    pairsA<<<dim3(8, NSUP, B_), 256, 0, stream>>>(Qb, Kb, T, Pb);
    dsgemm<<<dim3(16, 7, B_), 256, 0, stream>>>(VT, KT, Suf, Sst);
    scanfix<<<dim3(1024), 256, 0, stream>>>(Sst, Lam);

    bigout<<<dim3(2, 4, B_*NSUP), 256, 0, stream>>>(Qb, Pre, Sst, Pb, VT, xb);

    mfma_gemm<<<gg, bb, 0, stream>>>(xb, Wb + 4*(size_t)D_*D_, bo, d_out, 0);
}

// Round 5
// 236.127 us; speedup vs baseline: 10.3460x; 1.1674x over previous
//
#include <hip/hip_runtime.h>
#include <hip/hip_bf16.h>
#include <stdint.h>

// SRALayer R5: chunked GLA.
//  conv_x/conv_w -> proj4 (fused Q|K|V|G GEMM, N=2048) -> prep (LDS-free, coalesced)
//  -> tables -> pairsA (balanced i-pairs) -> dsgemm -> scanfix -> bigout -> out proj.

#define B_ 8
#define S_ 2048
#define D_ 512
#define M_ (B_ * S_)
#define NSUB 64
#define SUBL 32
#define NSUP 8
#define SUPL 256

typedef __bf16 bf16x8 __attribute__((ext_vector_type(8)));
typedef float f32x4 __attribute__((ext_vector_type(4)));

__device__ __forceinline__ float bflo(uint32_t u){ return __uint_as_float(u<<16); }
__device__ __forceinline__ float bfhi(uint32_t u){ return __uint_as_float(u&0xffff0000u); }
__device__ __forceinline__ uint16_t f2bf(float f){
    uint32_t u = __float_as_uint(f);
    return (uint16_t)((u + 0x7fffu + ((u>>16)&1u)) >> 16);
}
__device__ __forceinline__ uint32_t pack2bf(float a, float b){
    return (uint32_t)f2bf(a) | ((uint32_t)f2bf(b)<<16);
}
__device__ __forceinline__ void gload16(const void* g, void* l){
    __builtin_amdgcn_global_load_lds(
        (const __attribute__((address_space(1))) uint32_t*)g,
        (__attribute__((address_space(3))) uint32_t*)l, 16, 0, 0);
}

// ---------------- fp32 -> bf16 converters -----------------------------------------
__global__ __launch_bounds__(256) void conv_x(const float* __restrict__ in,
                                              uint16_t* __restrict__ out){
    const size_t i = ((size_t)blockIdx.x*256 + threadIdx.x)*8;
    float4 a = *(const float4*)&in[i];
    float4 b = *(const float4*)&in[i+4];
    uint4 o; o.x=pack2bf(a.x,a.y); o.y=pack2bf(a.z,a.w); o.z=pack2bf(b.x,b.y); o.w=pack2bf(b.z,b.w);
    *(uint4*)&out[i] = o;
}
__global__ __launch_bounds__(256) void conv_w(const float* w0, const float* w1, const float* w2,
                                              const float* w3, const float* w4,
                                              uint16_t* __restrict__ out){
    const float* ws[5] = {w0,w1,w2,w3,w4};
    const float* in = ws[blockIdx.y];
    uint16_t* o = out + (size_t)blockIdx.y*D_*D_;
    const size_t i = ((size_t)blockIdx.x*256 + threadIdx.x)*8;
    float4 a = *(const float4*)&in[i];
    float4 b = *(const float4*)&in[i+4];
    uint4 u; u.x=pack2bf(a.x,a.y); u.y=pack2bf(a.z,a.w); u.z=pack2bf(b.x,b.y); u.w=pack2bf(b.z,b.w);
    *(uint4*)&o[i] = u;
}

// ---------------- proj4: fused Q|K|V|G projection GEMM, N=2048 ---------------------
// grid (M_/128, 16). section = blockIdx.y>>2 : 0=Q(bf16) 1=K(bf16) 2=V(transposed) 3=G(sigmoid fp32)
__global__ __launch_bounds__(256) void proj4(const uint16_t* __restrict__ A,
                                             const uint16_t* __restrict__ Wb,
                                             const float* __restrict__ bq_,
                                             const float* __restrict__ bk_,
                                             const float* __restrict__ bv_,
                                             const float* __restrict__ bg_,
                                             uint16_t* __restrict__ Qb,
                                             uint16_t* __restrict__ Kb,
                                             uint16_t* __restrict__ VT,
                                             float* __restrict__ Gf)
{
    __shared__ __attribute__((aligned(16))) uint16_t As[128*64];
    __shared__ __attribute__((aligned(16))) uint16_t Bs[128*64];
    const int tid = threadIdx.x, wave = tid>>6, lane = tid&63;
    const int m0 = blockIdx.x*128, n0 = blockIdx.y*128;
    const int wr = (wave>>1)*64, wc = (wave&1)*64;
    const int fr = lane&15, fq = lane>>4;
    f32x4 acc[4][4] = {};

    for (int k0 = 0; k0 < D_; k0 += 64) {
        __syncthreads();
#pragma unroll
        for (int i = 0; i < 4; ++i) {
            const int c = i*256 + tid;
            const int row = c>>3, kc = (c&7)*8;
            const int ldsb = (i*256 + wave*64)*8;
            gload16(&A [(size_t)(m0+row)*D_ + k0 + kc], &As[ldsb]);
            gload16(&Wb[(size_t)(n0+row)*D_ + k0 + kc], &Bs[ldsb]);
        }
        __syncthreads();
#pragma unroll
        for (int kk = 0; kk < 64; kk += 32) {
            bf16x8 af[4], bf[4];
#pragma unroll
            for (int m = 0; m < 4; ++m) af[m] = *(const bf16x8*)&As[(wr+m*16+fr)*64 + kk + fq*8];
#pragma unroll
            for (int n = 0; n < 4; ++n) bf[n] = *(const bf16x8*)&Bs[(wc+n*16+fr)*64 + kk + fq*8];
#pragma unroll
            for (int m = 0; m < 4; ++m)
#pragma unroll
                for (int n = 0; n < 4; ++n)
                    acc[m][n] = __builtin_amdgcn_mfma_f32_16x16x32_bf16(af[m], bf[n], acc[m][n], 0,0,0);
        }
    }
    const int sect = blockIdx.y >> 2;
    const float* bias = (sect==0) ? bq_ : (sect==1) ? bk_ : (sect==2) ? bv_ : bg_;
#pragma unroll
    for (int n = 0; n < 4; ++n) {
        const int coll = (n0 & 511) + wc + n*16 + fr;
        const float bv = bias[coll];
        if (sect == 2) {
#pragma unroll
            for (int m = 0; m < 4; ++m) {
                const int rg = m0 + wr + m*16 + fq*4;
                const int bb = rg >> 11, t = rg & 2047;
                uint2 pk;
                pk.x = pack2bf(acc[m][n][0]+bv, acc[m][n][1]+bv);
                pk.y = pack2bf(acc[m][n][2]+bv, acc[m][n][3]+bv);
                *(uint2*)&VT[((size_t)bb*D_ + coll)*S_ + t] = pk;
            }
        } else if (sect == 3) {
#pragma unroll
            for (int m = 0; m < 4; ++m)
#pragma unroll
                for (int q = 0; q < 4; ++q) {
                    const int row = m0 + wr + m*16 + fq*4 + q;
                    Gf[(size_t)row*D_ + coll] = 1.f/(1.f+expf(-(acc[m][n][q]+bv)));
                }
        } else {
            uint16_t* dst = sect ? Kb : Qb;
#pragma unroll
            for (int m = 0; m < 4; ++m)
#pragma unroll
                for (int q = 0; q < 4; ++q) {
                    const int row = m0 + wr + m*16 + fq*4 + q;
                    dst[(size_t)row*D_ + coll] = f2bf(acc[m][n][q]+bv);
                }
        }
    }
}

// ---------------- mfma_gemm: final output projection (fp32 out) --------------------
__global__ __launch_bounds__(256) void mfma_gemm(const uint16_t* __restrict__ A,
                                                 const uint16_t* __restrict__ Wt,
                                                 const float* __restrict__ bias,
                                                 float* __restrict__ out)
{
    __shared__ __attribute__((aligned(16))) uint16_t As[128*64];
    __shared__ __attribute__((aligned(16))) uint16_t Bs[128*64];
    const int tid = threadIdx.x, wave = tid>>6, lane = tid&63;
    const int m0 = blockIdx.x*128, n0 = blockIdx.y*128;
    const int wr = (wave>>1)*64, wc = (wave&1)*64;
    const int fr = lane&15, fq = lane>>4;
    f32x4 acc[4][4] = {};

    for (int k0 = 0; k0 < D_; k0 += 64) {
        __syncthreads();
#pragma unroll
        for (int i = 0; i < 4; ++i) {
            const int c = i*256 + tid;
            const int row = c>>3, kc = (c&7)*8;
            const int ldsb = (i*256 + wave*64)*8;
            gload16(&A [(size_t)(m0+row)*D_ + k0 + kc], &As[ldsb]);
            gload16(&Wt[(size_t)(n0+row)*D_ + k0 + kc], &Bs[ldsb]);
        }
        __syncthreads();
#pragma unroll
        for (int kk = 0; kk < 64; kk += 32) {
            bf16x8 af[4], bf[4];
#pragma unroll
            for (int m = 0; m < 4; ++m) af[m] = *(const bf16x8*)&As[(wr+m*16+fr)*64 + kk + fq*8];
#pragma unroll
            for (int n = 0; n < 4; ++n) bf[n] = *(const bf16x8*)&Bs[(wc+n*16+fr)*64 + kk + fq*8];
#pragma unroll
            for (int m = 0; m < 4; ++m)
#pragma unroll
                for (int n = 0; n < 4; ++n)
                    acc[m][n] = __builtin_amdgcn_mfma_f32_16x16x32_bf16(af[m], bf[n], acc[m][n], 0,0,0);
        }
    }
#pragma unroll
    for (int n = 0; n < 4; ++n) {
        const int col = n0 + wc + n*16 + fr;
        const float bv = bias[col];
#pragma unroll
        for (int m = 0; m < 4; ++m)
#pragma unroll
            for (int q = 0; q < 4; ++q) {
                const int row = m0 + wr + m*16 + fq*4 + q;
                out[(size_t)row*D_ + col] = acc[m][n][q] + bv;
            }
    }
}

// ---------------- prep: LDS-free. thread owns 2 dk cols over 32 t ------------------
// grid (NSUB, B_), 256 thr. Per t: coalesced 8B(g)/4B(q,k) per thread.
__global__ __launch_bounds__(256) void prep(const float* __restrict__ Gf,
                                            uint16_t* __restrict__ Qb,
                                            uint16_t* __restrict__ Kb,
                                            uint16_t* __restrict__ KT,
                                            float* __restrict__ T)
{
    const int sub = blockIdx.x, b = blockIdx.y;
    const int tid = threadIdx.x;
    const int dk0 = tid*2;
    const size_t rowbase = ((size_t)b*S_ + sub*SUBL)*D_;
    const float*    gp = Gf + rowbase + dk0;
    uint16_t*       qp = Qb + rowbase + dk0;
    uint16_t*       kp = Kb + rowbase + dk0;

    float mu0 = 1.f, mu1 = 1.f;
    uint32_t ksave[SUBL];
#pragma unroll
    for (int t = 0; t < SUBL; ++t) {
        const float2   g  = *(const float2*)(gp + (size_t)t*D_);
        const uint32_t qu = *(const uint32_t*)(qp + (size_t)t*D_);
        const uint32_t ku = *(const uint32_t*)(kp + (size_t)t*D_);
        mu0 = fmaxf(mu0*g.x, 1e-30f);
        mu1 = fmaxf(mu1*g.y, 1e-30f);
        const float r0 = __builtin_amdgcn_rcpf(mu0);
        const float r1 = __builtin_amdgcn_rcpf(mu1);
        *(uint32_t*)(qp + (size_t)t*D_) = pack2bf(bflo(qu)*mu0, bfhi(qu)*mu1);
        const uint32_t kw = pack2bf(bflo(ku)*r0, bfhi(ku)*r1);
        *(uint32_t*)(kp + (size_t)t*D_) = kw;
        ksave[t] = kw;
    }
    T[((size_t)b*NSUB + sub)*D_ + dk0]     = mu0;
    T[((size_t)b*NSUB + sub)*D_ + dk0 + 1] = mu1;

    // KT[b][dk][t]: row dk0 = lo16 of ksave, row dk0+1 = hi16
    uint16_t* d0 = &KT[((size_t)b*D_ + dk0)*S_ + sub*SUBL];
    uint16_t* d1 = d0 + S_;
#pragma unroll
    for (int q4 = 0; q4 < 4; ++q4) {
        uint4 lo, hi;
        lo.x = (ksave[q4*8+0]&0xffffu) | (ksave[q4*8+1]<<16);
        lo.y = (ksave[q4*8+2]&0xffffu) | (ksave[q4*8+3]<<16);
        lo.z = (ksave[q4*8+4]&0xffffu) | (ksave[q4*8+5]<<16);
        lo.w = (ksave[q4*8+6]&0xffffu) | (ksave[q4*8+7]<<16);
        hi.x = (ksave[q4*8+0]>>16) | (ksave[q4*8+1]&0xffff0000u);
        hi.y = (ksave[q4*8+2]>>16) | (ksave[q4*8+3]&0xffff0000u);
        hi.z = (ksave[q4*8+4]>>16) | (ksave[q4*8+5]&0xffff0000u);
        hi.w = (ksave[q4*8+6]>>16) | (ksave[q4*8+7]&0xffff0000u);
        *(uint4*)&d0[q4*8] = lo;
        *(uint4*)&d1[q4*8] = hi;
    }
}

// ---------------- tables: Pre / Suf / Lam from T -----------------------------------
__global__ __launch_bounds__(512) void tables(const float* __restrict__ T,
                                              float* __restrict__ Pre,
                                              float* __restrict__ Suf,
                                              float* __restrict__ Lam)
{
    const int b = blockIdx.x, dk = threadIdx.x;
    for (int sp = 0; sp < NSUP; ++sp) {
        float run = 1.f;
#pragma unroll
        for (int m = 0; m < 8; ++m) {
            Pre[((size_t)b*NSUB + sp*8+m)*D_ + dk] = run;
            run *= T[((size_t)b*NSUB + sp*8+m)*D_ + dk];
        }
        Lam[((size_t)b*NSUP + sp)*D_ + dk] = run;
        float rs = 1.f;
#pragma unroll
        for (int m = 7; m >= 0; --m) {
            rs *= T[((size_t)b*NSUB + sp*8+m)*D_ + dk];
            Suf[((size_t)b*NSUB + sp*8+m)*D_ + dk] = rs;
        }
    }
}

// ---------------- pairsA: P_ij = Q~_i @ (D_ij * K^_j)^T, self-masked ---------------
// grid (4, sp:8, b:8): block bx handles i = bx and i = 7-bx (9 j-iters each, balanced).
__device__ __forceinline__ int swz(int r, int c){ return r*D_ + (c ^ ((r&7)<<3)); }

__global__ __launch_bounds__(256) void pairsA(const uint16_t* __restrict__ Qt,
                                              const uint16_t* __restrict__ Kh,
                                              const float* __restrict__ T,
                                              uint16_t* __restrict__ P)
{
    __shared__ __attribute__((aligned(16))) uint16_t qs[SUBL*D_];
    __shared__ __attribute__((aligned(16))) uint16_t ks[SUBL*D_];
    __shared__ float D_lds[D_];
    const int bx = blockIdx.x, sp = blockIdx.y, b = blockIdx.z;
    const int tid = threadIdx.x, wave = tid>>6, lane = tid&63;
    const int fr = lane&15, fq = lane>>4;
    const int mq = wave>>1, nq = wave&1;
    const int dkA = tid*2, dkB = tid*2+1;

    for (int ii = 0; ii < 2; ++ii) {
        const int i = ii ? 7-bx : bx;
        const size_t qrow = (size_t)b*S_ + sp*SUPL + i*SUBL;
        const size_t prow = ((size_t)(b*NSUP + sp)*SUPL + i*SUBL);

        // stage Q~_i and raw K^_i (self), swizzled
#pragma unroll
        for (int z = 0; z < 8; ++z) {
            int ch = z*256 + tid, r = ch>>6, c = (ch&63)*8;
            *(uint4*)&qs[swz(r,c)] = *(const uint4*)&Qt[(qrow + r)*D_ + c];
            *(uint4*)&ks[swz(r,c)] = *(const uint4*)&Kh[(qrow + r)*D_ + c];
        }
        float d0 = 1.f, d1 = 1.f;

        for (int j = i; j >= 0; --j) {
            if (j < i) {
                d0 *= T[((size_t)b*NSUB + sp*8 + j)*D_ + dkA];
                d1 *= T[((size_t)b*NSUB + sp*8 + j)*D_ + dkB];
                D_lds[dkA] = d0; D_lds[dkB] = d1;
                __syncthreads();     // D visible; prev iter's LDS frag reads done
#pragma unroll
                for (int z = 0; z < 8; ++z) {
                    int ch = z*256 + tid, r = ch>>6, c = (ch&63)*8;
                    uint4 u = *(const uint4*)&Kh[((size_t)b*S_ + sp*SUPL + j*SUBL + r)*D_ + c];
                    uint4 o;
                    o.x = pack2bf(bflo(u.x)*D_lds[c+0], bfhi(u.x)*D_lds[c+1]);
                    o.y = pack2bf(bflo(u.y)*D_lds[c+2], bfhi(u.y)*D_lds[c+3]);
                    o.z = pack2bf(bflo(u.z)*D_lds[c+4], bfhi(u.z)*D_lds[c+5]);
                    o.w = pack2bf(bflo(u.w)*D_lds[c+6], bfhi(u.w)*D_lds[c+7]);
                    *(uint4*)&ks[swz(r,c)] = o;
                }
            }
            __syncthreads();
            f32x4 a0 = {}, a1 = {}, a2 = {}, a3 = {};
#pragma unroll
            for (int kk = 0; kk < 512; kk += 128) {
                bf16x8 q0 = *(const bf16x8*)&qs[swz(mq*16+fr, kk      + fq*8)];
                bf16x8 k0 = *(const bf16x8*)&ks[swz(nq*16+fr, kk      + fq*8)];
                bf16x8 q1 = *(const bf16x8*)&qs[swz(mq*16+fr, kk + 32 + fq*8)];
                bf16x8 k1 = *(const bf16x8*)&ks[swz(nq*16+fr, kk + 32 + fq*8)];
                bf16x8 q2 = *(const bf16x8*)&qs[swz(mq*16+fr, kk + 64 + fq*8)];
                bf16x8 k2 = *(const bf16x8*)&ks[swz(nq*16+fr, kk + 64 + fq*8)];
                bf16x8 q3 = *(const bf16x8*)&qs[swz(mq*16+fr, kk + 96 + fq*8)];
                bf16x8 k3 = *(const bf16x8*)&ks[swz(nq*16+fr, kk + 96 + fq*8)];
                a0 = __builtin_amdgcn_mfma_f32_16x16x32_bf16(q0, k0, a0, 0,0,0);
                a1 = __builtin_amdgcn_mfma_f32_16x16x32_bf16(q1, k1, a1, 0,0,0);
                a2 = __builtin_amdgcn_mfma_f32_16x16x32_bf16(q2, k2, a2, 0,0,0);
                a3 = __builtin_amdgcn_mfma_f32_16x16x32_bf16(q3, k3, a3, 0,0,0);
            }
            const int ul = nq*16 + fr;
#pragma unroll
            for (int q_ = 0; q_ < 4; ++q_) {
                const int tl = mq*16 + fq*4 + q_;
                float v = a0[q_] + a1[q_] + a2[q_] + a3[q_];
                if (j == i && ul > tl) v = 0.f;
                P[(prow + tl)*SUPL + j*SUBL + ul] = f2bf(v);
            }
            __syncthreads();        // P-frag LDS reads done before next stage overwrites
        }
    }
}

// ---------------- dsgemm: dS_c = sum_u (Suf*k^_u) v_u^T  (stored [dv][dk]) ---------
__global__ __launch_bounds__(256) void dsgemm(const uint16_t* __restrict__ VT,
                                              const uint16_t* __restrict__ KT,
                                              const float* __restrict__ Suf,
                                              uint16_t* __restrict__ Sst)
{
    __shared__ __attribute__((aligned(16))) uint16_t As[128][40];
    __shared__ __attribute__((aligned(16))) uint16_t Bs[128][40];
    const int tile = blockIdx.x, c = blockIdx.y, b = blockIdx.z;
    const int m0 = (tile&3)*128, n0 = (tile>>2)*128;
    const int tid = threadIdx.x, wave = tid>>6, lane = tid&63;
    const int wr = (wave>>1)*64, wc = (wave&1)*64;
    const int fr = lane&15, fq = lane>>4;
    f32x4 acc[4][4] = {};

    for (int j = 0; j < 8; ++j) {
        const int t0 = c*SUPL + j*SUBL;
        __syncthreads();
#pragma unroll
        for (int ch = tid; ch < 512; ch += 256) {
            int row = ch>>2, tc = (ch&3)*8;
            *(uint4*)&As[row][tc] = *(const uint4*)&VT[((size_t)b*D_ + m0+row)*S_ + t0 + tc];
        }
#pragma unroll
        for (int ch = tid; ch < 512; ch += 256) {
            int row = ch>>2, tc = (ch&3)*8;
            uint4 u = *(const uint4*)&KT[((size_t)b*D_ + n0+row)*S_ + t0 + tc];
            float sf = Suf[((size_t)b*NSUB + c*8 + j)*D_ + n0 + row];
            uint4 o;
            o.x = pack2bf(bflo(u.x)*sf, bfhi(u.x)*sf);
            o.y = pack2bf(bflo(u.y)*sf, bfhi(u.y)*sf);
            o.z = pack2bf(bflo(u.z)*sf, bfhi(u.z)*sf);
            o.w = pack2bf(bflo(u.w)*sf, bfhi(u.w)*sf);
            *(uint4*)&Bs[row][tc] = o;
        }
        __syncthreads();
        bf16x8 af[4], bf[4];
#pragma unroll
        for (int m = 0; m < 4; ++m) af[m] = *(const bf16x8*)&As[wr+m*16+fr][fq*8];
#pragma unroll
        for (int n = 0; n < 4; ++n) bf[n] = *(const bf16x8*)&Bs[wc+n*16+fr][fq*8];
#pragma unroll
        for (int m = 0; m < 4; ++m)
#pragma unroll
            for (int n = 0; n < 4; ++n)
                acc[m][n] = __builtin_amdgcn_mfma_f32_16x16x32_bf16(af[m], bf[n], acc[m][n], 0,0,0);
    }
#pragma unroll
    for (int n = 0; n < 4; ++n) {
        const int dk = n0 + wc + n*16 + fr;
#pragma unroll
        for (int m = 0; m < 4; ++m)
#pragma unroll
            for (int q = 0; q < 4; ++q) {
                const int dv = m0 + wr + m*16 + fq*4 + q;
                Sst[(((size_t)c*B_ + b)*D_ + dv)*D_ + dk] = f2bf(acc[m][n][q]);
            }
    }
}

// ---------------- scanfix: S_c = Lam_c (x) S_{c-1} + dS_c, c = 1..6 ----------------
__global__ __launch_bounds__(256) void scanfix(uint16_t* __restrict__ Sst,
                                               const float* __restrict__ Lam)
{
    const int id = blockIdx.x*256 + threadIdx.x;
    const int g = id & 63, dv = (id>>6) & 511, b = id >> 15;
    const int dk = g*8;
    float s[8];
    {
        uint4 u = *(const uint4*)&Sst[(((size_t)0*B_ + b)*D_ + dv)*D_ + dk];
        s[0]=bflo(u.x); s[1]=bfhi(u.x); s[2]=bflo(u.y); s[3]=bfhi(u.y);
        s[4]=bflo(u.z); s[5]=bfhi(u.z); s[6]=bflo(u.w); s[7]=bfhi(u.w);
    }
    for (int c = 1; c < 7; ++c) {
        const size_t bs = (((size_t)c*B_ + b)*D_ + dv)*D_ + dk;
        uint4 d = *(const uint4*)&Sst[bs];
        float4 l0 = *(const float4*)&Lam[((size_t)b*NSUP + c)*D_ + dk];
        float4 l1 = *(const float4*)&Lam[((size_t)b*NSUP + c)*D_ + dk + 4];
        s[0] = l0.x*s[0] + bflo(d.x); s[1] = l0.y*s[1] + bfhi(d.x);
        s[2] = l0.z*s[2] + bflo(d.y); s[3] = l0.w*s[3] + bfhi(d.y);
        s[4] = l1.x*s[4] + bflo(d.z); s[5] = l1.y*s[5] + bfhi(d.z);
        s[6] = l1.z*s[6] + bflo(d.w); s[7] = l1.w*s[7] + bfhi(d.w);
        uint4 o;
        o.x = pack2bf(s[0],s[1]); o.y = pack2bf(s[2],s[3]);
        o.z = pack2bf(s[4],s[5]); o.w = pack2bf(s[6],s[7]);
        *(uint4*)&Sst[bs] = o;
    }
}

// ---------------- bigout: O = [Q~*Pre | P] @ [S_prev ; V], K=768, 128x128 ----------
__global__ __launch_bounds__(256) void bigout(const uint16_t* __restrict__ Qt,
                                              const float* __restrict__ Pre,
                                              const uint16_t* __restrict__ Sst,
                                              const uint16_t* __restrict__ Pb,
                                              const uint16_t* __restrict__ VT,
                                              uint16_t* __restrict__ O)
{
    __shared__ __attribute__((aligned(16))) uint16_t As[128*64];
    __shared__ __attribute__((aligned(16))) uint16_t Bs[128*64];
    __shared__ float PreL[4*512];
    const int m0 = blockIdx.x*128, n0 = blockIdx.y*128;
    const int b = blockIdx.z>>3, sp = blockIdx.z&7;
    const int tid = threadIdx.x, wave = tid>>6, lane = tid&63;
    const int wr = (wave>>1)*64, wc = (wave&1)*64;
    const int fr = lane&15, fq = lane>>4;
    const int i0 = m0>>5;

#pragma unroll
    for (int z = 0; z < 8; ++z) {
        int idx = z*256 + tid;
        PreL[idx] = Pre[((size_t)b*NSUB + sp*8 + i0 + (idx>>9))*D_ + (idx&511)];
    }
    f32x4 acc[4][4] = {};
    const int kt0 = (sp == 0) ? 8 : 0;
    for (int kt = kt0; kt < 12; ++kt) {
        __syncthreads();
        if (kt < 8) {
            const int k0 = kt*64;
#pragma unroll
            for (int z = 0; z < 4; ++z) {       // A: reg-staged Q~ * Pre
                int ch = z*256 + tid, r = ch>>3, cc = (ch&7)*8;
                uint4 u = *(const uint4*)&Qt[((size_t)b*S_ + sp*SUPL + m0 + r)*D_ + k0 + cc];
                const float* pr = &PreL[((r>>5)<<9) + k0 + cc];
                uint4 o;
                o.x = pack2bf(bflo(u.x)*pr[0], bfhi(u.x)*pr[1]);
                o.y = pack2bf(bflo(u.y)*pr[2], bfhi(u.y)*pr[3]);
                o.z = pack2bf(bflo(u.z)*pr[4], bfhi(u.z)*pr[5]);
                o.w = pack2bf(bflo(u.w)*pr[6], bfhi(u.w)*pr[7]);
                *(uint4*)&As[r*64 + cc] = o;
            }
#pragma unroll
            for (int z = 0; z < 4; ++z) {       // B: S_prev rows (dv), unscaled
                int ch = z*256 + tid, row = ch>>3, cc = (ch&7)*8;
                int ldsb = (z*256 + wave*64)*8;
                gload16(&Sst[(((size_t)(sp-1)*B_ + b)*D_ + n0 + row)*D_ + k0 + cc], &Bs[ldsb]);
            }
        } else {
            const int u0 = (kt-8)*64;
#pragma unroll
            for (int z = 0; z < 4; ++z) {
                int ch = z*256 + tid, row = ch>>3, cc = (ch&7)*8;
                int ldsb = (z*256 + wave*64)*8;
                gload16(&Pb[((size_t)(b*NSUP + sp)*SUPL + m0 + row)*SUPL + u0 + cc], &As[ldsb]);
                gload16(&VT[((size_t)b*D_ + n0 + row)*S_ + sp*SUPL + u0 + cc], &Bs[ldsb]);
            }
        }
        __syncthreads();
#pragma unroll
        for (int kk = 0; kk < 64; kk += 32) {
            bf16x8 af[4], bf[4];
#pragma unroll
            for (int m = 0; m < 4; ++m) af[m] = *(const bf16x8*)&As[(wr+m*16+fr)*64 + kk + fq*8];
#pragma unroll
            for (int n = 0; n < 4; ++n) bf[n] = *(const bf16x8*)&Bs[(wc+n*16+fr)*64 + kk + fq*8];
#pragma unroll
            for (int m = 0; m < 4; ++m)
#pragma unroll
                for (int n = 0; n < 4; ++n)
                    acc[m][n] = __builtin_amdgcn_mfma_f32_16x16x32_bf16(af[m], bf[n], acc[m][n], 0,0,0);
        }
    }
#pragma unroll
    for (int n = 0; n < 4; ++n) {
        const int dv = n0 + wc + n*16 + fr;
#pragma unroll
        for (int m = 0; m < 4; ++m)
#pragma unroll
            for (int q = 0; q < 4; ++q) {
                const int t = sp*SUPL + m0 + wr + m*16 + fq*4 + q;
                O[((size_t)b*S_ + t)*D_ + dv] = f2bf(acc[m][n][q]);
            }
    }
}

// ---------------- launch ----------------------------------------------------------
extern "C" void kernel_launch(void* const* d_in, const int* in_sizes, int n_in,
                              void* d_out, int out_size, void* d_ws, size_t ws_size,
                              hipStream_t stream)
{
    (void)in_sizes; (void)n_in; (void)out_size; (void)ws_size;
    const float* x  = (const float*)d_in[0];
    const float* Wq = (const float*)d_in[1];  const float* bq = (const float*)d_in[2];
    const float* Wk = (const float*)d_in[3];  const float* bk = (const float*)d_in[4];
    const float* Wv = (const float*)d_in[5];  const float* bv = (const float*)d_in[6];
    const float* Wg = (const float*)d_in[7];  const float* bg = (const float*)d_in[8];
    const float* Wo = (const float*)d_in[9];  const float* bo = (const float*)d_in[10];

    char* w = (char*)d_ws;
    const size_t MD2 = (size_t)M_*D_*2;
    uint16_t* Wb = (uint16_t*)w;                       w += 5*(size_t)D_*D_*2;
    uint16_t* xb = (uint16_t*)w;                       w += MD2;                  // x, later O
    uint16_t* Qb = (uint16_t*)w;                       w += MD2;                  // Q -> Q~
    uint16_t* Kb = (uint16_t*)w;                       w += MD2;                  // K -> K^ rows
    uint16_t* KT = (uint16_t*)w;                       w += MD2;                  // K^T [b][dk][t]
    uint16_t* VT = (uint16_t*)w;                       w += MD2;                  // V^T [b][dv][t]
    float*    Gf = (float*)w;                          w += (size_t)M_*D_*4;
    uint16_t* Sst = (uint16_t*)w;                      w += (size_t)7*B_*D_*D_*2;
    uint16_t* Pb  = (uint16_t*)w;                      w += (size_t)B_*NSUP*SUPL*SUPL*2;
    float*    T   = (float*)w;                         w += (size_t)B_*NSUB*D_*4;
    float*    Pre = (float*)w;                         w += (size_t)B_*NSUB*D_*4;
    float*    Suf = (float*)w;                         w += (size_t)B_*NSUB*D_*4;
    float*    Lam = (float*)w;                         w += (size_t)B_*NSUP*D_*4;

    hipMemsetAsync(Pb, 0, (size_t)B_*NSUP*SUPL*SUPL*2, stream);

    conv_x<<<dim3(M_*D_/2048), 256, 0, stream>>>(x, xb);
    conv_w<<<dim3(D_*D_/2048, 5), 256, 0, stream>>>(Wq, Wk, Wv, Wg, Wo, Wb);

    proj4<<<dim3(M_/128, 16), 256, 0, stream>>>(xb, Wb, bq, bk, bv, bg, Qb, Kb, VT, Gf);

    prep<<<dim3(NSUB, B_), 256, 0, stream>>>(Gf, Qb, Kb, KT, T);
    tables<<<dim3(B_), 512, 0, stream>>>(T, Pre, Suf, Lam);

    pairsA<<<dim3(4, NSUP, B_), 256, 0, stream>>>(Qb, Kb, T, Pb);
    dsgemm<<<dim3(16, 7, B_), 256, 0, stream>>>(VT, KT, Suf, Sst);
    scanfix<<<dim3(1024), 256, 0, stream>>>(Sst, Lam);

    bigout<<<dim3(2, 4, B_*NSUP), 256, 0, stream>>>(Qb, Pre, Sst, Pb, VT, xb);

    mfma_gemm<<<dim3(M_/128, D_/128), 256, 0, stream>>>(xb, Wb + 4*(size_t)D_*D_, bo, (float*)d_out);
}

// Round 6
// 218.144 us; speedup vs baseline: 11.1989x; 1.0824x over previous
//
#include <hip/hip_runtime.h>
#include <hip/hip_bf16.h>
#include <stdint.h>

// SRALayer R6: chunked GLA. R5 + (a) T2 XOR-swizzle on all gload_lds GEMM LDS tiles
// (linear dest + inverse-swizzled global source + swizzled frag read), (b) coalesced
// epilogues through LDS (256B row stores), (c) V-section operand swap -> direct V^T.

#define B_ 8
#define S_ 2048
#define D_ 512
#define M_ (B_ * S_)
#define NSUB 64
#define SUBL 32
#define NSUP 8
#define SUPL 256

typedef __bf16 bf16x8 __attribute__((ext_vector_type(8)));
typedef float f32x4 __attribute__((ext_vector_type(4)));

__device__ __forceinline__ float bflo(uint32_t u){ return __uint_as_float(u<<16); }
__device__ __forceinline__ float bfhi(uint32_t u){ return __uint_as_float(u&0xffff0000u); }
__device__ __forceinline__ uint16_t f2bf(float f){
    uint32_t u = __float_as_uint(f);
    return (uint16_t)((u + 0x7fffu + ((u>>16)&1u)) >> 16);
}
__device__ __forceinline__ uint32_t pack2bf(float a, float b){
    return (uint32_t)f2bf(a) | ((uint32_t)f2bf(b)<<16);
}
__device__ __forceinline__ void gload16(const void* g, void* l){
    __builtin_amdgcn_global_load_lds(
        (const __attribute__((address_space(1))) uint32_t*)g,
        (__attribute__((address_space(3))) uint32_t*)l, 16, 0, 0);
}

// ---------------- fp32 -> bf16 converters -----------------------------------------
__global__ __launch_bounds__(256) void conv_x(const float* __restrict__ in,
                                              uint16_t* __restrict__ out){
    const size_t i = ((size_t)blockIdx.x*256 + threadIdx.x)*8;
    float4 a = *(const float4*)&in[i];
    float4 b = *(const float4*)&in[i+4];
    uint4 o; o.x=pack2bf(a.x,a.y); o.y=pack2bf(a.z,a.w); o.z=pack2bf(b.x,b.y); o.w=pack2bf(b.z,b.w);
    *(uint4*)&out[i] = o;
}
__global__ __launch_bounds__(256) void conv_w(const float* w0, const float* w1, const float* w2,
                                              const float* w3, const float* w4,
                                              uint16_t* __restrict__ out){
    const float* ws[5] = {w0,w1,w2,w3,w4};
    const float* in = ws[blockIdx.y];
    uint16_t* o = out + (size_t)blockIdx.y*D_*D_;
    const size_t i = ((size_t)blockIdx.x*256 + threadIdx.x)*8;
    float4 a = *(const float4*)&in[i];
    float4 b = *(const float4*)&in[i+4];
    uint4 u; u.x=pack2bf(a.x,a.y); u.y=pack2bf(a.z,a.w); u.z=pack2bf(b.x,b.y); u.w=pack2bf(b.z,b.w);
    *(uint4*)&o[i] = u;
}

// ---------------- proj4: fused Q|K|V|G projection GEMM, N=2048 ---------------------
// grid (M_/128, 16). sect = by>>2 : 0=Q(bf16) 1=K(bf16) 2=V^T(swapped mfma) 3=G(sigmoid fp32)
__global__ __launch_bounds__(256) void proj4(const uint16_t* __restrict__ A,
                                             const uint16_t* __restrict__ Wb,
                                             const float* __restrict__ bq_,
                                             const float* __restrict__ bk_,
                                             const float* __restrict__ bv_,
                                             const float* __restrict__ bg_,
                                             uint16_t* __restrict__ Qb,
                                             uint16_t* __restrict__ Kb,
                                             uint16_t* __restrict__ VT,
                                             float* __restrict__ Gf)
{
    __shared__ __attribute__((aligned(16))) uint16_t SM[17472];
    uint16_t* As = SM;
    uint16_t* Bs = SM + 8192;
    const int tid = threadIdx.x, wave = tid>>6, lane = tid&63;
    const int m0 = blockIdx.x*128, n0 = blockIdx.y*128;
    const int wr = (wave>>1)*64, wc = (wave&1)*64;
    const int fr = lane&15, fq = lane>>4;
    const int sect = blockIdx.y >> 2;
    const int n0c = n0 & 511;
    f32x4 acc[4][4] = {};

    for (int k0 = 0; k0 < D_; k0 += 64) {
        __syncthreads();
#pragma unroll
        for (int i = 0; i < 4; ++i) {
            const int c = i*256 + tid;
            const int row = c>>3, kc = ((c&7) ^ (row&7))*8;   // inverse-swizzled source
            const int ldsb = (i*256 + wave*64)*8;             // linear LDS dest
            gload16(&A [(size_t)(m0+row)*D_ + k0 + kc], &As[ldsb]);
            gload16(&Wb[(size_t)(n0+row)*D_ + k0 + kc], &Bs[ldsb]);
        }
        __syncthreads();
#pragma unroll
        for (int kk = 0; kk < 64; kk += 32) {
            const int sc = (kk + fq*8) ^ ((fr&7)<<3);         // swizzled frag column
            bf16x8 af[4], bf[4];
#pragma unroll
            for (int m = 0; m < 4; ++m) af[m] = *(const bf16x8*)&As[(wr+m*16+fr)*64 + sc];
#pragma unroll
            for (int n = 0; n < 4; ++n) bf[n] = *(const bf16x8*)&Bs[(wc+n*16+fr)*64 + sc];
            if (sect == 2) {
#pragma unroll
                for (int m = 0; m < 4; ++m)
#pragma unroll
                    for (int n = 0; n < 4; ++n)
                        acc[m][n] = __builtin_amdgcn_mfma_f32_16x16x32_bf16(bf[n], af[m], acc[m][n], 0,0,0);
            } else {
#pragma unroll
                for (int m = 0; m < 4; ++m)
#pragma unroll
                    for (int n = 0; n < 4; ++n)
                        acc[m][n] = __builtin_amdgcn_mfma_f32_16x16x32_bf16(af[m], bf[n], acc[m][n], 0,0,0);
            }
        }
    }
    __syncthreads();   // all frag reads done before LDS reuse

    if (sect == 3) {                       // G: fp32 sigmoid, 2 column-half passes
        float (*L32)[68] = (float(*)[68])SM;
#pragma unroll
        for (int h = 0; h < 2; ++h) {
            if (wc == h*64) {
#pragma unroll
                for (int n = 0; n < 4; ++n) {
                    const float bvv = bg_[n0c + wc + n*16 + fr];
#pragma unroll
                    for (int m = 0; m < 4; ++m)
#pragma unroll
                        for (int q = 0; q < 4; ++q)
                            L32[wr + m*16 + fq*4 + q][n*16 + fr] =
                                1.f/(1.f + expf(-(acc[m][n][q] + bvv)));
                }
            }
            __syncthreads();
#pragma unroll
            for (int it = 0; it < 8; ++it) {
                const int r = it*16 + (tid>>4), c4 = (tid&15)*4;
                *(uint4*)&Gf[(size_t)(m0+r)*D_ + n0c + h*64 + c4] = *(uint4*)&L32[r][c4];
            }
            __syncthreads();
        }
    } else {
        uint16_t (*L)[136] = (uint16_t(*)[136])SM;
        const float* bias = (sect==0) ? bq_ : (sect==1) ? bk_ : bv_;
        if (sect == 2) {                   // acc holds V^T[dv][t]
#pragma unroll
            for (int n = 0; n < 4; ++n)
#pragma unroll
                for (int q = 0; q < 4; ++q) {
                    const int dvl = wc + n*16 + fq*4 + q;
                    const float bvv = bias[n0c + dvl];
#pragma unroll
                    for (int m = 0; m < 4; ++m)
                        L[dvl][wr + m*16 + fr] = f2bf(acc[m][n][q] + bvv);
                }
        } else {
#pragma unroll
            for (int n = 0; n < 4; ++n) {
                const int cl = wc + n*16 + fr;
                const float bvv = bias[n0c + cl];
#pragma unroll
                for (int m = 0; m < 4; ++m)
#pragma unroll
                    for (int q = 0; q < 4; ++q)
                        L[wr + m*16 + fq*4 + q][cl] = f2bf(acc[m][n][q] + bvv);
            }
        }
        __syncthreads();
        const int bb = m0 >> 11, t0 = m0 & 2047;
#pragma unroll
        for (int it = 0; it < 8; ++it) {
            const int r = it*16 + (tid>>4), c8 = (tid&15)*8;
            uint4 v = *(uint4*)&L[r][c8];
            if (sect == 0)      *(uint4*)&Qb[(size_t)(m0+r)*D_ + n0c + c8] = v;
            else if (sect == 1) *(uint4*)&Kb[(size_t)(m0+r)*D_ + n0c + c8] = v;
            else                *(uint4*)&VT[((size_t)bb*D_ + n0c + r)*S_ + t0 + c8] = v;
        }
    }
}

// ---------------- mfma_gemm: final output projection (fp32 out, swz + LDS epi) -----
__global__ __launch_bounds__(256) void mfma_gemm(const uint16_t* __restrict__ A,
                                                 const uint16_t* __restrict__ Wt,
                                                 const float* __restrict__ bias,
                                                 float* __restrict__ out)
{
    __shared__ __attribute__((aligned(16))) uint16_t SM[17472];
    uint16_t* As = SM;
    uint16_t* Bs = SM + 8192;
    const int tid = threadIdx.x, wave = tid>>6, lane = tid&63;
    const int m0 = blockIdx.x*128, n0 = blockIdx.y*128;
    const int wr = (wave>>1)*64, wc = (wave&1)*64;
    const int fr = lane&15, fq = lane>>4;
    f32x4 acc[4][4] = {};

    for (int k0 = 0; k0 < D_; k0 += 64) {
        __syncthreads();
#pragma unroll
        for (int i = 0; i < 4; ++i) {
            const int c = i*256 + tid;
            const int row = c>>3, kc = ((c&7) ^ (row&7))*8;
            const int ldsb = (i*256 + wave*64)*8;
            gload16(&A [(size_t)(m0+row)*D_ + k0 + kc], &As[ldsb]);
            gload16(&Wt[(size_t)(n0+row)*D_ + k0 + kc], &Bs[ldsb]);
        }
        __syncthreads();
#pragma unroll
        for (int kk = 0; kk < 64; kk += 32) {
            const int sc = (kk + fq*8) ^ ((fr&7)<<3);
            bf16x8 af[4], bf[4];
#pragma unroll
            for (int m = 0; m < 4; ++m) af[m] = *(const bf16x8*)&As[(wr+m*16+fr)*64 + sc];
#pragma unroll
            for (int n = 0; n < 4; ++n) bf[n] = *(const bf16x8*)&Bs[(wc+n*16+fr)*64 + sc];
#pragma unroll
            for (int m = 0; m < 4; ++m)
#pragma unroll
                for (int n = 0; n < 4; ++n)
                    acc[m][n] = __builtin_amdgcn_mfma_f32_16x16x32_bf16(af[m], bf[n], acc[m][n], 0,0,0);
        }
    }
    __syncthreads();
    float (*L32)[68] = (float(*)[68])SM;
#pragma unroll
    for (int h = 0; h < 2; ++h) {
        if (wc == h*64) {
#pragma unroll
            for (int n = 0; n < 4; ++n) {
                const float bvv = bias[n0 + wc + n*16 + fr];
#pragma unroll
                for (int m = 0; m < 4; ++m)
#pragma unroll
                    for (int q = 0; q < 4; ++q)
                        L32[wr + m*16 + fq*4 + q][n*16 + fr] = acc[m][n][q] + bvv;
            }
        }
        __syncthreads();
#pragma unroll
        for (int it = 0; it < 8; ++it) {
            const int r = it*16 + (tid>>4), c4 = (tid&15)*4;
            *(uint4*)&out[(size_t)(m0+r)*D_ + n0 + h*64 + c4] = *(uint4*)&L32[r][c4];
        }
        __syncthreads();
    }
}

// ---------------- prep: LDS-free. thread owns 2 dk cols over 32 t ------------------
__global__ __launch_bounds__(256) void prep(const float* __restrict__ Gf,
                                            uint16_t* __restrict__ Qb,
                                            uint16_t* __restrict__ Kb,
                                            uint16_t* __restrict__ KT,
                                            float* __restrict__ T)
{
    const int sub = blockIdx.x, b = blockIdx.y;
    const int tid = threadIdx.x;
    const int dk0 = tid*2;
    const size_t rowbase = ((size_t)b*S_ + sub*SUBL)*D_;
    const float*    gp = Gf + rowbase + dk0;
    uint16_t*       qp = Qb + rowbase + dk0;
    uint16_t*       kp = Kb + rowbase + dk0;

    float mu0 = 1.f, mu1 = 1.f;
    uint32_t ksave[SUBL];
#pragma unroll
    for (int t = 0; t < SUBL; ++t) {
        const float2   g  = *(const float2*)(gp + (size_t)t*D_);
        const uint32_t qu = *(const uint32_t*)(qp + (size_t)t*D_);
        const uint32_t ku = *(const uint32_t*)(kp + (size_t)t*D_);
        mu0 = fmaxf(mu0*g.x, 1e-30f);
        mu1 = fmaxf(mu1*g.y, 1e-30f);
        const float r0 = __builtin_amdgcn_rcpf(mu0);
        const float r1 = __builtin_amdgcn_rcpf(mu1);
        *(uint32_t*)(qp + (size_t)t*D_) = pack2bf(bflo(qu)*mu0, bfhi(qu)*mu1);
        const uint32_t kw = pack2bf(bflo(ku)*r0, bfhi(ku)*r1);
        *(uint32_t*)(kp + (size_t)t*D_) = kw;
        ksave[t] = kw;
    }
    T[((size_t)b*NSUB + sub)*D_ + dk0]     = mu0;
    T[((size_t)b*NSUB + sub)*D_ + dk0 + 1] = mu1;

    uint16_t* d0 = &KT[((size_t)b*D_ + dk0)*S_ + sub*SUBL];
    uint16_t* d1 = d0 + S_;
#pragma unroll
    for (int q4 = 0; q4 < 4; ++q4) {
        uint4 lo, hi;
        lo.x = (ksave[q4*8+0]&0xffffu) | (ksave[q4*8+1]<<16);
        lo.y = (ksave[q4*8+2]&0xffffu) | (ksave[q4*8+3]<<16);
        lo.z = (ksave[q4*8+4]&0xffffu) | (ksave[q4*8+5]<<16);
        lo.w = (ksave[q4*8+6]&0xffffu) | (ksave[q4*8+7]<<16);
        hi.x = (ksave[q4*8+0]>>16) | (ksave[q4*8+1]&0xffff0000u);
        hi.y = (ksave[q4*8+2]>>16) | (ksave[q4*8+3]&0xffff0000u);
        hi.z = (ksave[q4*8+4]>>16) | (ksave[q4*8+5]&0xffff0000u);
        hi.w = (ksave[q4*8+6]>>16) | (ksave[q4*8+7]&0xffff0000u);
        *(uint4*)&d0[q4*8] = lo;
        *(uint4*)&d1[q4*8] = hi;
    }
}

// ---------------- tables: Pre / Suf / Lam from T -----------------------------------
__global__ __launch_bounds__(512) void tables(const float* __restrict__ T,
                                              float* __restrict__ Pre,
                                              float* __restrict__ Suf,
                                              float* __restrict__ Lam)
{
    const int b = blockIdx.x, dk = threadIdx.x;
    for (int sp = 0; sp < NSUP; ++sp) {
        float run = 1.f;
#pragma unroll
        for (int m = 0; m < 8; ++m) {
            Pre[((size_t)b*NSUB + sp*8+m)*D_ + dk] = run;
            run *= T[((size_t)b*NSUB + sp*8+m)*D_ + dk];
        }
        Lam[((size_t)b*NSUP + sp)*D_ + dk] = run;
        float rs = 1.f;
#pragma unroll
        for (int m = 7; m >= 0; --m) {
            rs *= T[((size_t)b*NSUB + sp*8+m)*D_ + dk];
            Suf[((size_t)b*NSUB + sp*8+m)*D_ + dk] = rs;
        }
    }
}

// ---------------- pairsA: P_ij = Q~_i @ (D_ij * K^_j)^T, self-masked ---------------
__device__ __forceinline__ int swz(int r, int c){ return r*D_ + (c ^ ((r&7)<<3)); }

__global__ __launch_bounds__(256) void pairsA(const uint16_t* __restrict__ Qt,
                                              const uint16_t* __restrict__ Kh,
                                              const float* __restrict__ T,
                                              uint16_t* __restrict__ P)
{
    __shared__ __attribute__((aligned(16))) uint16_t qs[SUBL*D_];
    __shared__ __attribute__((aligned(16))) uint16_t ks[SUBL*D_];
    __shared__ float D_lds[D_];
    const int bx = blockIdx.x, sp = blockIdx.y, b = blockIdx.z;
    const int tid = threadIdx.x, wave = tid>>6, lane = tid&63;
    const int fr = lane&15, fq = lane>>4;
    const int mq = wave>>1, nq = wave&1;
    const int dkA = tid*2, dkB = tid*2+1;

    for (int ii = 0; ii < 2; ++ii) {
        const int i = ii ? 7-bx : bx;
        const size_t qrow = (size_t)b*S_ + sp*SUPL + i*SUBL;
        const size_t prow = ((size_t)(b*NSUP + sp)*SUPL + i*SUBL);

#pragma unroll
        for (int z = 0; z < 8; ++z) {
            int ch = z*256 + tid, r = ch>>6, c = (ch&63)*8;
            *(uint4*)&qs[swz(r,c)] = *(const uint4*)&Qt[(qrow + r)*D_ + c];
            *(uint4*)&ks[swz(r,c)] = *(const uint4*)&Kh[(qrow + r)*D_ + c];
        }
        float d0 = 1.f, d1 = 1.f;

        for (int j = i; j >= 0; --j) {
            if (j < i) {
                d0 *= T[((size_t)b*NSUB + sp*8 + j)*D_ + dkA];
                d1 *= T[((size_t)b*NSUB + sp*8 + j)*D_ + dkB];
                D_lds[dkA] = d0; D_lds[dkB] = d1;
                __syncthreads();
#pragma unroll
                for (int z = 0; z < 8; ++z) {
                    int ch = z*256 + tid, r = ch>>6, c = (ch&63)*8;
                    uint4 u = *(const uint4*)&Kh[((size_t)b*S_ + sp*SUPL + j*SUBL + r)*D_ + c];
                    uint4 o;
                    o.x = pack2bf(bflo(u.x)*D_lds[c+0], bfhi(u.x)*D_lds[c+1]);
                    o.y = pack2bf(bflo(u.y)*D_lds[c+2], bfhi(u.y)*D_lds[c+3]);
                    o.z = pack2bf(bflo(u.z)*D_lds[c+4], bfhi(u.z)*D_lds[c+5]);
                    o.w = pack2bf(bflo(u.w)*D_lds[c+6], bfhi(u.w)*D_lds[c+7]);
                    *(uint4*)&ks[swz(r,c)] = o;
                }
            }
            __syncthreads();
            f32x4 a0 = {}, a1 = {}, a2 = {}, a3 = {};
#pragma unroll
            for (int kk = 0; kk < 512; kk += 128) {
                bf16x8 q0 = *(const bf16x8*)&qs[swz(mq*16+fr, kk      + fq*8)];
                bf16x8 k0 = *(const bf16x8*)&ks[swz(nq*16+fr, kk      + fq*8)];
                bf16x8 q1 = *(const bf16x8*)&qs[swz(mq*16+fr, kk + 32 + fq*8)];
                bf16x8 k1 = *(const bf16x8*)&ks[swz(nq*16+fr, kk + 32 + fq*8)];
                bf16x8 q2 = *(const bf16x8*)&qs[swz(mq*16+fr, kk + 64 + fq*8)];
                bf16x8 k2 = *(const bf16x8*)&ks[swz(nq*16+fr, kk + 64 + fq*8)];
                bf16x8 q3 = *(const bf16x8*)&qs[swz(mq*16+fr, kk + 96 + fq*8)];
                bf16x8 k3 = *(const bf16x8*)&ks[swz(nq*16+fr, kk + 96 + fq*8)];
                a0 = __builtin_amdgcn_mfma_f32_16x16x32_bf16(q0, k0, a0, 0,0,0);
                a1 = __builtin_amdgcn_mfma_f32_16x16x32_bf16(q1, k1, a1, 0,0,0);
                a2 = __builtin_amdgcn_mfma_f32_16x16x32_bf16(q2, k2, a2, 0,0,0);
                a3 = __builtin_amdgcn_mfma_f32_16x16x32_bf16(q3, k3, a3, 0,0,0);
            }
            const int ul = nq*16 + fr;
#pragma unroll
            for (int q_ = 0; q_ < 4; ++q_) {
                const int tl = mq*16 + fq*4 + q_;
                float v = a0[q_] + a1[q_] + a2[q_] + a3[q_];
                if (j == i && ul > tl) v = 0.f;
                P[(prow + tl)*SUPL + j*SUBL + ul] = f2bf(v);
            }
            __syncthreads();
        }
    }
}

// ---------------- dsgemm: dS_c = sum_u (Suf*k^_u) v_u^T  (stored [dv][dk]) ---------
__global__ __launch_bounds__(256) void dsgemm(const uint16_t* __restrict__ VT,
                                              const uint16_t* __restrict__ KT,
                                              const float* __restrict__ Suf,
                                              uint16_t* __restrict__ Sst)
{
    __shared__ __attribute__((aligned(16))) uint16_t As[128][40];
    __shared__ __attribute__((aligned(16))) uint16_t Bs[128][40];
    const int tile = blockIdx.x, c = blockIdx.y, b = blockIdx.z;
    const int m0 = (tile&3)*128, n0 = (tile>>2)*128;
    const int tid = threadIdx.x, wave = tid>>6, lane = tid&63;
    const int wr = (wave>>1)*64, wc = (wave&1)*64;
    const int fr = lane&15, fq = lane>>4;
    f32x4 acc[4][4] = {};

    for (int j = 0; j < 8; ++j) {
        const int t0 = c*SUPL + j*SUBL;
        __syncthreads();
#pragma unroll
        for (int ch = tid; ch < 512; ch += 256) {
            int row = ch>>2, tc = (ch&3)*8;
            *(uint4*)&As[row][tc] = *(const uint4*)&VT[((size_t)b*D_ + m0+row)*S_ + t0 + tc];
        }
#pragma unroll
        for (int ch = tid; ch < 512; ch += 256) {
            int row = ch>>2, tc = (ch&3)*8;
            uint4 u = *(const uint4*)&KT[((size_t)b*D_ + n0+row)*S_ + t0 + tc];
            float sf = Suf[((size_t)b*NSUB + c*8 + j)*D_ + n0 + row];
            uint4 o;
            o.x = pack2bf(bflo(u.x)*sf, bfhi(u.x)*sf);
            o.y = pack2bf(bflo(u.y)*sf, bfhi(u.y)*sf);
            o.z = pack2bf(bflo(u.z)*sf, bfhi(u.z)*sf);
            o.w = pack2bf(bflo(u.w)*sf, bfhi(u.w)*sf);
            *(uint4*)&Bs[row][tc] = o;
        }
        __syncthreads();
        bf16x8 af[4], bf[4];
#pragma unroll
        for (int m = 0; m < 4; ++m) af[m] = *(const bf16x8*)&As[wr+m*16+fr][fq*8];
#pragma unroll
        for (int n = 0; n < 4; ++n) bf[n] = *(const bf16x8*)&Bs[wc+n*16+fr][fq*8];
#pragma unroll
        for (int m = 0; m < 4; ++m)
#pragma unroll
            for (int n = 0; n < 4; ++n)
                acc[m][n] = __builtin_amdgcn_mfma_f32_16x16x32_bf16(af[m], bf[n], acc[m][n], 0,0,0);
    }
#pragma unroll
    for (int n = 0; n < 4; ++n) {
        const int dk = n0 + wc + n*16 + fr;
#pragma unroll
        for (int m = 0; m < 4; ++m)
#pragma unroll
            for (int q = 0; q < 4; ++q) {
                const int dv = m0 + wr + m*16 + fq*4 + q;
                Sst[(((size_t)c*B_ + b)*D_ + dv)*D_ + dk] = f2bf(acc[m][n][q]);
            }
    }
}

// ---------------- scanfix: S_c = Lam_c (x) S_{c-1} + dS_c, c = 1..6 ----------------
__global__ __launch_bounds__(256) void scanfix(uint16_t* __restrict__ Sst,
                                               const float* __restrict__ Lam)
{
    const int id = blockIdx.x*256 + threadIdx.x;
    const int g = id & 63, dv = (id>>6) & 511, b = id >> 15;
    const int dk = g*8;
    float s[8];
    {
        uint4 u = *(const uint4*)&Sst[(((size_t)0*B_ + b)*D_ + dv)*D_ + dk];
        s[0]=bflo(u.x); s[1]=bfhi(u.x); s[2]=bflo(u.y); s[3]=bfhi(u.y);
        s[4]=bflo(u.z); s[5]=bfhi(u.z); s[6]=bflo(u.w); s[7]=bfhi(u.w);
    }
    for (int c = 1; c < 7; ++c) {
        const size_t bs = (((size_t)c*B_ + b)*D_ + dv)*D_ + dk;
        uint4 d = *(const uint4*)&Sst[bs];
        float4 l0 = *(const float4*)&Lam[((size_t)b*NSUP + c)*D_ + dk];
        float4 l1 = *(const float4*)&Lam[((size_t)b*NSUP + c)*D_ + dk + 4];
        s[0] = l0.x*s[0] + bflo(d.x); s[1] = l0.y*s[1] + bfhi(d.x);
        s[2] = l0.z*s[2] + bflo(d.y); s[3] = l0.w*s[3] + bfhi(d.y);
        s[4] = l1.x*s[4] + bflo(d.z); s[5] = l1.y*s[5] + bfhi(d.z);
        s[6] = l1.z*s[6] + bflo(d.w); s[7] = l1.w*s[7] + bfhi(d.w);
        uint4 o;
        o.x = pack2bf(s[0],s[1]); o.y = pack2bf(s[2],s[3]);
        o.z = pack2bf(s[4],s[5]); o.w = pack2bf(s[6],s[7]);
        *(uint4*)&Sst[bs] = o;
    }
}

// ---------------- bigout: O = [Q~*Pre | P] @ [S_prev ; V], K=768, swz + LDS epi ----
__global__ __launch_bounds__(256) void bigout(const uint16_t* __restrict__ Qt,
                                              const float* __restrict__ Pre,
                                              const uint16_t* __restrict__ Sst,
                                              const uint16_t* __restrict__ Pb,
                                              const uint16_t* __restrict__ VT,
                                              uint16_t* __restrict__ O)
{
    __shared__ __attribute__((aligned(16))) uint16_t SM[17472];
    __shared__ float PreL[4*512];
    uint16_t* As = SM;
    uint16_t* Bs = SM + 8192;
    const int m0 = blockIdx.x*128, n0 = blockIdx.y*128;
    const int b = blockIdx.z>>3, sp = blockIdx.z&7;
    const int tid = threadIdx.x, wave = tid>>6, lane = tid&63;
    const int wr = (wave>>1)*64, wc = (wave&1)*64;
    const int fr = lane&15, fq = lane>>4;
    const int i0 = m0>>5;

#pragma unroll
    for (int z = 0; z < 8; ++z) {
        int idx = z*256 + tid;
        PreL[idx] = Pre[((size_t)b*NSUB + sp*8 + i0 + (idx>>9))*D_ + (idx&511)];
    }
    f32x4 acc[4][4] = {};
    const int kt0 = (sp == 0) ? 8 : 0;
    for (int kt = kt0; kt < 12; ++kt) {
        __syncthreads();
        if (kt < 8) {
            const int k0 = kt*64;
#pragma unroll
            for (int z = 0; z < 4; ++z) {       // A: reg-staged Q~ * Pre, swizzled ds_write
                int ch = z*256 + tid, r = ch>>3, cc = (ch&7)*8;
                uint4 u = *(const uint4*)&Qt[((size_t)b*S_ + sp*SUPL + m0 + r)*D_ + k0 + cc];
                const float* pr = &PreL[((r>>5)<<9) + k0 + cc];
                uint4 o;
                o.x = pack2bf(bflo(u.x)*pr[0], bfhi(u.x)*pr[1]);
                o.y = pack2bf(bflo(u.y)*pr[2], bfhi(u.y)*pr[3]);
                o.z = pack2bf(bflo(u.z)*pr[4], bfhi(u.z)*pr[5]);
                o.w = pack2bf(bflo(u.w)*pr[6], bfhi(u.w)*pr[7]);
                *(uint4*)&As[r*64 + (cc ^ ((r&7)<<3))] = o;
            }
#pragma unroll
            for (int z = 0; z < 4; ++z) {       // B: S_prev rows, swizzled source
                int ch = z*256 + tid, row = ch>>3, kc = ((ch&7) ^ (row&7))*8;
                int ldsb = (z*256 + wave*64)*8;
                gload16(&Sst[(((size_t)(sp-1)*B_ + b)*D_ + n0 + row)*D_ + k0 + kc], &Bs[ldsb]);
            }
        } else {
            const int u0 = (kt-8)*64;
#pragma unroll
            for (int z = 0; z < 4; ++z) {
                int ch = z*256 + tid, row = ch>>3, kc = ((ch&7) ^ (row&7))*8;
                int ldsb = (z*256 + wave*64)*8;
                gload16(&Pb[((size_t)(b*NSUP + sp)*SUPL + m0 + row)*SUPL + u0 + kc], &As[ldsb]);
                gload16(&VT[((size_t)b*D_ + n0 + row)*S_ + sp*SUPL + u0 + kc], &Bs[ldsb]);
            }
        }
        __syncthreads();
#pragma unroll
        for (int kk = 0; kk < 64; kk += 32) {
            const int sc = (kk + fq*8) ^ ((fr&7)<<3);
            bf16x8 af[4], bf[4];
#pragma unroll
            for (int m = 0; m < 4; ++m) af[m] = *(const bf16x8*)&As[(wr+m*16+fr)*64 + sc];
#pragma unroll
            for (int n = 0; n < 4; ++n) bf[n] = *(const bf16x8*)&Bs[(wc+n*16+fr)*64 + sc];
#pragma unroll
            for (int m = 0; m < 4; ++m)
#pragma unroll
                for (int n = 0; n < 4; ++n)
                    acc[m][n] = __builtin_amdgcn_mfma_f32_16x16x32_bf16(af[m], bf[n], acc[m][n], 0,0,0);
        }
    }
    __syncthreads();
    uint16_t (*L)[136] = (uint16_t(*)[136])SM;
#pragma unroll
    for (int n = 0; n < 4; ++n) {
        const int cl = wc + n*16 + fr;
#pragma unroll
        for (int m = 0; m < 4; ++m)
#pragma unroll
            for (int q = 0; q < 4; ++q)
                L[wr + m*16 + fq*4 + q][cl] = f2bf(acc[m][n][q]);
    }
    __syncthreads();
#pragma unroll
    for (int it = 0; it < 8; ++it) {
        const int r = it*16 + (tid>>4), c8 = (tid&15)*8;
        *(uint4*)&O[((size_t)b*S_ + sp*SUPL + m0 + r)*D_ + n0 + c8] = *(uint4*)&L[r][c8];
    }
}

// ---------------- launch ----------------------------------------------------------
extern "C" void kernel_launch(void* const* d_in, const int* in_sizes, int n_in,
                              void* d_out, int out_size, void* d_ws, size_t ws_size,
                              hipStream_t stream)
{
    (void)in_sizes; (void)n_in; (void)out_size; (void)ws_size;
    const float* x  = (const float*)d_in[0];
    const float* Wq = (const float*)d_in[1];  const float* bq = (const float*)d_in[2];
    const float* Wk = (const float*)d_in[3];  const float* bk = (const float*)d_in[4];
    const float* Wv = (const float*)d_in[5];  const float* bv = (const float*)d_in[6];
    const float* Wg = (const float*)d_in[7];  const float* bg = (const float*)d_in[8];
    const float* Wo = (const float*)d_in[9];  const float* bo = (const float*)d_in[10];

    char* w = (char*)d_ws;
    const size_t MD2 = (size_t)M_*D_*2;
    uint16_t* Wb = (uint16_t*)w;                       w += 5*(size_t)D_*D_*2;
    uint16_t* xb = (uint16_t*)w;                       w += MD2;                  // x, later O
    uint16_t* Qb = (uint16_t*)w;                       w += MD2;                  // Q -> Q~
    uint16_t* Kb = (uint16_t*)w;                       w += MD2;                  // K -> K^ rows
    uint16_t* KT = (uint16_t*)w;                       w += MD2;                  // K^T [b][dk][t]
    uint16_t* VT = (uint16_t*)w;                       w += MD2;                  // V^T [b][dv][t]
    float*    Gf = (float*)w;                          w += (size_t)M_*D_*4;
    uint16_t* Sst = (uint16_t*)w;                      w += (size_t)7*B_*D_*D_*2;
    uint16_t* Pb  = (uint16_t*)w;                      w += (size_t)B_*NSUP*SUPL*SUPL*2;
    float*    T   = (float*)w;                         w += (size_t)B_*NSUB*D_*4;
    float*    Pre = (float*)w;                         w += (size_t)B_*NSUB*D_*4;
    float*    Suf = (float*)w;                         w += (size_t)B_*NSUB*D_*4;
    float*    Lam = (float*)w;                         w += (size_t)B_*NSUP*D_*4;

    hipMemsetAsync(Pb, 0, (size_t)B_*NSUP*SUPL*SUPL*2, stream);

    conv_x<<<dim3(M_*D_/2048), 256, 0, stream>>>(x, xb);
    conv_w<<<dim3(D_*D_/2048, 5), 256, 0, stream>>>(Wq, Wk, Wv, Wg, Wo, Wb);

    proj4<<<dim3(M_/128, 16), 256, 0, stream>>>(xb, Wb, bq, bk, bv, bg, Qb, Kb, VT, Gf);

    prep<<<dim3(NSUB, B_), 256, 0, stream>>>(Gf, Qb, Kb, KT, T);
    tables<<<dim3(B_), 512, 0, stream>>>(T, Pre, Suf, Lam);

    pairsA<<<dim3(4, NSUP, B_), 256, 0, stream>>>(Qb, Kb, T, Pb);
    dsgemm<<<dim3(16, 7, B_), 256, 0, stream>>>(VT, KT, Suf, Sst);
    scanfix<<<dim3(1024), 256, 0, stream>>>(Sst, Lam);

    bigout<<<dim3(2, 4, B_*NSUP), 256, 0, stream>>>(Qb, Pre, Sst, Pb, VT, xb);

    mfma_gemm<<<dim3(M_/128, D_/128), 256, 0, stream>>>(xb, Wb + 4*(size_t)D_*D_, bo, (float*)d_out);
}

// Round 7
// 201.934 us; speedup vs baseline: 12.0979x; 1.0803x over previous
//
#include <hip/hip_runtime.h>
#include <hip/hip_bf16.h>
#include <stdint.h>

// SRALayer R7: chunked GLA.
//  - 2-phase double-buffered GEMM pipeline (stage(k+1) before compute(k), 1 barrier/step)
//    in proj4 / outproj / bigout / dsgemm.
//  - pairsA: flat lower-tri (i,j) grid (2304 blocks), per-block D from T.
//  - bigout masks upper-tri P blocks -> no Pb memset.
//  - gamma stored bf16 (Gb), prep reads bf16.

#define B_ 8
#define S_ 2048
#define D_ 512
#define M_ (B_ * S_)
#define NSUB 64
#define SUBL 32
#define NSUP 8
#define SUPL 256

typedef __bf16 bf16x8 __attribute__((ext_vector_type(8)));
typedef float f32x4 __attribute__((ext_vector_type(4)));

__device__ __forceinline__ float bflo(uint32_t u){ return __uint_as_float(u<<16); }
__device__ __forceinline__ float bfhi(uint32_t u){ return __uint_as_float(u&0xffff0000u); }
__device__ __forceinline__ uint16_t f2bf(float f){
    uint32_t u = __float_as_uint(f);
    return (uint16_t)((u + 0x7fffu + ((u>>16)&1u)) >> 16);
}
__device__ __forceinline__ uint32_t pack2bf(float a, float b){
    return (uint32_t)f2bf(a) | ((uint32_t)f2bf(b)<<16);
}
__device__ __forceinline__ void gload16(const void* g, void* l){
    __builtin_amdgcn_global_load_lds(
        (const __attribute__((address_space(1))) uint32_t*)g,
        (__attribute__((address_space(3))) uint32_t*)l, 16, 0, 0);
}

// ---------------- fp32 -> bf16 converters -----------------------------------------
__global__ __launch_bounds__(256) void conv_x(const float* __restrict__ in,
                                              uint16_t* __restrict__ out){
    const size_t i = ((size_t)blockIdx.x*256 + threadIdx.x)*8;
    float4 a = *(const float4*)&in[i];
    float4 b = *(const float4*)&in[i+4];
    uint4 o; o.x=pack2bf(a.x,a.y); o.y=pack2bf(a.z,a.w); o.z=pack2bf(b.x,b.y); o.w=pack2bf(b.z,b.w);
    *(uint4*)&out[i] = o;
}
__global__ __launch_bounds__(256) void conv_w(const float* w0, const float* w1, const float* w2,
                                              const float* w3, const float* w4,
                                              uint16_t* __restrict__ out){
    const float* ws[5] = {w0,w1,w2,w3,w4};
    const float* in = ws[blockIdx.y];
    uint16_t* o = out + (size_t)blockIdx.y*D_*D_;
    const size_t i = ((size_t)blockIdx.x*256 + threadIdx.x)*8;
    float4 a = *(const float4*)&in[i];
    float4 b = *(const float4*)&in[i+4];
    uint4 u; u.x=pack2bf(a.x,a.y); u.y=pack2bf(a.z,a.w); u.z=pack2bf(b.x,b.y); u.w=pack2bf(b.z,b.w);
    *(uint4*)&o[i] = u;
}

// ---------------- proj4: fused Q|K|V|G GEMM, dbuf 2-phase --------------------------
// grid (M_/128, 16). sect = by>>2 : 0=Q 1=K 2=V^T(swapped mfma) 3=G(sigmoid) all bf16 out
__global__ __launch_bounds__(256) void proj4(const uint16_t* __restrict__ A,
                                             const uint16_t* __restrict__ Wb,
                                             const float* __restrict__ bq_,
                                             const float* __restrict__ bk_,
                                             const float* __restrict__ bv_,
                                             const float* __restrict__ bg_,
                                             uint16_t* __restrict__ Qb,
                                             uint16_t* __restrict__ Kb,
                                             uint16_t* __restrict__ VT,
                                             uint16_t* __restrict__ Gb)
{
    __shared__ __attribute__((aligned(16))) uint16_t SM[2][16384];
    const int tid = threadIdx.x, wave = tid>>6, lane = tid&63;
    const int m0 = blockIdx.x*128, n0 = blockIdx.y*128;
    const int wr = (wave>>1)*64, wc = (wave&1)*64;
    const int fr = lane&15, fq = lane>>4;
    const int sect = blockIdx.y >> 2;
    const int n0c = n0 & 511;
    f32x4 acc[4][4] = {};

    auto STAGE = [&](int kt, int p){
        const int k0 = kt*64;
#pragma unroll
        for (int i = 0; i < 4; ++i) {
            const int c = i*256 + tid;
            const int row = c>>3, kc = ((c&7) ^ (row&7))*8;
            const int ldsb = (i*256 + wave*64)*8;
            gload16(&A [(size_t)(m0+row)*D_ + k0 + kc], &SM[p][ldsb]);
            gload16(&Wb[(size_t)(n0+row)*D_ + k0 + kc], &SM[p][8192+ldsb]);
        }
    };
    auto COMP = [&](int p){
#pragma unroll
        for (int kk = 0; kk < 64; kk += 32) {
            const int sc = (kk + fq*8) ^ ((fr&7)<<3);
            bf16x8 af[4], bfv[4];
#pragma unroll
            for (int m = 0; m < 4; ++m) af[m]  = *(const bf16x8*)&SM[p][(wr+m*16+fr)*64 + sc];
#pragma unroll
            for (int n = 0; n < 4; ++n) bfv[n] = *(const bf16x8*)&SM[p][8192+(wc+n*16+fr)*64 + sc];
            if (sect == 2) {
#pragma unroll
                for (int m = 0; m < 4; ++m)
#pragma unroll
                    for (int n = 0; n < 4; ++n)
                        acc[m][n] = __builtin_amdgcn_mfma_f32_16x16x32_bf16(bfv[n], af[m], acc[m][n], 0,0,0);
            } else {
#pragma unroll
                for (int m = 0; m < 4; ++m)
#pragma unroll
                    for (int n = 0; n < 4; ++n)
                        acc[m][n] = __builtin_amdgcn_mfma_f32_16x16x32_bf16(af[m], bfv[n], acc[m][n], 0,0,0);
            }
        }
    };

    STAGE(0, 0);
    __syncthreads();
    int p = 0;
    for (int kt = 0; kt < 8; ++kt) {
        if (kt < 7) STAGE(kt+1, p^1);
        COMP(p);
        __syncthreads();
        p ^= 1;
    }

    uint16_t (*L)[136] = (uint16_t(*)[136])&SM[0][0];
    const float* bias = (sect==0) ? bq_ : (sect==1) ? bk_ : (sect==2) ? bv_ : bg_;
    if (sect == 2) {                   // acc holds V^T[dv][t]
#pragma unroll
        for (int n = 0; n < 4; ++n)
#pragma unroll
            for (int q = 0; q < 4; ++q) {
                const int dvl = wc + n*16 + fq*4 + q;
                const float bvv = bias[n0c + dvl];
#pragma unroll
                for (int m = 0; m < 4; ++m)
                    L[dvl][wr + m*16 + fr] = f2bf(acc[m][n][q] + bvv);
            }
    } else {
#pragma unroll
        for (int n = 0; n < 4; ++n) {
            const int cl = wc + n*16 + fr;
            const float bvv = bias[n0c + cl];
#pragma unroll
            for (int m = 0; m < 4; ++m)
#pragma unroll
                for (int q = 0; q < 4; ++q) {
                    float c = acc[m][n][q] + bvv;
                    if (sect == 3) c = 1.f/(1.f + expf(-c));
                    L[wr + m*16 + fq*4 + q][cl] = f2bf(c);
                }
        }
    }
    __syncthreads();
    const int bb = m0 >> 11, t0 = m0 & 2047;
#pragma unroll
    for (int it = 0; it < 8; ++it) {
        const int r = it*16 + (tid>>4), c8 = (tid&15)*8;
        uint4 v = *(uint4*)&L[r][c8];
        if (sect == 0)      *(uint4*)&Qb[(size_t)(m0+r)*D_ + n0c + c8] = v;
        else if (sect == 1) *(uint4*)&Kb[(size_t)(m0+r)*D_ + n0c + c8] = v;
        else if (sect == 3) *(uint4*)&Gb[(size_t)(m0+r)*D_ + n0c + c8] = v;
        else                *(uint4*)&VT[((size_t)bb*D_ + n0c + r)*S_ + t0 + c8] = v;
    }
}

// ---------------- mfma_gemm: output projection (fp32 out), dbuf 2-phase ------------
__global__ __launch_bounds__(256) void mfma_gemm(const uint16_t* __restrict__ A,
                                                 const uint16_t* __restrict__ Wt,
                                                 const float* __restrict__ bias,
                                                 float* __restrict__ out)
{
    __shared__ __attribute__((aligned(16))) uint16_t SM[2][16384];
    const int tid = threadIdx.x, wave = tid>>6, lane = tid&63;
    const int m0 = blockIdx.x*128, n0 = blockIdx.y*128;
    const int wr = (wave>>1)*64, wc = (wave&1)*64;
    const int fr = lane&15, fq = lane>>4;
    f32x4 acc[4][4] = {};

    auto STAGE = [&](int kt, int p){
        const int k0 = kt*64;
#pragma unroll
        for (int i = 0; i < 4; ++i) {
            const int c = i*256 + tid;
            const int row = c>>3, kc = ((c&7) ^ (row&7))*8;
            const int ldsb = (i*256 + wave*64)*8;
            gload16(&A [(size_t)(m0+row)*D_ + k0 + kc], &SM[p][ldsb]);
            gload16(&Wt[(size_t)(n0+row)*D_ + k0 + kc], &SM[p][8192+ldsb]);
        }
    };
    auto COMP = [&](int p){
#pragma unroll
        for (int kk = 0; kk < 64; kk += 32) {
            const int sc = (kk + fq*8) ^ ((fr&7)<<3);
            bf16x8 af[4], bfv[4];
#pragma unroll
            for (int m = 0; m < 4; ++m) af[m]  = *(const bf16x8*)&SM[p][(wr+m*16+fr)*64 + sc];
#pragma unroll
            for (int n = 0; n < 4; ++n) bfv[n] = *(const bf16x8*)&SM[p][8192+(wc+n*16+fr)*64 + sc];
#pragma unroll
            for (int m = 0; m < 4; ++m)
#pragma unroll
                for (int n = 0; n < 4; ++n)
                    acc[m][n] = __builtin_amdgcn_mfma_f32_16x16x32_bf16(af[m], bfv[n], acc[m][n], 0,0,0);
        }
    };

    STAGE(0, 0);
    __syncthreads();
    int p = 0;
    for (int kt = 0; kt < 8; ++kt) {
        if (kt < 7) STAGE(kt+1, p^1);
        COMP(p);
        __syncthreads();
        p ^= 1;
    }

    float (*L32)[68] = (float(*)[68])&SM[0][0];
#pragma unroll
    for (int h = 0; h < 2; ++h) {
        if (wc == h*64) {
#pragma unroll
            for (int n = 0; n < 4; ++n) {
                const float bvv = bias[n0 + wc + n*16 + fr];
#pragma unroll
                for (int m = 0; m < 4; ++m)
#pragma unroll
                    for (int q = 0; q < 4; ++q)
                        L32[wr + m*16 + fq*4 + q][n*16 + fr] = acc[m][n][q] + bvv;
            }
        }
        __syncthreads();
#pragma unroll
        for (int it = 0; it < 8; ++it) {
            const int r = it*16 + (tid>>4), c4 = (tid&15)*4;
            *(uint4*)&out[(size_t)(m0+r)*D_ + n0 + h*64 + c4] = *(uint4*)&L32[r][c4];
        }
        __syncthreads();
    }
}

// ---------------- prep: LDS-free, bf16 gamma in ------------------------------------
__global__ __launch_bounds__(256) void prep(const uint16_t* __restrict__ Gb,
                                            uint16_t* __restrict__ Qb,
                                            uint16_t* __restrict__ Kb,
                                            uint16_t* __restrict__ KT,
                                            float* __restrict__ T)
{
    const int sub = blockIdx.x, b = blockIdx.y;
    const int tid = threadIdx.x;
    const int dk0 = tid*2;
    const size_t rowbase = ((size_t)b*S_ + sub*SUBL)*D_;
    const uint16_t* gp = Gb + rowbase + dk0;
    uint16_t*       qp = Qb + rowbase + dk0;
    uint16_t*       kp = Kb + rowbase + dk0;

    float mu0 = 1.f, mu1 = 1.f;
    uint32_t ksave[SUBL];
#pragma unroll
    for (int t = 0; t < SUBL; ++t) {
        const uint32_t g2 = *(const uint32_t*)(gp + (size_t)t*D_);
        const uint32_t qu = *(const uint32_t*)(qp + (size_t)t*D_);
        const uint32_t ku = *(const uint32_t*)(kp + (size_t)t*D_);
        mu0 = fmaxf(mu0*bflo(g2), 1e-30f);
        mu1 = fmaxf(mu1*bfhi(g2), 1e-30f);
        const float r0 = __builtin_amdgcn_rcpf(mu0);
        const float r1 = __builtin_amdgcn_rcpf(mu1);
        *(uint32_t*)(qp + (size_t)t*D_) = pack2bf(bflo(qu)*mu0, bfhi(qu)*mu1);
        const uint32_t kw = pack2bf(bflo(ku)*r0, bfhi(ku)*r1);
        *(uint32_t*)(kp + (size_t)t*D_) = kw;
        ksave[t] = kw;
    }
    T[((size_t)b*NSUB + sub)*D_ + dk0]     = mu0;
    T[((size_t)b*NSUB + sub)*D_ + dk0 + 1] = mu1;

    uint16_t* d0 = &KT[((size_t)b*D_ + dk0)*S_ + sub*SUBL];
    uint16_t* d1 = d0 + S_;
#pragma unroll
    for (int q4 = 0; q4 < 4; ++q4) {
        uint4 lo, hi;
        lo.x = (ksave[q4*8+0]&0xffffu) | (ksave[q4*8+1]<<16);
        lo.y = (ksave[q4*8+2]&0xffffu) | (ksave[q4*8+3]<<16);
        lo.z = (ksave[q4*8+4]&0xffffu) | (ksave[q4*8+5]<<16);
        lo.w = (ksave[q4*8+6]&0xffffu) | (ksave[q4*8+7]<<16);
        hi.x = (ksave[q4*8+0]>>16) | (ksave[q4*8+1]&0xffff0000u);
        hi.y = (ksave[q4*8+2]>>16) | (ksave[q4*8+3]&0xffff0000u);
        hi.z = (ksave[q4*8+4]>>16) | (ksave[q4*8+5]&0xffff0000u);
        hi.w = (ksave[q4*8+6]>>16) | (ksave[q4*8+7]&0xffff0000u);
        *(uint4*)&d0[q4*8] = lo;
        *(uint4*)&d1[q4*8] = hi;
    }
}

// ---------------- tables: Pre / Suf / Lam from T, grid (sp,b) ----------------------
__global__ __launch_bounds__(512) void tables(const float* __restrict__ T,
                                              float* __restrict__ Pre,
                                              float* __restrict__ Suf,
                                              float* __restrict__ Lam)
{
    const int sp = blockIdx.x, b = blockIdx.y, dk = threadIdx.x;
    float run = 1.f;
#pragma unroll
    for (int m = 0; m < 8; ++m) {
        Pre[((size_t)b*NSUB + sp*8+m)*D_ + dk] = run;
        run *= T[((size_t)b*NSUB + sp*8+m)*D_ + dk];
    }
    Lam[((size_t)b*NSUP + sp)*D_ + dk] = run;
    float rs = 1.f;
#pragma unroll
    for (int m = 7; m >= 0; --m) {
        rs *= T[((size_t)b*NSUB + sp*8+m)*D_ + dk];
        Suf[((size_t)b*NSUB + sp*8+m)*D_ + dk] = rs;
    }
}

// ---------------- pairsA: flat (i,j) grid, P_ij = Q~_i @ (D_ij * K^_j)^T -----------
__device__ __forceinline__ int swz(int r, int c){ return r*D_ + (c ^ ((r&7)<<3)); }

__global__ __launch_bounds__(256) void pairsA(const uint16_t* __restrict__ Qt,
                                              const uint16_t* __restrict__ Kh,
                                              const float* __restrict__ T,
                                              uint16_t* __restrict__ P)
{
    __shared__ __attribute__((aligned(16))) uint16_t qs[SUBL*D_];
    __shared__ __attribute__((aligned(16))) uint16_t ks[SUBL*D_];
    __shared__ float D_lds[D_];
    const int idx = blockIdx.x, sp = blockIdx.y, b = blockIdx.z;
    int i = 0;
    while (((i+1)*(i+2))/2 <= idx) ++i;
    const int j = idx - (i*(i+1))/2;

    const int tid = threadIdx.x, wave = tid>>6, lane = tid&63;
    const int fr = lane&15, fq = lane>>4;
    const int mq = wave>>1, nq = wave&1;
    const size_t qrow = (size_t)b*S_ + sp*SUPL + i*SUBL;
    const size_t krow = (size_t)b*S_ + sp*SUPL + j*SUBL;
    const size_t prow = ((size_t)(b*NSUP + sp)*SUPL + i*SUBL);

    // stage Q~_i swizzled; compute D_ij per thread (2 dk cols)
#pragma unroll
    for (int z = 0; z < 8; ++z) {
        int ch = z*256 + tid, r = ch>>6, c = (ch&63)*8;
        *(uint4*)&qs[swz(r,c)] = *(const uint4*)&Qt[(qrow + r)*D_ + c];
    }
    const int dkA = tid*2, dkB = tid*2+1;
    float d0 = 1.f, d1 = 1.f;
    for (int m = j; m < i; ++m) {
        d0 *= T[((size_t)b*NSUB + sp*8 + m)*D_ + dkA];
        d1 *= T[((size_t)b*NSUB + sp*8 + m)*D_ + dkB];
    }
    D_lds[dkA] = d0; D_lds[dkB] = d1;
    __syncthreads();

    // stage K^_j scaled by D, swizzled
#pragma unroll
    for (int z = 0; z < 8; ++z) {
        int ch = z*256 + tid, r = ch>>6, c = (ch&63)*8;
        uint4 u = *(const uint4*)&Kh[(krow + r)*D_ + c];
        uint4 o;
        o.x = pack2bf(bflo(u.x)*D_lds[c+0], bfhi(u.x)*D_lds[c+1]);
        o.y = pack2bf(bflo(u.y)*D_lds[c+2], bfhi(u.y)*D_lds[c+3]);
        o.z = pack2bf(bflo(u.z)*D_lds[c+4], bfhi(u.z)*D_lds[c+5]);
        o.w = pack2bf(bflo(u.w)*D_lds[c+6], bfhi(u.w)*D_lds[c+7]);
        *(uint4*)&ks[swz(r,c)] = o;
    }
    __syncthreads();

    f32x4 a0 = {}, a1 = {}, a2 = {}, a3 = {};
#pragma unroll
    for (int kk = 0; kk < 512; kk += 128) {
        bf16x8 q0 = *(const bf16x8*)&qs[swz(mq*16+fr, kk      + fq*8)];
        bf16x8 k0 = *(const bf16x8*)&ks[swz(nq*16+fr, kk      + fq*8)];
        bf16x8 q1 = *(const bf16x8*)&qs[swz(mq*16+fr, kk + 32 + fq*8)];
        bf16x8 k1 = *(const bf16x8*)&ks[swz(nq*16+fr, kk + 32 + fq*8)];
        bf16x8 q2 = *(const bf16x8*)&qs[swz(mq*16+fr, kk + 64 + fq*8)];
        bf16x8 k2 = *(const bf16x8*)&ks[swz(nq*16+fr, kk + 64 + fq*8)];
        bf16x8 q3 = *(const bf16x8*)&qs[swz(mq*16+fr, kk + 96 + fq*8)];
        bf16x8 k3 = *(const bf16x8*)&ks[swz(nq*16+fr, kk + 96 + fq*8)];
        a0 = __builtin_amdgcn_mfma_f32_16x16x32_bf16(q0, k0, a0, 0,0,0);
        a1 = __builtin_amdgcn_mfma_f32_16x16x32_bf16(q1, k1, a1, 0,0,0);
        a2 = __builtin_amdgcn_mfma_f32_16x16x32_bf16(q2, k2, a2, 0,0,0);
        a3 = __builtin_amdgcn_mfma_f32_16x16x32_bf16(q3, k3, a3, 0,0,0);
    }
    const int ul = nq*16 + fr;
#pragma unroll
    for (int q_ = 0; q_ < 4; ++q_) {
        const int tl = mq*16 + fq*4 + q_;
        float v = a0[q_] + a1[q_] + a2[q_] + a3[q_];
        if (i == j && ul > tl) v = 0.f;
        P[(prow + tl)*SUPL + j*SUBL + ul] = f2bf(v);
    }
}

// ---------------- dsgemm: dbuf 2-phase, dS_c = sum_u (Suf*k^_u) v_u^T --------------
__global__ __launch_bounds__(256) void dsgemm(const uint16_t* __restrict__ VT,
                                              const uint16_t* __restrict__ KT,
                                              const float* __restrict__ Suf,
                                              uint16_t* __restrict__ Sst)
{
    __shared__ __attribute__((aligned(16))) uint16_t As[2][128][40];
    __shared__ __attribute__((aligned(16))) uint16_t Bs[2][128][40];
    const int tile = blockIdx.x, c = blockIdx.y, b = blockIdx.z;
    const int m0 = (tile&3)*128, n0 = (tile>>2)*128;
    const int tid = threadIdx.x, wave = tid>>6, lane = tid&63;
    const int wr = (wave>>1)*64, wc = (wave&1)*64;
    const int fr = lane&15, fq = lane>>4;
    f32x4 acc[4][4] = {};

    auto STAGE = [&](int j, int p){
        const int t0 = c*SUPL + j*SUBL;
#pragma unroll
        for (int ch = tid; ch < 512; ch += 256) {
            int row = ch>>2, tc = (ch&3)*8;
            *(uint4*)&As[p][row][tc] = *(const uint4*)&VT[((size_t)b*D_ + m0+row)*S_ + t0 + tc];
        }
#pragma unroll
        for (int ch = tid; ch < 512; ch += 256) {
            int row = ch>>2, tc = (ch&3)*8;
            uint4 u = *(const uint4*)&KT[((size_t)b*D_ + n0+row)*S_ + t0 + tc];
            float sf = Suf[((size_t)b*NSUB + c*8 + j)*D_ + n0 + row];
            uint4 o;
            o.x = pack2bf(bflo(u.x)*sf, bfhi(u.x)*sf);
            o.y = pack2bf(bflo(u.y)*sf, bfhi(u.y)*sf);
            o.z = pack2bf(bflo(u.z)*sf, bfhi(u.z)*sf);
            o.w = pack2bf(bflo(u.w)*sf, bfhi(u.w)*sf);
            *(uint4*)&Bs[p][row][tc] = o;
        }
    };

    STAGE(0, 0);
    __syncthreads();
    int p = 0;
    for (int j = 0; j < 8; ++j) {
        if (j < 7) STAGE(j+1, p^1);
        bf16x8 af[4], bf[4];
#pragma unroll
        for (int m = 0; m < 4; ++m) af[m] = *(const bf16x8*)&As[p][wr+m*16+fr][fq*8];
#pragma unroll
        for (int n = 0; n < 4; ++n) bf[n] = *(const bf16x8*)&Bs[p][wc+n*16+fr][fq*8];
#pragma unroll
        for (int m = 0; m < 4; ++m)
#pragma unroll
            for (int n = 0; n < 4; ++n)
                acc[m][n] = __builtin_amdgcn_mfma_f32_16x16x32_bf16(af[m], bf[n], acc[m][n], 0,0,0);
        __syncthreads();
        p ^= 1;
    }
#pragma unroll
    for (int n = 0; n < 4; ++n) {
        const int dk = n0 + wc + n*16 + fr;
#pragma unroll
        for (int m = 0; m < 4; ++m)
#pragma unroll
            for (int q = 0; q < 4; ++q) {
                const int dv = m0 + wr + m*16 + fq*4 + q;
                Sst[(((size_t)c*B_ + b)*D_ + dv)*D_ + dk] = f2bf(acc[m][n][q]);
            }
    }
}

// ---------------- scanfix: S_c = Lam_c (x) S_{c-1} + dS_c, c = 1..6 ----------------
__global__ __launch_bounds__(256) void scanfix(uint16_t* __restrict__ Sst,
                                               const float* __restrict__ Lam)
{
    const int id = blockIdx.x*256 + threadIdx.x;
    const int g = id & 63, dv = (id>>6) & 511, b = id >> 15;
    const int dk = g*8;
    float s[8];
    {
        uint4 u = *(const uint4*)&Sst[(((size_t)0*B_ + b)*D_ + dv)*D_ + dk];
        s[0]=bflo(u.x); s[1]=bfhi(u.x); s[2]=bflo(u.y); s[3]=bfhi(u.y);
        s[4]=bflo(u.z); s[5]=bfhi(u.z); s[6]=bflo(u.w); s[7]=bfhi(u.w);
    }
    for (int c = 1; c < 7; ++c) {
        const size_t bs = (((size_t)c*B_ + b)*D_ + dv)*D_ + dk;
        uint4 d = *(const uint4*)&Sst[bs];
        float4 l0 = *(const float4*)&Lam[((size_t)b*NSUP + c)*D_ + dk];
        float4 l1 = *(const float4*)&Lam[((size_t)b*NSUP + c)*D_ + dk + 4];
        s[0] = l0.x*s[0] + bflo(d.x); s[1] = l0.y*s[1] + bfhi(d.x);
        s[2] = l0.z*s[2] + bflo(d.y); s[3] = l0.w*s[3] + bfhi(d.y);
        s[4] = l1.x*s[4] + bflo(d.z); s[5] = l1.y*s[5] + bfhi(d.z);
        s[6] = l1.z*s[6] + bflo(d.w); s[7] = l1.w*s[7] + bfhi(d.w);
        uint4 o;
        o.x = pack2bf(s[0],s[1]); o.y = pack2bf(s[2],s[3]);
        o.z = pack2bf(s[4],s[5]); o.w = pack2bf(s[6],s[7]);
        *(uint4*)&Sst[bs] = o;
    }
}

// ---------------- bigout: O = [Q~*Pre | P] @ [S_prev ; V], dbuf, upper-tri masked --
__global__ __launch_bounds__(256) void bigout(const uint16_t* __restrict__ Qt,
                                              const float* __restrict__ Pre,
                                              const uint16_t* __restrict__ Sst,
                                              const uint16_t* __restrict__ Pb,
                                              const uint16_t* __restrict__ VT,
                                              uint16_t* __restrict__ O)
{
    __shared__ __attribute__((aligned(16))) uint16_t SM[2][16384];
    __shared__ float PreL[4*512];
    const int m0 = blockIdx.x*128, n0 = blockIdx.y*128;
    const int b = blockIdx.z>>3, sp = blockIdx.z&7;
    const int tid = threadIdx.x, wave = tid>>6, lane = tid&63;
    const int wr = (wave>>1)*64, wc = (wave&1)*64;
    const int fr = lane&15, fq = lane>>4;
    const int i0 = m0>>5;

#pragma unroll
    for (int z = 0; z < 8; ++z) {
        int idx = z*256 + tid;
        PreL[idx] = Pre[((size_t)b*NSUB + sp*8 + i0 + (idx>>9))*D_ + (idx&511)];
    }
    f32x4 acc[4][4] = {};
    uint4 areg[4];

    auto ISSUE_A = [&](int kt){
        const int k0 = kt*64;
#pragma unroll
        for (int z = 0; z < 4; ++z) {
            int ch = z*256 + tid, r = ch>>3, cc = (ch&7)*8;
            areg[z] = *(const uint4*)&Qt[((size_t)b*S_ + sp*SUPL + m0 + r)*D_ + k0 + cc];
        }
    };
    auto WRITE_A = [&](int kt, int p){
        const int k0 = kt*64;
#pragma unroll
        for (int z = 0; z < 4; ++z) {
            int ch = z*256 + tid, r = ch>>3, cc = (ch&7)*8;
            const float* pr = &PreL[((r>>5)<<9) + k0 + cc];
            uint4 u = areg[z];
            uint4 o;
            o.x = pack2bf(bflo(u.x)*pr[0], bfhi(u.x)*pr[1]);
            o.y = pack2bf(bflo(u.y)*pr[2], bfhi(u.y)*pr[3]);
            o.z = pack2bf(bflo(u.z)*pr[4], bfhi(u.z)*pr[5]);
            o.w = pack2bf(bflo(u.w)*pr[6], bfhi(u.w)*pr[7]);
            *(uint4*)&SM[p][r*64 + (cc ^ ((r&7)<<3))] = o;
        }
    };
    auto STAGE_A_GL = [&](int kt, int p){
        const int u0 = (kt-8)*64;
#pragma unroll
        for (int z = 0; z < 4; ++z) {
            int ch = z*256 + tid, row = ch>>3, kc = ((ch&7) ^ (row&7))*8;
            int ldsb = (z*256 + wave*64)*8;
            gload16(&Pb[((size_t)(b*NSUP + sp)*SUPL + m0 + row)*SUPL + u0 + kc], &SM[p][ldsb]);
        }
    };
    auto STAGE_B = [&](int kt, int p){
        if (kt < 8) {
            const int k0 = kt*64;
#pragma unroll
            for (int z = 0; z < 4; ++z) {
                int ch = z*256 + tid, row = ch>>3, kc = ((ch&7) ^ (row&7))*8;
                int ldsb = (z*256 + wave*64)*8;
                gload16(&Sst[(((size_t)(sp-1)*B_ + b)*D_ + n0 + row)*D_ + k0 + kc], &SM[p][8192+ldsb]);
            }
        } else {
            const int u0 = (kt-8)*64;
#pragma unroll
            for (int z = 0; z < 4; ++z) {
                int ch = z*256 + tid, row = ch>>3, kc = ((ch&7) ^ (row&7))*8;
                int ldsb = (z*256 + wave*64)*8;
                gload16(&VT[((size_t)b*D_ + n0 + row)*S_ + sp*SUPL + u0 + kc], &SM[p][8192+ldsb]);
            }
        }
    };
    auto COMP = [&](int p, int kt){
        const bf16x8 zz = {};
#pragma unroll
        for (int kk = 0; kk < 64; kk += 32) {
            const int sc = (kk + fq*8) ^ ((fr&7)<<3);
            bf16x8 af[4], bfv[4];
#pragma unroll
            for (int m = 0; m < 4; ++m) af[m] = *(const bf16x8*)&SM[p][(wr+m*16+fr)*64 + sc];
            if (kt >= 8) {
                const int jb = ((kt-8)*64 + kk) >> 5;
#pragma unroll
                for (int m = 0; m < 4; ++m) {
                    const int ib = (m0 + wr + m*16) >> 5;
                    if (jb > ib) af[m] = zz;
                }
            }
#pragma unroll
            for (int n = 0; n < 4; ++n) bfv[n] = *(const bf16x8*)&SM[p][8192+(wc+n*16+fr)*64 + sc];
#pragma unroll
            for (int m = 0; m < 4; ++m)
#pragma unroll
                for (int n = 0; n < 4; ++n)
                    acc[m][n] = __builtin_amdgcn_mfma_f32_16x16x32_bf16(af[m], bfv[n], acc[m][n], 0,0,0);
        }
    };

    const int kt0 = (sp == 0) ? 8 : 0;
    // prologue: stage tile kt0 into buf 0
    if (kt0 < 8) {
        ISSUE_A(kt0);
        STAGE_B(kt0, 0);
        __syncthreads();           // PreL visible to all
        WRITE_A(kt0, 0);
    } else {
        STAGE_A_GL(kt0, 0);
        STAGE_B(kt0, 0);
    }
    __syncthreads();

    int p = 0;
    for (int kt = kt0; kt < 12; ++kt) {
        const int nxt = kt + 1;
        if (nxt < 12) {
            if (nxt < 8) ISSUE_A(nxt); else STAGE_A_GL(nxt, p^1);
            STAGE_B(nxt, p^1);
        }
        COMP(p, kt);
        if (nxt < 12 && nxt < 8) WRITE_A(nxt, p^1);
        __syncthreads();
        p ^= 1;
    }

    uint16_t (*L)[136] = (uint16_t(*)[136])&SM[0][0];
#pragma unroll
    for (int n = 0; n < 4; ++n) {
        const int cl = wc + n*16 + fr;
#pragma unroll
        for (int m = 0; m < 4; ++m)
#pragma unroll
            for (int q = 0; q < 4; ++q)
                L[wr + m*16 + fq*4 + q][cl] = f2bf(acc[m][n][q]);
    }
    __syncthreads();
#pragma unroll
    for (int it = 0; it < 8; ++it) {
        const int r = it*16 + (tid>>4), c8 = (tid&15)*8;
        *(uint4*)&O[((size_t)b*S_ + sp*SUPL + m0 + r)*D_ + n0 + c8] = *(uint4*)&L[r][c8];
    }
}

// ---------------- launch ----------------------------------------------------------
extern "C" void kernel_launch(void* const* d_in, const int* in_sizes, int n_in,
                              void* d_out, int out_size, void* d_ws, size_t ws_size,
                              hipStream_t stream)
{
    (void)in_sizes; (void)n_in; (void)out_size; (void)ws_size;
    const float* x  = (const float*)d_in[0];
    const float* Wq = (const float*)d_in[1];  const float* bq = (const float*)d_in[2];
    const float* Wk = (const float*)d_in[3];  const float* bk = (const float*)d_in[4];
    const float* Wv = (const float*)d_in[5];  const float* bv = (const float*)d_in[6];
    const float* Wg = (const float*)d_in[7];  const float* bg = (const float*)d_in[8];
    const float* Wo = (const float*)d_in[9];  const float* bo = (const float*)d_in[10];

    char* w = (char*)d_ws;
    const size_t MD2 = (size_t)M_*D_*2;
    uint16_t* Wb = (uint16_t*)w;                       w += 5*(size_t)D_*D_*2;
    uint16_t* xb = (uint16_t*)w;                       w += MD2;                  // x, later O
    uint16_t* Qb = (uint16_t*)w;                       w += MD2;                  // Q -> Q~
    uint16_t* Kb = (uint16_t*)w;                       w += MD2;                  // K -> K^ rows
    uint16_t* KT = (uint16_t*)w;                       w += MD2;                  // K^T [b][dk][t]
    uint16_t* VT = (uint16_t*)w;                       w += MD2;                  // V^T [b][dv][t]
    uint16_t* Gb = (uint16_t*)w;                       w += MD2;                  // gamma bf16
    uint16_t* Sst = (uint16_t*)w;                      w += (size_t)7*B_*D_*D_*2;
    uint16_t* Pb  = (uint16_t*)w;                      w += (size_t)B_*NSUP*SUPL*SUPL*2;
    float*    T   = (float*)w;                         w += (size_t)B_*NSUB*D_*4;
    float*    Pre = (float*)w;                         w += (size_t)B_*NSUB*D_*4;
    float*    Suf = (float*)w;                         w += (size_t)B_*NSUB*D_*4;
    float*    Lam = (float*)w;                         w += (size_t)B_*NSUP*D_*4;

    conv_x<<<dim3(M_*D_/2048), 256, 0, stream>>>(x, xb);
    conv_w<<<dim3(D_*D_/2048, 5), 256, 0, stream>>>(Wq, Wk, Wv, Wg, Wo, Wb);

    proj4<<<dim3(M_/128, 16), 256, 0, stream>>>(xb, Wb, bq, bk, bv, bg, Qb, Kb, VT, Gb);

    prep<<<dim3(NSUB, B_), 256, 0, stream>>>(Gb, Qb, Kb, KT, T);
    tables<<<dim3(NSUP, B_), 512, 0, stream>>>(T, Pre, Suf, Lam);

    pairsA<<<dim3(36, NSUP, B_), 256, 0, stream>>>(Qb, Kb, T, Pb);
    dsgemm<<<dim3(16, 7, B_), 256, 0, stream>>>(VT, KT, Suf, Sst);
    scanfix<<<dim3(1024), 256, 0, stream>>>(Sst, Lam);

    bigout<<<dim3(2, 4, B_*NSUP), 256, 0, stream>>>(Qb, Pre, Sst, Pb, VT, xb);

    mfma_gemm<<<dim3(M_/128, D_/128), 256, 0, stream>>>(xb, Wb + 4*(size_t)D_*D_, bo, (float*)d_out);
}

// Round 8
// 200.071 us; speedup vs baseline: 12.2106x; 1.0093x over previous
//
#include <hip/hip_runtime.h>
#include <hip/hip_bf16.h>
#include <stdint.h>

// SRALayer R8: chunked GLA. R7 + counted-vmcnt pipeline (T4) in proj4/outproj:
// raw s_barrier + s_waitcnt vmcnt(8) keeps next-tile global_load_lds in flight
// across the barrier (removes the __syncthreads vmcnt(0) drain = the 2-phase stall),
// + XCD-aware grid decode so all n-blocks of an m-tile share an XCD (A in L2).

#define B_ 8
#define S_ 2048
#define D_ 512
#define M_ (B_ * S_)
#define NSUB 64
#define SUBL 32
#define NSUP 8
#define SUPL 256

typedef __bf16 bf16x8 __attribute__((ext_vector_type(8)));
typedef float f32x4 __attribute__((ext_vector_type(4)));

__device__ __forceinline__ float bflo(uint32_t u){ return __uint_as_float(u<<16); }
__device__ __forceinline__ float bfhi(uint32_t u){ return __uint_as_float(u&0xffff0000u); }
__device__ __forceinline__ uint16_t f2bf(float f){
    uint32_t u = __float_as_uint(f);
    return (uint16_t)((u + 0x7fffu + ((u>>16)&1u)) >> 16);
}
__device__ __forceinline__ uint32_t pack2bf(float a, float b){
    return (uint32_t)f2bf(a) | ((uint32_t)f2bf(b)<<16);
}
__device__ __forceinline__ void gload16(const void* g, void* l){
    __builtin_amdgcn_global_load_lds(
        (const __attribute__((address_space(1))) uint32_t*)g,
        (__attribute__((address_space(3))) uint32_t*)l, 16, 0, 0);
}

// ---------------- fp32 -> bf16 converters -----------------------------------------
__global__ __launch_bounds__(256) void conv_x(const float* __restrict__ in,
                                              uint16_t* __restrict__ out){
    const size_t i = ((size_t)blockIdx.x*256 + threadIdx.x)*8;
    float4 a = *(const float4*)&in[i];
    float4 b = *(const float4*)&in[i+4];
    uint4 o; o.x=pack2bf(a.x,a.y); o.y=pack2bf(a.z,a.w); o.z=pack2bf(b.x,b.y); o.w=pack2bf(b.z,b.w);
    *(uint4*)&out[i] = o;
}
__global__ __launch_bounds__(256) void conv_w(const float* w0, const float* w1, const float* w2,
                                              const float* w3, const float* w4,
                                              uint16_t* __restrict__ out){
    const float* ws[5] = {w0,w1,w2,w3,w4};
    const float* in = ws[blockIdx.y];
    uint16_t* o = out + (size_t)blockIdx.y*D_*D_;
    const size_t i = ((size_t)blockIdx.x*256 + threadIdx.x)*8;
    float4 a = *(const float4*)&in[i];
    float4 b = *(const float4*)&in[i+4];
    uint4 u; u.x=pack2bf(a.x,a.y); u.y=pack2bf(a.z,a.w); u.z=pack2bf(b.x,b.y); u.w=pack2bf(b.z,b.w);
    *(uint4*)&o[i] = u;
}

// ---------------- proj4: fused Q|K|V|G GEMM, counted-vmcnt dbuf pipeline -----------
// 1-D grid 2048, XCD decode. sect: 0=Q 1=K 2=V^T(swapped mfma) 3=G(sigmoid), bf16 out.
__global__ __launch_bounds__(256) void proj4(const uint16_t* __restrict__ A,
                                             const uint16_t* __restrict__ Wb,
                                             const float* __restrict__ bq_,
                                             const float* __restrict__ bk_,
                                             const float* __restrict__ bv_,
                                             const float* __restrict__ bg_,
                                             uint16_t* __restrict__ Qb,
                                             uint16_t* __restrict__ Kb,
                                             uint16_t* __restrict__ VT,
                                             uint16_t* __restrict__ Gb)
{
    __shared__ __attribute__((aligned(16))) uint16_t SM[2][16384];
    const int id = blockIdx.x;
    const int bx = (id & 7) + 8*((id >> 3) & 15);   // 16 m-tiles per XCD
    const int by = id >> 7;                          // all 16 n-blocks of bx on same XCD
    const int tid = threadIdx.x, wave = tid>>6, lane = tid&63;
    const int m0 = bx*128, n0 = by*128;
    const int wr = (wave>>1)*64, wc = (wave&1)*64;
    const int fr = lane&15, fq = lane>>4;
    const int sect = by >> 2;
    const int n0c = n0 & 511;
    f32x4 acc[4][4] = {};

    auto STAGE = [&](int kt, int p){                 // exactly 8 VMEM ops / thread
        const int k0 = kt*64;
#pragma unroll
        for (int i = 0; i < 4; ++i) {
            const int c = i*256 + tid;
            const int row = c>>3, kc = ((c&7) ^ (row&7))*8;
            const int ldsb = (i*256 + wave*64)*8;
            gload16(&A [(size_t)(m0+row)*D_ + k0 + kc], &SM[p][ldsb]);
            gload16(&Wb[(size_t)(n0+row)*D_ + k0 + kc], &SM[p][8192+ldsb]);
        }
    };
    auto COMP = [&](int p){
#pragma unroll
        for (int kk = 0; kk < 64; kk += 32) {
            const int sc = (kk + fq*8) ^ ((fr&7)<<3);
            bf16x8 af[4], bfv[4];
#pragma unroll
            for (int m = 0; m < 4; ++m) af[m]  = *(const bf16x8*)&SM[p][(wr+m*16+fr)*64 + sc];
#pragma unroll
            for (int n = 0; n < 4; ++n) bfv[n] = *(const bf16x8*)&SM[p][8192+(wc+n*16+fr)*64 + sc];
            if (sect == 2) {
#pragma unroll
                for (int m = 0; m < 4; ++m)
#pragma unroll
                    for (int n = 0; n < 4; ++n)
                        acc[m][n] = __builtin_amdgcn_mfma_f32_16x16x32_bf16(bfv[n], af[m], acc[m][n], 0,0,0);
            } else {
#pragma unroll
                for (int m = 0; m < 4; ++m)
#pragma unroll
                    for (int n = 0; n < 4; ++n)
                        acc[m][n] = __builtin_amdgcn_mfma_f32_16x16x32_bf16(af[m], bfv[n], acc[m][n], 0,0,0);
            }
        }
    };

    STAGE(0, 0);
    __builtin_amdgcn_sched_barrier(0);
    asm volatile("s_waitcnt vmcnt(0)" ::: "memory");
    __builtin_amdgcn_s_barrier();
    __builtin_amdgcn_sched_barrier(0);
    int p = 0;
#pragma unroll
    for (int kt = 0; kt < 8; ++kt) {
        if (kt < 7) STAGE(kt+1, p^1);
        __builtin_amdgcn_sched_barrier(0);
        if (kt > 0) {                                // buffer p's loads issued last iter
            if (kt < 7) asm volatile("s_waitcnt vmcnt(8)" ::: "memory");
            else        asm volatile("s_waitcnt vmcnt(0)" ::: "memory");
            __builtin_amdgcn_s_barrier();
            __builtin_amdgcn_sched_barrier(0);
        }
        COMP(p);
        __builtin_amdgcn_sched_barrier(0);
        __builtin_amdgcn_s_barrier();                // readers of p done before re-stage
        __builtin_amdgcn_sched_barrier(0);
        p ^= 1;
    }

    uint16_t (*L)[136] = (uint16_t(*)[136])&SM[0][0];
    const float* bias = (sect==0) ? bq_ : (sect==1) ? bk_ : (sect==2) ? bv_ : bg_;
    if (sect == 2) {                   // acc holds V^T[dv][t]
#pragma unroll
        for (int n = 0; n < 4; ++n)
#pragma unroll
            for (int q = 0; q < 4; ++q) {
                const int dvl = wc + n*16 + fq*4 + q;
                const float bvv = bias[n0c + dvl];
#pragma unroll
                for (int m = 0; m < 4; ++m)
                    L[dvl][wr + m*16 + fr] = f2bf(acc[m][n][q] + bvv);
            }
    } else {
#pragma unroll
        for (int n = 0; n < 4; ++n) {
            const int cl = wc + n*16 + fr;
            const float bvv = bias[n0c + cl];
#pragma unroll
            for (int m = 0; m < 4; ++m)
#pragma unroll
                for (int q = 0; q < 4; ++q) {
                    float c = acc[m][n][q] + bvv;
                    if (sect == 3) c = 1.f/(1.f + expf(-c));
                    L[wr + m*16 + fq*4 + q][cl] = f2bf(c);
                }
        }
    }
    __syncthreads();
    const int bb = m0 >> 11, t0 = m0 & 2047;
#pragma unroll
    for (int it = 0; it < 8; ++it) {
        const int r = it*16 + (tid>>4), c8 = (tid&15)*8;
        uint4 v = *(uint4*)&L[r][c8];
        if (sect == 0)      *(uint4*)&Qb[(size_t)(m0+r)*D_ + n0c + c8] = v;
        else if (sect == 1) *(uint4*)&Kb[(size_t)(m0+r)*D_ + n0c + c8] = v;
        else if (sect == 3) *(uint4*)&Gb[(size_t)(m0+r)*D_ + n0c + c8] = v;
        else                *(uint4*)&VT[((size_t)bb*D_ + n0c + r)*S_ + t0 + c8] = v;
    }
}

// ---------------- mfma_gemm: output projection, counted-vmcnt pipeline -------------
__global__ __launch_bounds__(256) void mfma_gemm(const uint16_t* __restrict__ A,
                                                 const uint16_t* __restrict__ Wt,
                                                 const float* __restrict__ bias,
                                                 float* __restrict__ out)
{
    __shared__ __attribute__((aligned(16))) uint16_t SM[2][16384];
    const int id = blockIdx.x;
    const int bx = (id & 7) + 8*((id >> 3) & 15);
    const int by = id >> 7;                          // 0..3
    const int tid = threadIdx.x, wave = tid>>6, lane = tid&63;
    const int m0 = bx*128, n0 = by*128;
    const int wr = (wave>>1)*64, wc = (wave&1)*64;
    const int fr = lane&15, fq = lane>>4;
    f32x4 acc[4][4] = {};

    auto STAGE = [&](int kt, int p){
        const int k0 = kt*64;
#pragma unroll
        for (int i = 0; i < 4; ++i) {
            const int c = i*256 + tid;
            const int row = c>>3, kc = ((c&7) ^ (row&7))*8;
            const int ldsb = (i*256 + wave*64)*8;
            gload16(&A [(size_t)(m0+row)*D_ + k0 + kc], &SM[p][ldsb]);
            gload16(&Wt[(size_t)(n0+row)*D_ + k0 + kc], &SM[p][8192+ldsb]);
        }
    };
    auto COMP = [&](int p){
#pragma unroll
        for (int kk = 0; kk < 64; kk += 32) {
            const int sc = (kk + fq*8) ^ ((fr&7)<<3);
            bf16x8 af[4], bfv[4];
#pragma unroll
            for (int m = 0; m < 4; ++m) af[m]  = *(const bf16x8*)&SM[p][(wr+m*16+fr)*64 + sc];
#pragma unroll
            for (int n = 0; n < 4; ++n) bfv[n] = *(const bf16x8*)&SM[p][8192+(wc+n*16+fr)*64 + sc];
#pragma unroll
            for (int m = 0; m < 4; ++m)
#pragma unroll
                for (int n = 0; n < 4; ++n)
                    acc[m][n] = __builtin_amdgcn_mfma_f32_16x16x32_bf16(af[m], bfv[n], acc[m][n], 0,0,0);
        }
    };

    STAGE(0, 0);
    __builtin_amdgcn_sched_barrier(0);
    asm volatile("s_waitcnt vmcnt(0)" ::: "memory");
    __builtin_amdgcn_s_barrier();
    __builtin_amdgcn_sched_barrier(0);
    int p = 0;
#pragma unroll
    for (int kt = 0; kt < 8; ++kt) {
        if (kt < 7) STAGE(kt+1, p^1);
        __builtin_amdgcn_sched_barrier(0);
        if (kt > 0) {
            if (kt < 7) asm volatile("s_waitcnt vmcnt(8)" ::: "memory");
            else        asm volatile("s_waitcnt vmcnt(0)" ::: "memory");
            __builtin_amdgcn_s_barrier();
            __builtin_amdgcn_sched_barrier(0);
        }
        COMP(p);
        __builtin_amdgcn_sched_barrier(0);
        __builtin_amdgcn_s_barrier();
        __builtin_amdgcn_sched_barrier(0);
        p ^= 1;
    }

    float (*L32)[68] = (float(*)[68])&SM[0][0];
#pragma unroll
    for (int h = 0; h < 2; ++h) {
        if (wc == h*64) {
#pragma unroll
            for (int n = 0; n < 4; ++n) {
                const float bvv = bias[n0 + wc + n*16 + fr];
#pragma unroll
                for (int m = 0; m < 4; ++m)
#pragma unroll
                    for (int q = 0; q < 4; ++q)
                        L32[wr + m*16 + fq*4 + q][n*16 + fr] = acc[m][n][q] + bvv;
            }
        }
        __syncthreads();
#pragma unroll
        for (int it = 0; it < 8; ++it) {
            const int r = it*16 + (tid>>4), c4 = (tid&15)*4;
            *(uint4*)&out[(size_t)(m0+r)*D_ + n0 + h*64 + c4] = *(uint4*)&L32[r][c4];
        }
        __syncthreads();
    }
}

// ---------------- prep: LDS-free, bf16 gamma in ------------------------------------
__global__ __launch_bounds__(256) void prep(const uint16_t* __restrict__ Gb,
                                            uint16_t* __restrict__ Qb,
                                            uint16_t* __restrict__ Kb,
                                            uint16_t* __restrict__ KT,
                                            float* __restrict__ T)
{
    const int sub = blockIdx.x, b = blockIdx.y;
    const int tid = threadIdx.x;
    const int dk0 = tid*2;
    const size_t rowbase = ((size_t)b*S_ + sub*SUBL)*D_;
    const uint16_t* gp = Gb + rowbase + dk0;
    uint16_t*       qp = Qb + rowbase + dk0;
    uint16_t*       kp = Kb + rowbase + dk0;

    float mu0 = 1.f, mu1 = 1.f;
    uint32_t ksave[SUBL];
#pragma unroll
    for (int t = 0; t < SUBL; ++t) {
        const uint32_t g2 = *(const uint32_t*)(gp + (size_t)t*D_);
        const uint32_t qu = *(const uint32_t*)(qp + (size_t)t*D_);
        const uint32_t ku = *(const uint32_t*)(kp + (size_t)t*D_);
        mu0 = fmaxf(mu0*bflo(g2), 1e-30f);
        mu1 = fmaxf(mu1*bfhi(g2), 1e-30f);
        const float r0 = __builtin_amdgcn_rcpf(mu0);
        const float r1 = __builtin_amdgcn_rcpf(mu1);
        *(uint32_t*)(qp + (size_t)t*D_) = pack2bf(bflo(qu)*mu0, bfhi(qu)*mu1);
        const uint32_t kw = pack2bf(bflo(ku)*r0, bfhi(ku)*r1);
        *(uint32_t*)(kp + (size_t)t*D_) = kw;
        ksave[t] = kw;
    }
    T[((size_t)b*NSUB + sub)*D_ + dk0]     = mu0;
    T[((size_t)b*NSUB + sub)*D_ + dk0 + 1] = mu1;

    uint16_t* d0 = &KT[((size_t)b*D_ + dk0)*S_ + sub*SUBL];
    uint16_t* d1 = d0 + S_;
#pragma unroll
    for (int q4 = 0; q4 < 4; ++q4) {
        uint4 lo, hi;
        lo.x = (ksave[q4*8+0]&0xffffu) | (ksave[q4*8+1]<<16);
        lo.y = (ksave[q4*8+2]&0xffffu) | (ksave[q4*8+3]<<16);
        lo.z = (ksave[q4*8+4]&0xffffu) | (ksave[q4*8+5]<<16);
        lo.w = (ksave[q4*8+6]&0xffffu) | (ksave[q4*8+7]<<16);
        hi.x = (ksave[q4*8+0]>>16) | (ksave[q4*8+1]&0xffff0000u);
        hi.y = (ksave[q4*8+2]>>16) | (ksave[q4*8+3]&0xffff0000u);
        hi.z = (ksave[q4*8+4]>>16) | (ksave[q4*8+5]&0xffff0000u);
        hi.w = (ksave[q4*8+6]>>16) | (ksave[q4*8+7]&0xffff0000u);
        *(uint4*)&d0[q4*8] = lo;
        *(uint4*)&d1[q4*8] = hi;
    }
}

// ---------------- tables: Pre / Suf / Lam from T, grid (sp,b) ----------------------
__global__ __launch_bounds__(512) void tables(const float* __restrict__ T,
                                              float* __restrict__ Pre,
                                              float* __restrict__ Suf,
                                              float* __restrict__ Lam)
{
    const int sp = blockIdx.x, b = blockIdx.y, dk = threadIdx.x;
    float run = 1.f;
#pragma unroll
    for (int m = 0; m < 8; ++m) {
        Pre[((size_t)b*NSUB + sp*8+m)*D_ + dk] = run;
        run *= T[((size_t)b*NSUB + sp*8+m)*D_ + dk];
    }
    Lam[((size_t)b*NSUP + sp)*D_ + dk] = run;
    float rs = 1.f;
#pragma unroll
    for (int m = 7; m >= 0; --m) {
        rs *= T[((size_t)b*NSUB + sp*8+m)*D_ + dk];
        Suf[((size_t)b*NSUB + sp*8+m)*D_ + dk] = rs;
    }
}

// ---------------- pairsA: flat (i,j) grid, P_ij = Q~_i @ (D_ij * K^_j)^T -----------
__device__ __forceinline__ int swz(int r, int c){ return r*D_ + (c ^ ((r&7)<<3)); }

__global__ __launch_bounds__(256) void pairsA(const uint16_t* __restrict__ Qt,
                                              const uint16_t* __restrict__ Kh,
                                              const float* __restrict__ T,
                                              uint16_t* __restrict__ P)
{
    __shared__ __attribute__((aligned(16))) uint16_t qs[SUBL*D_];
    __shared__ __attribute__((aligned(16))) uint16_t ks[SUBL*D_];
    __shared__ float D_lds[D_];
    const int idx = blockIdx.x, sp = blockIdx.y, b = blockIdx.z;
    int i = 0;
    while (((i+1)*(i+2))/2 <= idx) ++i;
    const int j = idx - (i*(i+1))/2;

    const int tid = threadIdx.x, wave = tid>>6, lane = tid&63;
    const int fr = lane&15, fq = lane>>4;
    const int mq = wave>>1, nq = wave&1;
    const size_t qrow = (size_t)b*S_ + sp*SUPL + i*SUBL;
    const size_t krow = (size_t)b*S_ + sp*SUPL + j*SUBL;
    const size_t prow = ((size_t)(b*NSUP + sp)*SUPL + i*SUBL);

#pragma unroll
    for (int z = 0; z < 8; ++z) {
        int ch = z*256 + tid, r = ch>>6, c = (ch&63)*8;
        *(uint4*)&qs[swz(r,c)] = *(const uint4*)&Qt[(qrow + r)*D_ + c];
    }
    const int dkA = tid*2, dkB = tid*2+1;
    float d0 = 1.f, d1 = 1.f;
    for (int m = j; m < i; ++m) {
        d0 *= T[((size_t)b*NSUB + sp*8 + m)*D_ + dkA];
        d1 *= T[((size_t)b*NSUB + sp*8 + m)*D_ + dkB];
    }
    D_lds[dkA] = d0; D_lds[dkB] = d1;
    __syncthreads();

#pragma unroll
    for (int z = 0; z < 8; ++z) {
        int ch = z*256 + tid, r = ch>>6, c = (ch&63)*8;
        uint4 u = *(const uint4*)&Kh[(krow + r)*D_ + c];
        uint4 o;
        o.x = pack2bf(bflo(u.x)*D_lds[c+0], bfhi(u.x)*D_lds[c+1]);
        o.y = pack2bf(bflo(u.y)*D_lds[c+2], bfhi(u.y)*D_lds[c+3]);
        o.z = pack2bf(bflo(u.z)*D_lds[c+4], bfhi(u.z)*D_lds[c+5]);
        o.w = pack2bf(bflo(u.w)*D_lds[c+6], bfhi(u.w)*D_lds[c+7]);
        *(uint4*)&ks[swz(r,c)] = o;
    }
    __syncthreads();

    f32x4 a0 = {}, a1 = {}, a2 = {}, a3 = {};
#pragma unroll
    for (int kk = 0; kk < 512; kk += 128) {
        bf16x8 q0 = *(const bf16x8*)&qs[swz(mq*16+fr, kk      + fq*8)];
        bf16x8 k0 = *(const bf16x8*)&ks[swz(nq*16+fr, kk      + fq*8)];
        bf16x8 q1 = *(const bf16x8*)&qs[swz(mq*16+fr, kk + 32 + fq*8)];
        bf16x8 k1 = *(const bf16x8*)&ks[swz(nq*16+fr, kk + 32 + fq*8)];
        bf16x8 q2 = *(const bf16x8*)&qs[swz(mq*16+fr, kk + 64 + fq*8)];
        bf16x8 k2 = *(const bf16x8*)&ks[swz(nq*16+fr, kk + 64 + fq*8)];
        bf16x8 q3 = *(const bf16x8*)&qs[swz(mq*16+fr, kk + 96 + fq*8)];
        bf16x8 k3 = *(const bf16x8*)&ks[swz(nq*16+fr, kk + 96 + fq*8)];
        a0 = __builtin_amdgcn_mfma_f32_16x16x32_bf16(q0, k0, a0, 0,0,0);
        a1 = __builtin_amdgcn_mfma_f32_16x16x32_bf16(q1, k1, a1, 0,0,0);
        a2 = __builtin_amdgcn_mfma_f32_16x16x32_bf16(q2, k2, a2, 0,0,0);
        a3 = __builtin_amdgcn_mfma_f32_16x16x32_bf16(q3, k3, a3, 0,0,0);
    }
    const int ul = nq*16 + fr;
#pragma unroll
    for (int q_ = 0; q_ < 4; ++q_) {
        const int tl = mq*16 + fq*4 + q_;
        float v = a0[q_] + a1[q_] + a2[q_] + a3[q_];
        if (i == j && ul > tl) v = 0.f;
        P[(prow + tl)*SUPL + j*SUBL + ul] = f2bf(v);
    }
}

// ---------------- dsgemm: dbuf 2-phase, dS_c = sum_u (Suf*k^_u) v_u^T --------------
__global__ __launch_bounds__(256) void dsgemm(const uint16_t* __restrict__ VT,
                                              const uint16_t* __restrict__ KT,
                                              const float* __restrict__ Suf,
                                              uint16_t* __restrict__ Sst)
{
    __shared__ __attribute__((aligned(16))) uint16_t As[2][128][40];
    __shared__ __attribute__((aligned(16))) uint16_t Bs[2][128][40];
    const int tile = blockIdx.x, c = blockIdx.y, b = blockIdx.z;
    const int m0 = (tile&3)*128, n0 = (tile>>2)*128;
    const int tid = threadIdx.x, wave = tid>>6, lane = tid&63;
    const int wr = (wave>>1)*64, wc = (wave&1)*64;
    const int fr = lane&15, fq = lane>>4;
    f32x4 acc[4][4] = {};

    auto STAGE = [&](int j, int p){
        const int t0 = c*SUPL + j*SUBL;
#pragma unroll
        for (int ch = tid; ch < 512; ch += 256) {
            int row = ch>>2, tc = (ch&3)*8;
            *(uint4*)&As[p][row][tc] = *(const uint4*)&VT[((size_t)b*D_ + m0+row)*S_ + t0 + tc];
        }
#pragma unroll
        for (int ch = tid; ch < 512; ch += 256) {
            int row = ch>>2, tc = (ch&3)*8;
            uint4 u = *(const uint4*)&KT[((size_t)b*D_ + n0+row)*S_ + t0 + tc];
            float sf = Suf[((size_t)b*NSUB + c*8 + j)*D_ + n0 + row];
            uint4 o;
            o.x = pack2bf(bflo(u.x)*sf, bfhi(u.x)*sf);
            o.y = pack2bf(bflo(u.y)*sf, bfhi(u.y)*sf);
            o.z = pack2bf(bflo(u.z)*sf, bfhi(u.z)*sf);
            o.w = pack2bf(bflo(u.w)*sf, bfhi(u.w)*sf);
            *(uint4*)&Bs[p][row][tc] = o;
        }
    };

    STAGE(0, 0);
    __syncthreads();
    int p = 0;
    for (int j = 0; j < 8; ++j) {
        if (j < 7) STAGE(j+1, p^1);
        bf16x8 af[4], bf[4];
#pragma unroll
        for (int m = 0; m < 4; ++m) af[m] = *(const bf16x8*)&As[p][wr+m*16+fr][fq*8];
#pragma unroll
        for (int n = 0; n < 4; ++n) bf[n] = *(const bf16x8*)&Bs[p][wc+n*16+fr][fq*8];
#pragma unroll
        for (int m = 0; m < 4; ++m)
#pragma unroll
            for (int n = 0; n < 4; ++n)
                acc[m][n] = __builtin_amdgcn_mfma_f32_16x16x32_bf16(af[m], bf[n], acc[m][n], 0,0,0);
        __syncthreads();
        p ^= 1;
    }
#pragma unroll
    for (int n = 0; n < 4; ++n) {
        const int dk = n0 + wc + n*16 + fr;
#pragma unroll
        for (int m = 0; m < 4; ++m)
#pragma unroll
            for (int q = 0; q < 4; ++q) {
                const int dv = m0 + wr + m*16 + fq*4 + q;
                Sst[(((size_t)c*B_ + b)*D_ + dv)*D_ + dk] = f2bf(acc[m][n][q]);
            }
    }
}

// ---------------- scanfix: S_c = Lam_c (x) S_{c-1} + dS_c, c = 1..6 ----------------
__global__ __launch_bounds__(256) void scanfix(uint16_t* __restrict__ Sst,
                                               const float* __restrict__ Lam)
{
    const int id = blockIdx.x*256 + threadIdx.x;
    const int g = id & 63, dv = (id>>6) & 511, b = id >> 15;
    const int dk = g*8;
    float s[8];
    {
        uint4 u = *(const uint4*)&Sst[(((size_t)0*B_ + b)*D_ + dv)*D_ + dk];
        s[0]=bflo(u.x); s[1]=bfhi(u.x); s[2]=bflo(u.y); s[3]=bfhi(u.y);
        s[4]=bflo(u.z); s[5]=bfhi(u.z); s[6]=bflo(u.w); s[7]=bfhi(u.w);
    }
    for (int c = 1; c < 7; ++c) {
        const size_t bs = (((size_t)c*B_ + b)*D_ + dv)*D_ + dk;
        uint4 d = *(const uint4*)&Sst[bs];
        float4 l0 = *(const float4*)&Lam[((size_t)b*NSUP + c)*D_ + dk];
        float4 l1 = *(const float4*)&Lam[((size_t)b*NSUP + c)*D_ + dk + 4];
        s[0] = l0.x*s[0] + bflo(d.x); s[1] = l0.y*s[1] + bfhi(d.x);
        s[2] = l0.z*s[2] + bflo(d.y); s[3] = l0.w*s[3] + bfhi(d.y);
        s[4] = l1.x*s[4] + bflo(d.z); s[5] = l1.y*s[5] + bfhi(d.z);
        s[6] = l1.z*s[6] + bflo(d.w); s[7] = l1.w*s[7] + bfhi(d.w);
        uint4 o;
        o.x = pack2bf(s[0],s[1]); o.y = pack2bf(s[2],s[3]);
        o.z = pack2bf(s[4],s[5]); o.w = pack2bf(s[6],s[7]);
        *(uint4*)&Sst[bs] = o;
    }
}

// ---------------- bigout: O = [Q~*Pre | P] @ [S_prev ; V], dbuf, upper-tri masked --
__global__ __launch_bounds__(256) void bigout(const uint16_t* __restrict__ Qt,
                                              const float* __restrict__ Pre,
                                              const uint16_t* __restrict__ Sst,
                                              const uint16_t* __restrict__ Pb,
                                              const uint16_t* __restrict__ VT,
                                              uint16_t* __restrict__ O)
{
    __shared__ __attribute__((aligned(16))) uint16_t SM[2][16384];
    __shared__ float PreL[4*512];
    const int m0 = blockIdx.x*128, n0 = blockIdx.y*128;
    const int b = blockIdx.z>>3, sp = blockIdx.z&7;
    const int tid = threadIdx.x, wave = tid>>6, lane = tid&63;
    const int wr = (wave>>1)*64, wc = (wave&1)*64;
    const int fr = lane&15, fq = lane>>4;
    const int i0 = m0>>5;

#pragma unroll
    for (int z = 0; z < 8; ++z) {
        int idx = z*256 + tid;
        PreL[idx] = Pre[((size_t)b*NSUB + sp*8 + i0 + (idx>>9))*D_ + (idx&511)];
    }
    f32x4 acc[4][4] = {};
    uint4 areg[4];

    auto ISSUE_A = [&](int kt){
        const int k0 = kt*64;
#pragma unroll
        for (int z = 0; z < 4; ++z) {
            int ch = z*256 + tid, r = ch>>3, cc = (ch&7)*8;
            areg[z] = *(const uint4*)&Qt[((size_t)b*S_ + sp*SUPL + m0 + r)*D_ + k0 + cc];
        }
    };
    auto WRITE_A = [&](int kt, int p){
        const int k0 = kt*64;
#pragma unroll
        for (int z = 0; z < 4; ++z) {
            int ch = z*256 + tid, r = ch>>3, cc = (ch&7)*8;
            const float* pr = &PreL[((r>>5)<<9) + k0 + cc];
            uint4 u = areg[z];
            uint4 o;
            o.x = pack2bf(bflo(u.x)*pr[0], bfhi(u.x)*pr[1]);
            o.y = pack2bf(bflo(u.y)*pr[2], bfhi(u.y)*pr[3]);
            o.z = pack2bf(bflo(u.z)*pr[4], bfhi(u.z)*pr[5]);
            o.w = pack2bf(bflo(u.w)*pr[6], bfhi(u.w)*pr[7]);
            *(uint4*)&SM[p][r*64 + (cc ^ ((r&7)<<3))] = o;
        }
    };
    auto STAGE_A_GL = [&](int kt, int p){
        const int u0 = (kt-8)*64;
#pragma unroll
        for (int z = 0; z < 4; ++z) {
            int ch = z*256 + tid, row = ch>>3, kc = ((ch&7) ^ (row&7))*8;
            int ldsb = (z*256 + wave*64)*8;
            gload16(&Pb[((size_t)(b*NSUP + sp)*SUPL + m0 + row)*SUPL + u0 + kc], &SM[p][ldsb]);
        }
    };
    auto STAGE_B = [&](int kt, int p){
        if (kt < 8) {
            const int k0 = kt*64;
#pragma unroll
            for (int z = 0; z < 4; ++z) {
                int ch = z*256 + tid, row = ch>>3, kc = ((ch&7) ^ (row&7))*8;
                int ldsb = (z*256 + wave*64)*8;
                gload16(&Sst[(((size_t)(sp-1)*B_ + b)*D_ + n0 + row)*D_ + k0 + kc], &SM[p][8192+ldsb]);
            }
        } else {
            const int u0 = (kt-8)*64;
#pragma unroll
            for (int z = 0; z < 4; ++z) {
                int ch = z*256 + tid, row = ch>>3, kc = ((ch&7) ^ (row&7))*8;
                int ldsb = (z*256 + wave*64)*8;
                gload16(&VT[((size_t)b*D_ + n0 + row)*S_ + sp*SUPL + u0 + kc], &SM[p][8192+ldsb]);
            }
        }
    };
    auto COMP = [&](int p, int kt){
        const bf16x8 zz = {};
#pragma unroll
        for (int kk = 0; kk < 64; kk += 32) {
            const int sc = (kk + fq*8) ^ ((fr&7)<<3);
            bf16x8 af[4], bfv[4];
#pragma unroll
            for (int m = 0; m < 4; ++m) af[m] = *(const bf16x8*)&SM[p][(wr+m*16+fr)*64 + sc];
            if (kt >= 8) {
                const int jb = ((kt-8)*64 + kk) >> 5;
#pragma unroll
                for (int m = 0; m < 4; ++m) {
                    const int ib = (m0 + wr + m*16) >> 5;
                    if (jb > ib) af[m] = zz;
                }
            }
#pragma unroll
            for (int n = 0; n < 4; ++n) bfv[n] = *(const bf16x8*)&SM[p][8192+(wc+n*16+fr)*64 + sc];
#pragma unroll
            for (int m = 0; m < 4; ++m)
#pragma unroll
                for (int n = 0; n < 4; ++n)
                    acc[m][n] = __builtin_amdgcn_mfma_f32_16x16x32_bf16(af[m], bfv[n], acc[m][n], 0,0,0);
        }
    };

    const int kt0 = (sp == 0) ? 8 : 0;
    if (kt0 < 8) {
        ISSUE_A(kt0);
        STAGE_B(kt0, 0);
        __syncthreads();
        WRITE_A(kt0, 0);
    } else {
        STAGE_A_GL(kt0, 0);
        STAGE_B(kt0, 0);
    }
    __syncthreads();

    int p = 0;
    for (int kt = kt0; kt < 12; ++kt) {
        const int nxt = kt + 1;
        if (nxt < 12) {
            if (nxt < 8) ISSUE_A(nxt); else STAGE_A_GL(nxt, p^1);
            STAGE_B(nxt, p^1);
        }
        COMP(p, kt);
        if (nxt < 12 && nxt < 8) WRITE_A(nxt, p^1);
        __syncthreads();
        p ^= 1;
    }

    uint16_t (*L)[136] = (uint16_t(*)[136])&SM[0][0];
#pragma unroll
    for (int n = 0; n < 4; ++n) {
        const int cl = wc + n*16 + fr;
#pragma unroll
        for (int m = 0; m < 4; ++m)
#pragma unroll
            for (int q = 0; q < 4; ++q)
                L[wr + m*16 + fq*4 + q][cl] = f2bf(acc[m][n][q]);
    }
    __syncthreads();
#pragma unroll
    for (int it = 0; it < 8; ++it) {
        const int r = it*16 + (tid>>4), c8 = (tid&15)*8;
        *(uint4*)&O[((size_t)b*S_ + sp*SUPL + m0 + r)*D_ + n0 + c8] = *(uint4*)&L[r][c8];
    }
}

// ---------------- launch ----------------------------------------------------------
extern "C" void kernel_launch(void* const* d_in, const int* in_sizes, int n_in,
                              void* d_out, int out_size, void* d_ws, size_t ws_size,
                              hipStream_t stream)
{
    (void)in_sizes; (void)n_in; (void)out_size; (void)ws_size;
    const float* x  = (const float*)d_in[0];
    const float* Wq = (const float*)d_in[1];  const float* bq = (const float*)d_in[2];
    const float* Wk = (const float*)d_in[3];  const float* bk = (const float*)d_in[4];
    const float* Wv = (const float*)d_in[5];  const float* bv = (const float*)d_in[6];
    const float* Wg = (const float*)d_in[7];  const float* bg = (const float*)d_in[8];
    const float* Wo = (const float*)d_in[9];  const float* bo = (const float*)d_in[10];

    char* w = (char*)d_ws;
    const size_t MD2 = (size_t)M_*D_*2;
    uint16_t* Wb = (uint16_t*)w;                       w += 5*(size_t)D_*D_*2;
    uint16_t* xb = (uint16_t*)w;                       w += MD2;                  // x, later O
    uint16_t* Qb = (uint16_t*)w;                       w += MD2;                  // Q -> Q~
    uint16_t* Kb = (uint16_t*)w;                       w += MD2;                  // K -> K^ rows
    uint16_t* KT = (uint16_t*)w;                       w += MD2;                  // K^T [b][dk][t]
    uint16_t* VT = (uint16_t*)w;                       w += MD2;                  // V^T [b][dv][t]
    uint16_t* Gb = (uint16_t*)w;                       w += MD2;                  // gamma bf16
    uint16_t* Sst = (uint16_t*)w;                      w += (size_t)7*B_*D_*D_*2;
    uint16_t* Pb  = (uint16_t*)w;                      w += (size_t)B_*NSUP*SUPL*SUPL*2;
    float*    T   = (float*)w;                         w += (size_t)B_*NSUB*D_*4;
    float*    Pre = (float*)w;                         w += (size_t)B_*NSUB*D_*4;
    float*    Suf = (float*)w;                         w += (size_t)B_*NSUB*D_*4;
    float*    Lam = (float*)w;                         w += (size_t)B_*NSUP*D_*4;

    conv_x<<<dim3(M_*D_/2048), 256, 0, stream>>>(x, xb);
    conv_w<<<dim3(D_*D_/2048, 5), 256, 0, stream>>>(Wq, Wk, Wv, Wg, Wo, Wb);

    proj4<<<dim3(2048), 256, 0, stream>>>(xb, Wb, bq, bk, bv, bg, Qb, Kb, VT, Gb);

    prep<<<dim3(NSUB, B_), 256, 0, stream>>>(Gb, Qb, Kb, KT, T);
    tables<<<dim3(NSUP, B_), 512, 0, stream>>>(T, Pre, Suf, Lam);

    pairsA<<<dim3(36, NSUP, B_), 256, 0, stream>>>(Qb, Kb, T, Pb);
    dsgemm<<<dim3(16, 7, B_), 256, 0, stream>>>(VT, KT, Suf, Sst);
    scanfix<<<dim3(1024), 256, 0, stream>>>(Sst, Lam);

    bigout<<<dim3(2, 4, B_*NSUP), 256, 0, stream>>>(Qb, Pre, Sst, Pb, VT, xb);

    mfma_gemm<<<dim3(512), 256, 0, stream>>>(xb, Wb + 4*(size_t)D_*D_, bo, (float*)d_out);
}